// Round 16
// baseline (1203.451 us; speedup 1.0000x reference)
//
#include <hip/hip_runtime.h>
#include <hip/hip_bf16.h>
#include <stdint.h>

#define B_    8
#define N_    256
#define CTX_  196
#define CTXP_ 224   // ctx padded to multiple of 32 for PV K-loop
#define CTXF_ 13    // score col frags (13*16 = 208 >= 196)
#define IMGD_ 1024
#define DIM_  512
#define DEPTH_ 6
#define DIN_  1024
#define DTR_  32
#define DST_  16
#define HEADS_ 8
#define HD_   64
#define NCHUNK_ 16
#define CLEN_   16   // N_/NCHUNK_
#define DG_     4    // d's per scan block

typedef __bf16 bf16x8 __attribute__((ext_vector_type(8)));
typedef __bf16 bf16x4 __attribute__((ext_vector_type(4)));
typedef float  f32x4  __attribute__((ext_vector_type(4)));

// 16-lane sum via DPP butterfly; all 16 lanes get total
__device__ __forceinline__ float dpp_red16(float v) {
    int y;
    y = __builtin_amdgcn_update_dpp(0, __float_as_int(v), 0xB1, 0xF, 0xF, true);
    v += __int_as_float(y);
    y = __builtin_amdgcn_update_dpp(0, __float_as_int(v), 0x4E, 0xF, 0xF, true);
    v += __int_as_float(y);
    y = __builtin_amdgcn_update_dpp(0, __float_as_int(v), 0x141, 0xF, 0xF, true);
    v += __int_as_float(y);
    y = __builtin_amdgcn_update_dpp(0, __float_as_int(v), 0x140, 0xF, 0xF, true);
    v += __int_as_float(y);
    return v;
}
__device__ __forceinline__ float dpp_max16(float v) {
    int y;
    y = __builtin_amdgcn_update_dpp(0, __float_as_int(v), 0xB1, 0xF, 0xF, true);
    v = fmaxf(v, __int_as_float(y));
    y = __builtin_amdgcn_update_dpp(0, __float_as_int(v), 0x4E, 0xF, 0xF, true);
    v = fmaxf(v, __int_as_float(y));
    y = __builtin_amdgcn_update_dpp(0, __float_as_int(v), 0x141, 0xF, 0xF, true);
    v = fmaxf(v, __int_as_float(y));
    y = __builtin_amdgcn_update_dpp(0, __float_as_int(v), 0x140, 0xF, 0xF, true);
    v = fmaxf(v, __int_as_float(y));
    return v;
}

// async global->LDS 16B (direct-to-LDS DMA; no VGPR round trip)
__device__ __forceinline__ void gload16(const void* g, void* l) {
    __builtin_amdgcn_global_load_lds(
        (const __attribute__((address_space(1))) uint32_t*)g,
        (__attribute__((address_space(3))) uint32_t*)l, 16, 0, 0);
}

// ---------------- elementwise / small kernels ----------------

__global__ void dyt_kernel(const float* __restrict__ img, const float* __restrict__ alpha_p,
                           const float* __restrict__ gamma, const float* __restrict__ beta,
                           __bf16* __restrict__ out, int total) {
    int i = blockIdx.x * 256 + threadIdx.x;
    if (i >= total) return;
    float a = alpha_p[0];
    int c = i & (IMGD_ - 1);
    out[i] = (__bf16)(gamma[c] * tanhf(a * img[i]) + beta[c]);
}

__global__ void pool_kernel(const float* __restrict__ imgf, float* __restrict__ pooled) {
    int i = blockIdx.x * 256 + threadIdx.x;
    if (i >= B_ * DIM_) return;
    int b = i >> 9, c = i & (DIM_ - 1);
    const float* p = imgf + (size_t)b * CTX_ * DIM_ + c;
    float s = 0.f;
    for (int t = 0; t < CTX_; ++t) s += p[t * DIM_];
    pooled[i] = s * (1.f / CTX_);
}

__global__ void gate1_kernel(const float* __restrict__ pooled, const float* __restrict__ W,
                             const float* __restrict__ bias, float* __restrict__ g1) {
    int i = blockIdx.x * 256 + threadIdx.x;
    if (i >= B_ * 128) return;
    int b = i >> 7, j = i & 127;
    const float* p = pooled + b * DIM_;
    float s = bias[j];
    for (int c = 0; c < DIM_; ++c) s += p[c] * W[c * 128 + j];
    g1[i] = 0.5f * s * (1.f + erff(s * 0.70710678118654752f));
}

__global__ void gate2_kernel(const float* __restrict__ g1, const float* __restrict__ W,
                             const float* __restrict__ bias, float* __restrict__ gate) {
    int i = blockIdx.x * 256 + threadIdx.x;
    if (i >= B_ * DIM_) return;
    int b = i >> 9, c = i & (DIM_ - 1);
    const float* p = g1 + b * 128;
    float s = bias[c];
    for (int j = 0; j < 128; ++j) s += p[j] * W[j * DIM_ + c];
    gate[i] = 1.f / (1.f + __expf(-s));
}

__global__ void scale_kernel(const float* __restrict__ imgf, const float* __restrict__ gate,
                             __bf16* __restrict__ imgfb) {
    int i = blockIdx.x * 256 + threadIdx.x;
    if (i >= B_ * CTX_ * DIM_) return;
    int c = i & (DIM_ - 1);
    int b = i / (CTX_ * DIM_);
    imgfb[i] = (__bf16)(imgf[i] * gate[b * DIM_ + c]);
}

__global__ void embed_kernel(const int* __restrict__ text, const float* __restrict__ temb,
                             const float* __restrict__ pemb, float* __restrict__ x) {
    int i = blockIdx.x * 256 + threadIdx.x;
    if (i >= B_ * N_ * DIM_) return;
    int c = i & (DIM_ - 1);
    int row = i >> 9;
    int n = row & (N_ - 1);
    int tok = text[row];
    x[i] = temb[(size_t)tok * DIM_ + c] + pemb[(size_t)n * DIM_ + c];
}

// wave-per-row layernorm, row = 512 floats, bf16 output
__global__ void ln_kernel(const float* __restrict__ x, const float* __restrict__ g,
                          const float* __restrict__ b, __bf16* __restrict__ o, int rows) {
    int row = blockIdx.x * 4 + (threadIdx.x >> 6);
    if (row >= rows) return;
    int lane = threadIdx.x & 63;
    const float* xr = x + (size_t)row * DIM_ + lane * 8;
    float4 v0 = ((const float4*)xr)[0];
    float4 v1 = ((const float4*)xr)[1];
    float r[8] = {v0.x, v0.y, v0.z, v0.w, v1.x, v1.y, v1.z, v1.w};
    float sum = 0.f, sq = 0.f;
    #pragma unroll
    for (int j = 0; j < 8; ++j) { sum += r[j]; sq += r[j] * r[j]; }
    #pragma unroll
    for (int m = 1; m < 64; m <<= 1) { sum += __shfl_xor(sum, m); sq += __shfl_xor(sq, m); }
    float mean = sum * (1.f / DIM_);
    float var  = sq * (1.f / DIM_) - mean * mean;
    float inv  = rsqrtf(fmaxf(var, 0.f) + 1e-5f);
    const float* gp = g + lane * 8;
    const float* bp = b + lane * 8;
    __bf16* op = o + (size_t)row * DIM_ + lane * 8;
    bf16x8 ov;
    #pragma unroll
    for (int j = 0; j < 8; ++j) ov[j] = (__bf16)((r[j] - mean) * inv * gp[j] + bp[j]);
    *(bf16x8*)op = ov;
}

// causal depthwise conv (4 taps) + SiLU; float4-vectorized over d
__global__ void conv_silu_kernel(const float* __restrict__ xz, const float* __restrict__ cw,
                                 const float* __restrict__ cb, float* __restrict__ xc,
                                 __bf16* __restrict__ xcb) {
    int idx = blockIdx.x * 256 + threadIdx.x;
    if (idx >= B_ * N_ * DIN_ / 4) return;
    int i4 = idx * 4;
    int d = i4 & (DIN_ - 1);
    int row = i4 >> 10;
    int n = row & (N_ - 1);
    int rowb = row - n;
    float4 acc = *(const float4*)(cb + d);
    #pragma unroll
    for (int k = 0; k < 4; ++k) {
        int m = n - 3 + k;
        if (m >= 0) {
            float4 v = *(const float4*)(xz + (size_t)(rowb + m) * (2 * DIN_) + d);
            acc.x += v.x * cw[(d + 0) * 4 + k];
            acc.y += v.y * cw[(d + 1) * 4 + k];
            acc.z += v.z * cw[(d + 2) * 4 + k];
            acc.w += v.w * cw[(d + 3) * 4 + k];
        }
    }
    float4 s;
    s.x = acc.x / (1.f + __expf(-acc.x));
    s.y = acc.y / (1.f + __expf(-acc.y));
    s.z = acc.z / (1.f + __expf(-acc.z));
    s.w = acc.w / (1.f + __expf(-acc.w));
    *(float4*)(xc + i4) = s;
    bf16x4 p = {(__bf16)s.x, (__bf16)s.y, (__bf16)s.z, (__bf16)s.w};
    *(bf16x4*)(xcb + i4) = p;
}

__global__ void cvt_bf16_kernel(const float* __restrict__ src, __bf16* __restrict__ dst, int count) {
    int i = (blockIdx.x * 256 + threadIdx.x) * 4;
    if (i >= count) return;
    float4 v = *(const float4*)(src + i);
    bf16x4 p = {(__bf16)v.x, (__bf16)v.y, (__bf16)v.z, (__bf16)v.w};
    *(bf16x4*)(dst + i) = p;
}

// row-sliced convert: dst row i (K=512) <- src row (i/rpl)*1536 + off + (i%rpl)
__global__ void cvt_rows_kernel(const float* __restrict__ src, __bf16* __restrict__ dst,
                                int totalRows, int rpl, int off) {
    int t = blockIdx.x * 256 + threadIdx.x;
    int total = totalRows * (DIM_ / 4);
    if (t >= total) return;
    int i = t / (DIM_ / 4), c4 = (t % (DIM_ / 4)) * 4;
    int l = i / rpl, r = i % rpl;
    const float* s = src + ((size_t)l * 1536 + off + r) * DIM_ + c4;
    float4 v = *(const float4*)s;
    bf16x4 p = {(__bf16)v.x, (__bf16)v.y, (__bf16)v.z, (__bf16)v.w};
    *(bf16x4*)(dst + (size_t)i * DIM_ + c4) = p;
}

// ---------------- fused selective scan v5: 4 d's per block ----------------
__global__ __launch_bounds__(256) void scanf_kernel(
    const float* __restrict__ xc, const float* __restrict__ dbl,
    const float* __restrict__ xz, const float* __restrict__ dtw,
    const float* __restrict__ dtb, const float* __restrict__ A_log,
    const float* __restrict__ Dsk, __bf16* __restrict__ ybb) {
    __shared__ float sdt[DG_][N_], su[DG_][N_];
    __shared__ float sA[DG_][256], sB[DG_][256];
    int bid = blockIdx.x;
    int nwg = gridDim.x;                       // 2048, % 8 == 0
    int bd = (bid & 7) * (nwg >> 3) + (bid >> 3);   // bijective XCD swizzle
    int dg = bd & (DIN_ / DG_ - 1), b = bd / (DIN_ / DG_);
    int d0 = dg * DG_;
    int tid = threadIdx.x, s = tid & 15, c = tid >> 4;
    {
        int row = b * N_ + tid;
        const float* dp = dbl + row * 64;
        float4 acc = *(const float4*)(dtb + d0);
        #pragma unroll
        for (int k = 0; k < DTR_; k += 4) {
            float4 dv = *(const float4*)(dp + k);
            float4 w0 = *(const float4*)(dtw + (k + 0) * DIN_ + d0);
            float4 w1 = *(const float4*)(dtw + (k + 1) * DIN_ + d0);
            float4 w2 = *(const float4*)(dtw + (k + 2) * DIN_ + d0);
            float4 w3 = *(const float4*)(dtw + (k + 3) * DIN_ + d0);
            acc.x += dv.x * w0.x + dv.y * w1.x + dv.z * w2.x + dv.w * w3.x;
            acc.y += dv.x * w0.y + dv.y * w1.y + dv.z * w2.y + dv.w * w3.y;
            acc.z += dv.x * w0.z + dv.y * w1.z + dv.z * w2.z + dv.w * w3.z;
            acc.w += dv.x * w0.w + dv.y * w1.w + dv.z * w2.w + dv.w * w3.w;
        }
        float4 xcv = *(const float4*)(xc + (size_t)row * DIN_ + d0);
        float av[4] = {acc.x, acc.y, acc.z, acc.w};
        float xv[4] = {xcv.x, xcv.y, xcv.z, xcv.w};
        #pragma unroll
        for (int g = 0; g < DG_; ++g) {
            float dt = fmaxf(av[g], 0.f) + __logf(1.f + __expf(-fabsf(av[g])));
            sdt[g][tid] = dt;
            su[g][tid] = dt * xv[g];
        }
    }
    float As4[DG_];
    #pragma unroll
    for (int g = 0; g < DG_; ++g) As4[g] = -__expf(A_log[((d0 + g) << 4) | s]);
    __syncthreads();
    int r0 = c * CLEN_;
    int row0 = b * N_ + r0;
    float a[DG_], hb[DG_];
    #pragma unroll
    for (int g = 0; g < DG_; ++g) { a[g] = 1.f; hb[g] = 0.f; }
    #pragma unroll 2
    for (int n = 0; n < CLEN_; ++n) {
        float Bv = dbl[(row0 + n) * 64 + 32 + s];
        #pragma unroll
        for (int g = 0; g < DG_; ++g) {
            float dA = __expf(sdt[g][r0 + n] * As4[g]);
            hb[g] = hb[g] * dA + su[g][r0 + n] * Bv;
            a[g] *= dA;
        }
    }
    #pragma unroll
    for (int g = 0; g < DG_; ++g) { sA[g][tid] = a[g]; sB[g][tid] = hb[g]; }
    __syncthreads();
    float h[DG_];
    #pragma unroll
    for (int g = 0; g < DG_; ++g) h[g] = 0.f;
    for (int j = 0; j < c; ++j)
        #pragma unroll
        for (int g = 0; g < DG_; ++g)
            h[g] = h[g] * sA[g][j * 16 + s] + sB[g][j * 16 + s];
    float4 Dv4 = *(const float4*)(Dsk + d0);
    float Dv[4] = {Dv4.x, Dv4.y, Dv4.z, Dv4.w};
    #pragma unroll 2
    for (int n = 0; n < CLEN_; ++n) {
        int row = row0 + n;
        float Bv = dbl[row * 64 + 32 + s];
        float Cv = dbl[row * 64 + 48 + s];
        float p[DG_];
        #pragma unroll
        for (int g = 0; g < DG_; ++g) {
            float dA = __expf(sdt[g][r0 + n] * As4[g]);
            h[g] = h[g] * dA + su[g][r0 + n] * Bv;
            p[g] = dpp_red16(h[g] * Cv);
        }
        if (s == 0) {
            float4 xcv = *(const float4*)(xc + (size_t)row * DIN_ + d0);
            float4 zz4 = *(const float4*)(xz + (size_t)row * (2 * DIN_) + DIN_ + d0);
            float xv[4] = {xcv.x, xcv.y, xcv.z, xcv.w};
            float zv[4] = {zz4.x, zz4.y, zz4.z, zz4.w};
            bf16x4 yo;
            #pragma unroll
            for (int g = 0; g < DG_; ++g) {
                float y = (p[g] + xv[g] * Dv[g]) * (zv[g] / (1.f + __expf(-zv[g])));
                yo[g] = (__bf16)y;
            }
            *(bf16x4*)(ybb + (size_t)row * DIN_ + d0) = yo;
        }
    }
}

// ---------------- weight prep ----------------

__global__ void tconv_kernel(const float* __restrict__ src, __bf16* __restrict__ dst,
                             int K, int N) {
    __shared__ float tile[32][33];
    int n0 = blockIdx.x * 32, k0 = blockIdx.y * 32;
    src += (size_t)blockIdx.z * K * N;
    dst += (size_t)blockIdx.z * K * N;
    int tx = threadIdx.x & 31, ty = threadIdx.x >> 5;
    #pragma unroll
    for (int i = 0; i < 32; i += 8) {
        int k = k0 + ty + i, n = n0 + tx;
        tile[ty + i][tx] = (k < K && n < N) ? src[(size_t)k * N + n] : 0.f;
    }
    __syncthreads();
    #pragma unroll
    for (int i = 0; i < 32; i += 8) {
        int n = n0 + ty + i, k = k0 + tx;
        if (n < N && k < K) dst[(size_t)n * K + k] = (__bf16)tile[tx][ty + i];
    }
}

// ---------------- bf16 MFMA GEMM v3: global_load_lds staging ----------------
// MODE 0: fp32 out (+res). MODE 1: bf16 out. MODE 3: batched-kv epilogue.
// CMAJ: column-major block mapping — each XCD owns a col-slab so the B panel
// slice (not the whole B) must fit its L2. Use when N >> M (kv, logits).

template <int BM, int BN, int MODE, bool CMAJ = false>
__global__ __launch_bounds__(256) void mgemm_k(
    const __bf16* __restrict__ A, const __bf16* __restrict__ Bw,
    const float* __restrict__ bias, const float* __restrict__ res,
    void* __restrict__ Cp, void* __restrict__ Cp2,
    int M, int N, int K, int lda, int ldc) {
    constexpr int UA = BM * 4;   // 16B units per 32-K slab tile
    constexpr int UB = BN * 4;
    constexpr int FM = BM / 32, FN = BN / 32;
    __shared__ __align__(16) __bf16 As[2][UA * 8];
    __shared__ __align__(16) __bf16 Bs[2][UB * 8];
    int tid = threadIdx.x;
    int ntx = gridDim.x;
    int nwg = ntx * gridDim.y;
    int bid = blockIdx.y * ntx + blockIdx.x;
    if ((nwg & 7) == 0) bid = (bid & 7) * (nwg >> 3) + (bid >> 3);
    int row0, col0;
    if constexpr (CMAJ) {
        int nty = nwg / ntx;
        row0 = (bid % nty) * BM;
        col0 = (bid / nty) * BN;
    } else {
        row0 = (bid / ntx) * BM;
        col0 = (bid % ntx) * BN;
    }
    int wave = tid >> 6, lane = tid & 63;
    int wm = (wave >> 1) * (BM / 2), wn = (wave & 1) * (BN / 2);
    int fr = lane & 15, fk = lane >> 4;
    f32x4 acc[FM][FN] = {};

    auto stage = [&](int buf, int k0) {
        #pragma unroll
        for (int j = 0; j < (UA + 255) / 256; ++j) {
            int u = j * 256 + tid;
            if ((UA & 255) == 0 || u < UA) {
                int ks = u / BM, r = u % BM;
                gload16(A + (size_t)(row0 + r) * lda + k0 + ks * 8, &As[buf][u * 8]);
            }
        }
        #pragma unroll
        for (int j = 0; j < (UB + 255) / 256; ++j) {
            int u = j * 256 + tid;
            if ((UB & 255) == 0 || u < UB) {
                int ks = u / BN, r = u % BN;
                gload16(Bw + (size_t)(col0 + r) * K + k0 + ks * 8, &Bs[buf][u * 8]);
            }
        }
    };

    stage(0, 0);
    __syncthreads();
    int NK = K >> 5;
    for (int kt = 0; kt < NK; ++kt) {
        int cur = kt & 1;
        if (kt + 1 < NK) stage(cur ^ 1, (kt + 1) << 5);   // loads fly over MFMA phase
        bf16x8 af[FM], bg[FN];
        #pragma unroll
        for (int mf = 0; mf < FM; ++mf)
            af[mf] = *(const bf16x8*)&As[cur][(fk * BM + wm + mf * 16 + fr) * 8];
        #pragma unroll
        for (int nf = 0; nf < FN; ++nf)
            bg[nf] = *(const bf16x8*)&Bs[cur][(fk * BN + wn + nf * 16 + fr) * 8];
        #pragma unroll
        for (int mf = 0; mf < FM; ++mf)
            #pragma unroll
            for (int nf = 0; nf < FN; ++nf)
                acc[mf][nf] = __builtin_amdgcn_mfma_f32_16x16x32_bf16(af[mf], bg[nf], acc[mf][nf], 0, 0, 0);
        __syncthreads();   // drains vmcnt (next tile landed) + protects cur for overwrite
    }
    #pragma unroll
    for (int mf = 0; mf < FM; ++mf) {
        #pragma unroll
        for (int nf = 0; nf < FN; ++nf) {
            int gn = col0 + wn + nf * 16 + fr;
            if (gn >= N) continue;
            float bb = (MODE != 3 && bias) ? bias[gn] : 0.f;
            #pragma unroll
            for (int e = 0; e < 4; ++e) {
                int gm = row0 + wm + mf * 16 + fk * 4 + e;
                if (gm >= M) continue;
                float v = acc[mf][nf][e] + bb;
                if constexpr (MODE == 0) {
                    size_t idx = (size_t)gm * ldc + gn;
                    if (res) v += res[idx];
                    ((float*)Cp)[idx] = v;
                } else if constexpr (MODE == 1) {
                    ((__bf16*)Cp)[(size_t)gm * ldc + gn] = (__bf16)v;
                } else {
                    int l = gn >> 10, j = gn & 1023;
                    float vb = v + res[l * 1536 + 512 + j];  // ainb[l][512+j]
                    if (j < DIM_) {
                        ((__bf16*)Cp)[(size_t)l * (B_ * CTX_) * DIM_ + (size_t)gm * DIM_ + j] = (__bf16)vb;
                    } else {
                        int jj = j - DIM_;
                        int bimg = gm / CTX_, k = gm - bimg * CTX_;
                        ((__bf16*)Cp2)[(((size_t)l * B_ * HEADS_ + bimg * HEADS_ + (jj >> 6)) * HD_ + (jj & 63)) * CTXP_ + k] = (__bf16)vb;
                    }
                }
            }
        }
    }
}

template <int BM, int BN, int MODE = 0, bool CMAJ = false>
static inline void mgemm(const __bf16* A, const __bf16* Bw, const float* bias,
                         const float* res, void* C, void* C2, int M, int N, int K,
                         int lda, int ldc, hipStream_t s) {
    dim3 g((N + BN - 1) / BN, (M + BM - 1) / BM);
    mgemm_k<BM, BN, MODE, CMAJ><<<g, 256, 0, s>>>(A, Bw, bias, res, C, C2, M, N, K, lda, ldc);
}

// ---------------- fused attention ----------------
#define KP_ 72    // K LDS row pad (bf16)
#define PP_ 232   // P LDS row pad (bf16)

__global__ __launch_bounds__(256) void attn_k(
    const __bf16* __restrict__ qb, const __bf16* __restrict__ kbb,
    const __bf16* __restrict__ vbT, __bf16* __restrict__ obb) {
    __shared__ __align__(16) __bf16 Ks[CTXP_ * KP_];
    __shared__ __align__(16) __bf16 Ps[64 * PP_];
    int z = blockIdx.z, b = z >> 3, h = z & 7;
    int tid = threadIdx.x, wave = tid >> 6, lane = tid & 63;
    int fr = lane & 15, fk = lane >> 4;
    int q0 = blockIdx.y * 64;
    #pragma unroll
    for (int i = 0; i < 7; ++i) {
        int idx = i * 256 + tid;
        int r = idx >> 3, cu = (idx & 7) * 8;
        uint4 v = {0u, 0u, 0u, 0u};
        if (r < CTX_) v = *(const uint4*)(kbb + ((size_t)(b * CTX_ + r)) * DIM_ + h * HD_ + cu);
        *(uint4*)&Ks[r * KP_ + cu] = v;
    }
    bf16x8 aq[2];
    {
        int qrow = b * N_ + q0 + wave * 16 + fr;
        #pragma unroll
        for (int t = 0; t < 2; ++t)
            aq[t] = *(const bf16x8*)(qb + (size_t)qrow * DIM_ + h * HD_ + t * 32 + fk * 8);
    }
    __syncthreads();
    f32x4 acc[CTXF_] = {};
    #pragma unroll
    for (int t = 0; t < 2; ++t)
        #pragma unroll
        for (int cb = 0; cb < CTXF_; ++cb) {
            bf16x8 bg = *(const bf16x8*)&Ks[(cb * 16 + fr) * KP_ + t * 32 + fk * 8];
            acc[cb] = __builtin_amdgcn_mfma_f32_16x16x32_bf16(aq[t], bg, acc[cb], 0, 0, 0);
        }
    #pragma unroll
    for (int e = 0; e < 4; ++e) {
        float m = -1e30f;
        #pragma unroll
        for (int cb = 0; cb < CTXF_; ++cb) {
            float sv = acc[cb][e] * 0.125f;
            if (cb * 16 + fr >= CTX_) sv = -1e30f;
            acc[cb][e] = sv;
            m = fmaxf(m, sv);
        }
        m = dpp_max16(m);
        float ssum = 0.f;
        #pragma unroll
        for (int cb = 0; cb < CTXF_; ++cb) {
            float p = __expf(acc[cb][e] - m);
            acc[cb][e] = p;
            ssum += p;
        }
        ssum = dpp_red16(ssum);
        float inv = 1.f / ssum;
        #pragma unroll
        for (int cb = 0; cb < CTXF_; ++cb)
            Ps[(wave * 16 + fk * 4 + e) * PP_ + cb * 16 + fr] = (__bf16)(acc[cb][e] * inv);
        Ps[(wave * 16 + fk * 4 + e) * PP_ + 208 + fr] = (__bf16)0.f;
    }
    __syncthreads();
    f32x4 acc2[4] = {};
    const __bf16* vB = vbT + (size_t)z * HD_ * CTXP_;
    #pragma unroll
    for (int sl = 0; sl < 7; ++sl) {
        bf16x8 ap = *(const bf16x8*)&Ps[(wave * 16 + fr) * PP_ + sl * 32 + fk * 8];
        #pragma unroll
        for (int nf = 0; nf < 4; ++nf) {
            bf16x8 bv = *(const bf16x8*)(vB + (size_t)(nf * 16 + fr) * CTXP_ + sl * 32 + fk * 8);
            acc2[nf] = __builtin_amdgcn_mfma_f32_16x16x32_bf16(ap, bv, acc2[nf], 0, 0, 0);
        }
    }
    #pragma unroll
    for (int nf = 0; nf < 4; ++nf)
        #pragma unroll
        for (int e = 0; e < 4; ++e) {
            int gm = b * N_ + q0 + wave * 16 + fk * 4 + e;
            obb[(size_t)gm * DIM_ + h * HD_ + nf * 16 + fr] = (__bf16)acc2[nf][e];
        }
}

// ---------------- host side ----------------

extern "C" void kernel_launch(void* const* d_in, const int* in_sizes, int n_in,
                              void* d_out, int out_size, void* d_ws, size_t ws_size,
                              hipStream_t stream) {
    const int*   text   = (const int*)d_in[0];
    const float* images = (const float*)d_in[1];
    const float* alphap = (const float*)d_in[2];
    const float* dgam   = (const float*)d_in[3];
    const float* dbeta  = (const float*)d_in[4];
    const float* imgW   = (const float*)d_in[5];
    const float* imgb   = (const float*)d_in[6];
    const float* g1W    = (const float*)d_in[7];
    const float* g1b    = (const float*)d_in[8];
    const float* g2W    = (const float*)d_in[9];
    const float* g2b    = (const float*)d_in[10];
    const float* temb   = (const float*)d_in[11];
    const float* pemb   = (const float*)d_in[12];
    const float* ln1g   = (const float*)d_in[13];
    const float* ln1b   = (const float*)d_in[14];
    const float* inW    = (const float*)d_in[15];
    const float* convW  = (const float*)d_in[16];
    const float* convb  = (const float*)d_in[17];
    const float* xpW    = (const float*)d_in[18];
    const float* dtW    = (const float*)d_in[19];
    const float* dtb    = (const float*)d_in[20];
    const float* Alog   = (const float*)d_in[21];
    const float* Dsk    = (const float*)d_in[22];
    const float* outW   = (const float*)d_in[23];
    const float* ln2g   = (const float*)d_in[24];
    const float* ln2b   = (const float*)d_in[25];
    const float* ainW   = (const float*)d_in[26];
    const float* ainb   = (const float*)d_in[27];
    const float* aoutW  = (const float*)d_in[28];
    const float* aoutb  = (const float*)d_in[29];
    const float* fng    = (const float*)d_in[30];
    const float* fnb    = (const float*)d_in[31];
    const float* lgW    = (const float*)d_in[32];
    const float* lgb    = (const float*)d_in[33];
    float* out = (float*)d_out;

    float* w = (float*)d_ws;
    float* imgd   = w; w += (size_t)B_ * CTX_ * IMGD_;   // bf16 dyt out (aliased)
    float* imgf   = w; w += (size_t)B_ * CTX_ * DIM_;
    float* pooled = w; w += B_ * DIM_;
    float* g1     = w; w += B_ * 128;
    float* gate   = w; w += B_ * DIM_;
    float* x      = w; w += (size_t)B_ * N_ * DIM_;
    float* xn     = w; w += (size_t)B_ * N_ * DIM_;      // bf16 ln out (aliased)
    float* xz     = w; w += (size_t)B_ * N_ * 2 * DIN_;
    float* xc     = w; w += (size_t)B_ * N_ * DIN_;
    float* dblb   = w; w += (size_t)B_ * N_ * 64;
    // bf16 buffers
    __bf16* xcb   = (__bf16*)w; w += (size_t)B_ * N_ * DIN_ / 2;
    __bf16* imgfb = (__bf16*)w; w += (size_t)B_ * CTX_ * DIM_ / 2;
    __bf16* ybb   = (__bf16*)w; w += (size_t)B_ * N_ * DIN_ / 2;
    __bf16* qb    = (__bf16*)w; w += (size_t)B_ * N_ * DIM_ / 2;
    __bf16* kbb   = (__bf16*)w; w += (size_t)DEPTH_ * B_ * CTX_ * DIM_ / 2;
    __bf16* vbT   = (__bf16*)w; w += (size_t)DEPTH_ * B_ * HEADS_ * HD_ * CTXP_ / 2;
    __bf16* obb   = (__bf16*)w; w += (size_t)B_ * N_ * DIM_ / 2;
    __bf16* lgT   = (__bf16*)w; w += (size_t)10000 * DIM_ / 2;
    // bf16 weights
    __bf16* inpT  = (__bf16*)w; w += (size_t)DEPTH_ * 2 * DIN_ * DIM_ / 2;
    __bf16* outpT = (__bf16*)w; w += (size_t)DEPTH_ * DIM_ * DIN_ / 2;
    __bf16* qWB   = (__bf16*)w; w += (size_t)DEPTH_ * DIM_ * DIM_ / 2;
    __bf16* kvWB  = (__bf16*)w; w += (size_t)DEPTH_ * 2 * DIM_ * DIM_ / 2;
    __bf16* aoutB = (__bf16*)w; w += (size_t)DEPTH_ * DIM_ * DIM_ / 2;
    __bf16* imgWT = (__bf16*)w; w += (size_t)DIM_ * IMGD_ / 2;
    __bf16* xpWT  = (__bf16*)w; w += (size_t)DEPTH_ * 64 * DIN_ / 2;
    __bf16* imgdb = (__bf16*)imgd;
    __bf16* xnb   = (__bf16*)xn;

    const int TOKENS = B_ * N_;
    const int IMGT   = B_ * CTX_;

    // zero all layers' vbT pad columns once
    hipMemsetAsync(vbT, 0, (size_t)DEPTH_ * B_ * HEADS_ * HD_ * CTXP_ * sizeof(__bf16), stream);

    // ---- weight prep ----
    tconv_kernel<<<dim3(2 * DIN_ / 32, DIM_ / 32, DEPTH_), 256, 0, stream>>>(inW,  inpT,  DIM_, 2 * DIN_);
    tconv_kernel<<<dim3(DIM_ / 32, DIN_ / 32, DEPTH_),     256, 0, stream>>>(outW, outpT, DIN_, DIM_);
    tconv_kernel<<<dim3(DIM_ / 32, IMGD_ / 32, 1),         256, 0, stream>>>(imgW, imgWT, IMGD_, DIM_);
    tconv_kernel<<<dim3(64 / 32, DIN_ / 32, DEPTH_),       256, 0, stream>>>(xpW,  xpWT,  DIN_, 64);
    tconv_kernel<<<dim3((10000 + 31) / 32, DIM_ / 32, 1),  256, 0, stream>>>(lgW, lgT, DIM_, 10000);
    cvt_rows_kernel<<<(DEPTH_ * DIM_ * (DIM_ / 4) + 255) / 256, 256, 0, stream>>>(
        ainW, qWB, DEPTH_ * DIM_, DIM_, 0);
    cvt_rows_kernel<<<(DEPTH_ * 2 * DIM_ * (DIM_ / 4) + 255) / 256, 256, 0, stream>>>(
        ainW, kvWB, DEPTH_ * 2 * DIM_, 2 * DIM_, DIM_);
    cvt_bf16_kernel<<<(DEPTH_ * DIM_ * DIM_ / 4 + 255) / 256, 256, 0, stream>>>(aoutW, aoutB, DEPTH_ * DIM_ * DIM_);

    // ---- image path ----
    {
        int total = B_ * CTX_ * IMGD_;
        dyt_kernel<<<(total + 255) / 256, 256, 0, stream>>>(images, alphap, dgam, dbeta, imgdb, total);
        mgemm<32, 64>(imgdb, imgWT, imgb, nullptr, imgf, nullptr, IMGT, DIM_, IMGD_, IMGD_, DIM_, stream);
        pool_kernel<<<(B_ * DIM_ + 255) / 256, 256, 0, stream>>>(imgf, pooled);
        gate1_kernel<<<(B_ * 128 + 255) / 256, 256, 0, stream>>>(pooled, g1W, g1b, g1);
        gate2_kernel<<<(B_ * DIM_ + 255) / 256, 256, 0, stream>>>(g1, g2W, g2b, gate);
        scale_kernel<<<(B_ * CTX_ * DIM_ + 255) / 256, 256, 0, stream>>>(imgf, gate, imgfb);
    }
    embed_kernel<<<(TOKENS * DIM_ + 255) / 256, 256, 0, stream>>>(text, temb, pemb, x);

    // ---- ALL layers' K/V projections in ONE batched GEMM (col-major slabs) ----
    mgemm<64, 128, 3, true>(imgfb, kvWB, nullptr, ainb, kbb, vbT,
                            IMGT, DEPTH_ * 2 * DIM_, DIM_, DIM_, 0, stream);

    for (int l = 0; l < DEPTH_; ++l) {
        const __bf16* inpT_l  = inpT  + (size_t)l * 2 * DIN_ * DIM_;
        const __bf16* outpT_l = outpT + (size_t)l * DIM_ * DIN_;
        const __bf16* qWB_l   = qWB   + (size_t)l * DIM_ * DIM_;
        const __bf16* aoutB_l = aoutB + (size_t)l * DIM_ * DIM_;
        const __bf16* xpWT_l  = xpWT  + (size_t)l * 64 * DIN_;
        const __bf16* kbb_l   = kbb   + (size_t)l * IMGT * DIM_;
        const __bf16* vbT_l   = vbT   + (size_t)l * B_ * HEADS_ * HD_ * CTXP_;
        const float* cw    = convW + (size_t)l * DIN_ * 4;
        const float* cb    = convb + (size_t)l * DIN_;
        const float* dtw   = dtW  + (size_t)l * DTR_ * DIN_;
        const float* dtbi  = dtb  + (size_t)l * DIN_;
        const float* alog  = Alog + (size_t)l * DIN_ * DST_;
        const float* dsk   = Dsk  + (size_t)l * DIN_;
        const float* ab    = ainb + (size_t)l * 3 * DIM_;
        const float* aob   = aoutb + (size_t)l * DIM_;

        // mamba block
        ln_kernel<<<TOKENS / 4, 256, 0, stream>>>(x, ln1g + l * DIM_, ln1b + l * DIM_, xnb, TOKENS);
        mgemm<64, 128>(xnb, inpT_l, nullptr, nullptr, xz, nullptr, TOKENS, 2 * DIN_, DIM_, DIM_, 2 * DIN_, stream);
        conv_silu_kernel<<<(TOKENS * DIN_ / 4 + 255) / 256, 256, 0, stream>>>(xz, cw, cb, xc, xcb);
        mgemm<32, 64>(xcb, xpWT_l, nullptr, nullptr, dblb, nullptr, TOKENS, 64, DIN_, DIN_, 64, stream);
        scanf_kernel<<<B_ * DIN_ / DG_, 256, 0, stream>>>(xc, dblb, xz, dtw, dtbi, alog, dsk, ybb);
        mgemm<32, 64>(ybb, outpT_l, nullptr, x, x, nullptr, TOKENS, DIM_, DIN_, DIN_, DIM_, stream);

        // cross-attention block
        ln_kernel<<<TOKENS / 4, 256, 0, stream>>>(x, ln2g + l * DIM_, ln2b + l * DIM_, xnb, TOKENS);
        mgemm<32, 64, 1>(xnb, qWB_l, ab, nullptr, qb, nullptr, TOKENS, DIM_, DIM_, DIM_, DIM_, stream);
        attn_k<<<dim3(1, 4, B_ * HEADS_), 256, 0, stream>>>(qb, kbb_l, vbT_l, obb);
        mgemm<32, 64>(obb, aoutB_l, aob, x, x, nullptr, TOKENS, DIM_, DIM_, DIM_, DIM_, stream);
    }

    // final LN + logits (col-major slabs + 64-row tile: more resident waves
    // to hide the 82 MB fp32 output-write drain)
    ln_kernel<<<TOKENS / 4, 256, 0, stream>>>(x, fng, fnb, xnb, TOKENS);
    mgemm<64, 128, 0, true>(xnb, lgT, lgb, nullptr, out, nullptr, TOKENS, 10000, DIM_, DIM_, 10000, stream);
}

// Round 17
// 1190.886 us; speedup vs baseline: 1.0106x; 1.0106x over previous
//
#include <hip/hip_runtime.h>
#include <hip/hip_bf16.h>
#include <stdint.h>

#define B_    8
#define N_    256
#define CTX_  196
#define CTXP_ 224   // ctx padded to multiple of 32 for PV K-loop
#define CTXF_ 13    // score col frags (13*16 = 208 >= 196)
#define IMGD_ 1024
#define DIM_  512
#define DEPTH_ 6
#define DIN_  1024
#define DTR_  32
#define DST_  16
#define HEADS_ 8
#define HD_   64
#define NCHUNK_ 16
#define CLEN_   16   // N_/NCHUNK_
#define DG_     4    // d's per scan block

typedef __bf16 bf16x8 __attribute__((ext_vector_type(8)));
typedef __bf16 bf16x4 __attribute__((ext_vector_type(4)));
typedef float  f32x4  __attribute__((ext_vector_type(4)));

// 16-lane sum via DPP butterfly; all 16 lanes get total
__device__ __forceinline__ float dpp_red16(float v) {
    int y;
    y = __builtin_amdgcn_update_dpp(0, __float_as_int(v), 0xB1, 0xF, 0xF, true);
    v += __int_as_float(y);
    y = __builtin_amdgcn_update_dpp(0, __float_as_int(v), 0x4E, 0xF, 0xF, true);
    v += __int_as_float(y);
    y = __builtin_amdgcn_update_dpp(0, __float_as_int(v), 0x141, 0xF, 0xF, true);
    v += __int_as_float(y);
    y = __builtin_amdgcn_update_dpp(0, __float_as_int(v), 0x140, 0xF, 0xF, true);
    v += __int_as_float(y);
    return v;
}
__device__ __forceinline__ float dpp_max16(float v) {
    int y;
    y = __builtin_amdgcn_update_dpp(0, __float_as_int(v), 0xB1, 0xF, 0xF, true);
    v = fmaxf(v, __int_as_float(y));
    y = __builtin_amdgcn_update_dpp(0, __float_as_int(v), 0x4E, 0xF, 0xF, true);
    v = fmaxf(v, __int_as_float(y));
    y = __builtin_amdgcn_update_dpp(0, __float_as_int(v), 0x141, 0xF, 0xF, true);
    v = fmaxf(v, __int_as_float(y));
    y = __builtin_amdgcn_update_dpp(0, __float_as_int(v), 0x140, 0xF, 0xF, true);
    v = fmaxf(v, __int_as_float(y));
    return v;
}

// async global->LDS 16B (direct-to-LDS DMA; no VGPR round trip)
__device__ __forceinline__ void gload16(const void* g, void* l) {
    __builtin_amdgcn_global_load_lds(
        (const __attribute__((address_space(1))) uint32_t*)g,
        (__attribute__((address_space(3))) uint32_t*)l, 16, 0, 0);
}

// ---------------- elementwise / small kernels ----------------

__global__ void dyt_kernel(const float* __restrict__ img, const float* __restrict__ alpha_p,
                           const float* __restrict__ gamma, const float* __restrict__ beta,
                           __bf16* __restrict__ out, int total) {
    int i = blockIdx.x * 256 + threadIdx.x;
    if (i >= total) return;
    float a = alpha_p[0];
    int c = i & (IMGD_ - 1);
    out[i] = (__bf16)(gamma[c] * tanhf(a * img[i]) + beta[c]);
}

__global__ void pool_kernel(const float* __restrict__ imgf, float* __restrict__ pooled) {
    int i = blockIdx.x * 256 + threadIdx.x;
    if (i >= B_ * DIM_) return;
    int b = i >> 9, c = i & (DIM_ - 1);
    const float* p = imgf + (size_t)b * CTX_ * DIM_ + c;
    float s = 0.f;
    for (int t = 0; t < CTX_; ++t) s += p[t * DIM_];
    pooled[i] = s * (1.f / CTX_);
}

__global__ void gate1_kernel(const float* __restrict__ pooled, const float* __restrict__ W,
                             const float* __restrict__ bias, float* __restrict__ g1) {
    int i = blockIdx.x * 256 + threadIdx.x;
    if (i >= B_ * 128) return;
    int b = i >> 7, j = i & 127;
    const float* p = pooled + b * DIM_;
    float s = bias[j];
    for (int c = 0; c < DIM_; ++c) s += p[c] * W[c * 128 + j];
    g1[i] = 0.5f * s * (1.f + erff(s * 0.70710678118654752f));
}

__global__ void gate2_kernel(const float* __restrict__ g1, const float* __restrict__ W,
                             const float* __restrict__ bias, float* __restrict__ gate) {
    int i = blockIdx.x * 256 + threadIdx.x;
    if (i >= B_ * DIM_) return;
    int b = i >> 9, c = i & (DIM_ - 1);
    const float* p = g1 + b * 128;
    float s = bias[c];
    for (int j = 0; j < 128; ++j) s += p[j] * W[j * DIM_ + c];
    gate[i] = 1.f / (1.f + __expf(-s));
}

__global__ void scale_kernel(const float* __restrict__ imgf, const float* __restrict__ gate,
                             __bf16* __restrict__ imgfb) {
    int i = blockIdx.x * 256 + threadIdx.x;
    if (i >= B_ * CTX_ * DIM_) return;
    int c = i & (DIM_ - 1);
    int b = i / (CTX_ * DIM_);
    imgfb[i] = (__bf16)(imgf[i] * gate[b * DIM_ + c]);
}

__global__ void embed_kernel(const int* __restrict__ text, const float* __restrict__ temb,
                             const float* __restrict__ pemb, float* __restrict__ x) {
    int i = blockIdx.x * 256 + threadIdx.x;
    if (i >= B_ * N_ * DIM_) return;
    int c = i & (DIM_ - 1);
    int row = i >> 9;
    int n = row & (N_ - 1);
    int tok = text[row];
    x[i] = temb[(size_t)tok * DIM_ + c] + pemb[(size_t)n * DIM_ + c];
}

// wave-per-row layernorm, row = 512 floats, bf16 output
__global__ void ln_kernel(const float* __restrict__ x, const float* __restrict__ g,
                          const float* __restrict__ b, __bf16* __restrict__ o, int rows) {
    int row = blockIdx.x * 4 + (threadIdx.x >> 6);
    if (row >= rows) return;
    int lane = threadIdx.x & 63;
    const float* xr = x + (size_t)row * DIM_ + lane * 8;
    float4 v0 = ((const float4*)xr)[0];
    float4 v1 = ((const float4*)xr)[1];
    float r[8] = {v0.x, v0.y, v0.z, v0.w, v1.x, v1.y, v1.z, v1.w};
    float sum = 0.f, sq = 0.f;
    #pragma unroll
    for (int j = 0; j < 8; ++j) { sum += r[j]; sq += r[j] * r[j]; }
    #pragma unroll
    for (int m = 1; m < 64; m <<= 1) { sum += __shfl_xor(sum, m); sq += __shfl_xor(sq, m); }
    float mean = sum * (1.f / DIM_);
    float var  = sq * (1.f / DIM_) - mean * mean;
    float inv  = rsqrtf(fmaxf(var, 0.f) + 1e-5f);
    const float* gp = g + lane * 8;
    const float* bp = b + lane * 8;
    __bf16* op = o + (size_t)row * DIM_ + lane * 8;
    bf16x8 ov;
    #pragma unroll
    for (int j = 0; j < 8; ++j) ov[j] = (__bf16)((r[j] - mean) * inv * gp[j] + bp[j]);
    *(bf16x8*)op = ov;
}

// causal depthwise conv (4 taps) + SiLU; bf16 in (xzb), bf16 out (xcb)
__global__ void conv_silu_kernel(const __bf16* __restrict__ xzb, const float* __restrict__ cw,
                                 const float* __restrict__ cb, __bf16* __restrict__ xcb) {
    int idx = blockIdx.x * 256 + threadIdx.x;
    if (idx >= B_ * N_ * DIN_ / 4) return;
    int i4 = idx * 4;
    int d = i4 & (DIN_ - 1);
    int row = i4 >> 10;
    int n = row & (N_ - 1);
    int rowb = row - n;
    float4 acc = *(const float4*)(cb + d);
    #pragma unroll
    for (int k = 0; k < 4; ++k) {
        int m = n - 3 + k;
        if (m >= 0) {
            bf16x4 v = *(const bf16x4*)(xzb + (size_t)(rowb + m) * (2 * DIN_) + d);
            acc.x += (float)v[0] * cw[(d + 0) * 4 + k];
            acc.y += (float)v[1] * cw[(d + 1) * 4 + k];
            acc.z += (float)v[2] * cw[(d + 2) * 4 + k];
            acc.w += (float)v[3] * cw[(d + 3) * 4 + k];
        }
    }
    bf16x4 p;
    p[0] = (__bf16)(acc.x / (1.f + __expf(-acc.x)));
    p[1] = (__bf16)(acc.y / (1.f + __expf(-acc.y)));
    p[2] = (__bf16)(acc.z / (1.f + __expf(-acc.z)));
    p[3] = (__bf16)(acc.w / (1.f + __expf(-acc.w)));
    *(bf16x4*)(xcb + i4) = p;
}

__global__ void cvt_bf16_kernel(const float* __restrict__ src, __bf16* __restrict__ dst, int count) {
    int i = (blockIdx.x * 256 + threadIdx.x) * 4;
    if (i >= count) return;
    float4 v = *(const float4*)(src + i);
    bf16x4 p = {(__bf16)v.x, (__bf16)v.y, (__bf16)v.z, (__bf16)v.w};
    *(bf16x4*)(dst + i) = p;
}

// row-sliced convert: dst row i (K=512) <- src row (i/rpl)*1536 + off + (i%rpl)
__global__ void cvt_rows_kernel(const float* __restrict__ src, __bf16* __restrict__ dst,
                                int totalRows, int rpl, int off) {
    int t = blockIdx.x * 256 + threadIdx.x;
    int total = totalRows * (DIM_ / 4);
    if (t >= total) return;
    int i = t / (DIM_ / 4), c4 = (t % (DIM_ / 4)) * 4;
    int l = i / rpl, r = i % rpl;
    const float* s = src + ((size_t)l * 1536 + off + r) * DIM_ + c4;
    float4 v = *(const float4*)s;
    bf16x4 p = {(__bf16)v.x, (__bf16)v.y, (__bf16)v.z, (__bf16)v.w};
    *(bf16x4*)(dst + (size_t)i * DIM_ + c4) = p;
}

// ---------------- fused selective scan v5: 4 d's per block, bf16 activations ----
__global__ __launch_bounds__(256) void scanf_kernel(
    const __bf16* __restrict__ xcb, const float* __restrict__ dbl,
    const __bf16* __restrict__ xzb, const float* __restrict__ dtw,
    const float* __restrict__ dtb, const float* __restrict__ A_log,
    const float* __restrict__ Dsk, __bf16* __restrict__ ybb) {
    __shared__ float sdt[DG_][N_], su[DG_][N_];
    __shared__ float sA[DG_][256], sB[DG_][256];
    int bid = blockIdx.x;
    int nwg = gridDim.x;                       // 2048, % 8 == 0
    int bd = (bid & 7) * (nwg >> 3) + (bid >> 3);   // bijective XCD swizzle
    int dg = bd & (DIN_ / DG_ - 1), b = bd / (DIN_ / DG_);
    int d0 = dg * DG_;
    int tid = threadIdx.x, s = tid & 15, c = tid >> 4;
    {
        int row = b * N_ + tid;
        const float* dp = dbl + row * 64;
        float4 acc = *(const float4*)(dtb + d0);
        #pragma unroll
        for (int k = 0; k < DTR_; k += 4) {
            float4 dv = *(const float4*)(dp + k);
            float4 w0 = *(const float4*)(dtw + (k + 0) * DIN_ + d0);
            float4 w1 = *(const float4*)(dtw + (k + 1) * DIN_ + d0);
            float4 w2 = *(const float4*)(dtw + (k + 2) * DIN_ + d0);
            float4 w3 = *(const float4*)(dtw + (k + 3) * DIN_ + d0);
            acc.x += dv.x * w0.x + dv.y * w1.x + dv.z * w2.x + dv.w * w3.x;
            acc.y += dv.x * w0.y + dv.y * w1.y + dv.z * w2.y + dv.w * w3.y;
            acc.z += dv.x * w0.z + dv.y * w1.z + dv.z * w2.z + dv.w * w3.z;
            acc.w += dv.x * w0.w + dv.y * w1.w + dv.z * w2.w + dv.w * w3.w;
        }
        bf16x4 xcv4 = *(const bf16x4*)(xcb + (size_t)row * DIN_ + d0);
        float av[4] = {acc.x, acc.y, acc.z, acc.w};
        float xv[4] = {(float)xcv4[0], (float)xcv4[1], (float)xcv4[2], (float)xcv4[3]};
        #pragma unroll
        for (int g = 0; g < DG_; ++g) {
            float dt = fmaxf(av[g], 0.f) + __logf(1.f + __expf(-fabsf(av[g])));
            sdt[g][tid] = dt;
            su[g][tid] = dt * xv[g];
        }
    }
    float As4[DG_];
    #pragma unroll
    for (int g = 0; g < DG_; ++g) As4[g] = -__expf(A_log[((d0 + g) << 4) | s]);
    __syncthreads();
    int r0 = c * CLEN_;
    int row0 = b * N_ + r0;
    float a[DG_], hb[DG_];
    #pragma unroll
    for (int g = 0; g < DG_; ++g) { a[g] = 1.f; hb[g] = 0.f; }
    #pragma unroll 2
    for (int n = 0; n < CLEN_; ++n) {
        float Bv = dbl[(row0 + n) * 64 + 32 + s];
        #pragma unroll
        for (int g = 0; g < DG_; ++g) {
            float dA = __expf(sdt[g][r0 + n] * As4[g]);
            hb[g] = hb[g] * dA + su[g][r0 + n] * Bv;
            a[g] *= dA;
        }
    }
    #pragma unroll
    for (int g = 0; g < DG_; ++g) { sA[g][tid] = a[g]; sB[g][tid] = hb[g]; }
    __syncthreads();
    float h[DG_];
    #pragma unroll
    for (int g = 0; g < DG_; ++g) h[g] = 0.f;
    for (int j = 0; j < c; ++j)
        #pragma unroll
        for (int g = 0; g < DG_; ++g)
            h[g] = h[g] * sA[g][j * 16 + s] + sB[g][j * 16 + s];
    float4 Dv4 = *(const float4*)(Dsk + d0);
    float Dv[4] = {Dv4.x, Dv4.y, Dv4.z, Dv4.w};
    #pragma unroll 2
    for (int n = 0; n < CLEN_; ++n) {
        int row = row0 + n;
        float Bv = dbl[row * 64 + 32 + s];
        float Cv = dbl[row * 64 + 48 + s];
        float p[DG_];
        #pragma unroll
        for (int g = 0; g < DG_; ++g) {
            float dA = __expf(sdt[g][r0 + n] * As4[g]);
            h[g] = h[g] * dA + su[g][r0 + n] * Bv;
            p[g] = dpp_red16(h[g] * Cv);
        }
        if (s == 0) {
            bf16x4 xcv4 = *(const bf16x4*)(xcb + (size_t)row * DIN_ + d0);
            bf16x4 zz4  = *(const bf16x4*)(xzb + (size_t)row * (2 * DIN_) + DIN_ + d0);
            bf16x4 yo;
            #pragma unroll
            for (int g = 0; g < DG_; ++g) {
                float xv = (float)xcv4[g];
                float zv = (float)zz4[g];
                float y = (p[g] + xv * Dv[g]) * (zv / (1.f + __expf(-zv)));
                yo[g] = (__bf16)y;
            }
            *(bf16x4*)(ybb + (size_t)row * DIN_ + d0) = yo;
        }
    }
}

// ---------------- weight prep ----------------

__global__ void tconv_kernel(const float* __restrict__ src, __bf16* __restrict__ dst,
                             int K, int N) {
    __shared__ float tile[32][33];
    int n0 = blockIdx.x * 32, k0 = blockIdx.y * 32;
    src += (size_t)blockIdx.z * K * N;
    dst += (size_t)blockIdx.z * K * N;
    int tx = threadIdx.x & 31, ty = threadIdx.x >> 5;
    #pragma unroll
    for (int i = 0; i < 32; i += 8) {
        int k = k0 + ty + i, n = n0 + tx;
        tile[ty + i][tx] = (k < K && n < N) ? src[(size_t)k * N + n] : 0.f;
    }
    __syncthreads();
    #pragma unroll
    for (int i = 0; i < 32; i += 8) {
        int n = n0 + ty + i, k = k0 + tx;
        if (n < N && k < K) dst[(size_t)n * K + k] = (__bf16)tile[tx][ty + i];
    }
}

// ---------------- bf16 MFMA GEMM v3: global_load_lds staging ----------------
// MODE 0: fp32 out (+res). MODE 1: bf16 out. MODE 3: batched-kv epilogue.
// CMAJ: column-major block mapping for N >> M shapes (kv, logits).

template <int BM, int BN, int MODE, bool CMAJ = false>
__global__ __launch_bounds__(256) void mgemm_k(
    const __bf16* __restrict__ A, const __bf16* __restrict__ Bw,
    const float* __restrict__ bias, const float* __restrict__ res,
    void* __restrict__ Cp, void* __restrict__ Cp2,
    int M, int N, int K, int lda, int ldc) {
    constexpr int UA = BM * 4;   // 16B units per 32-K slab tile
    constexpr int UB = BN * 4;
    constexpr int FM = BM / 32, FN = BN / 32;
    __shared__ __align__(16) __bf16 As[2][UA * 8];
    __shared__ __align__(16) __bf16 Bs[2][UB * 8];
    int tid = threadIdx.x;
    int ntx = gridDim.x;
    int nwg = ntx * gridDim.y;
    int bid = blockIdx.y * ntx + blockIdx.x;
    if ((nwg & 7) == 0) bid = (bid & 7) * (nwg >> 3) + (bid >> 3);
    int row0, col0;
    if constexpr (CMAJ) {
        int nty = nwg / ntx;
        row0 = (bid % nty) * BM;
        col0 = (bid / nty) * BN;
    } else {
        row0 = (bid / ntx) * BM;
        col0 = (bid % ntx) * BN;
    }
    int wave = tid >> 6, lane = tid & 63;
    int wm = (wave >> 1) * (BM / 2), wn = (wave & 1) * (BN / 2);
    int fr = lane & 15, fk = lane >> 4;
    f32x4 acc[FM][FN] = {};

    auto stage = [&](int buf, int k0) {
        #pragma unroll
        for (int j = 0; j < (UA + 255) / 256; ++j) {
            int u = j * 256 + tid;
            if ((UA & 255) == 0 || u < UA) {
                int ks = u / BM, r = u % BM;
                gload16(A + (size_t)(row0 + r) * lda + k0 + ks * 8, &As[buf][u * 8]);
            }
        }
        #pragma unroll
        for (int j = 0; j < (UB + 255) / 256; ++j) {
            int u = j * 256 + tid;
            if ((UB & 255) == 0 || u < UB) {
                int ks = u / BN, r = u % BN;
                gload16(Bw + (size_t)(col0 + r) * K + k0 + ks * 8, &Bs[buf][u * 8]);
            }
        }
    };

    stage(0, 0);
    __syncthreads();
    int NK = K >> 5;
    for (int kt = 0; kt < NK; ++kt) {
        int cur = kt & 1;
        if (kt + 1 < NK) stage(cur ^ 1, (kt + 1) << 5);   // loads fly over MFMA phase
        bf16x8 af[FM], bg[FN];
        #pragma unroll
        for (int mf = 0; mf < FM; ++mf)
            af[mf] = *(const bf16x8*)&As[cur][(fk * BM + wm + mf * 16 + fr) * 8];
        #pragma unroll
        for (int nf = 0; nf < FN; ++nf)
            bg[nf] = *(const bf16x8*)&Bs[cur][(fk * BN + wn + nf * 16 + fr) * 8];
        #pragma unroll
        for (int mf = 0; mf < FM; ++mf)
            #pragma unroll
            for (int nf = 0; nf < FN; ++nf)
                acc[mf][nf] = __builtin_amdgcn_mfma_f32_16x16x32_bf16(af[mf], bg[nf], acc[mf][nf], 0, 0, 0);
        __syncthreads();   // drains vmcnt (next tile landed) + protects cur for overwrite
    }
    #pragma unroll
    for (int mf = 0; mf < FM; ++mf) {
        #pragma unroll
        for (int nf = 0; nf < FN; ++nf) {
            int gn = col0 + wn + nf * 16 + fr;
            if (gn >= N) continue;
            float bb = (MODE != 3 && bias) ? bias[gn] : 0.f;
            #pragma unroll
            for (int e = 0; e < 4; ++e) {
                int gm = row0 + wm + mf * 16 + fk * 4 + e;
                if (gm >= M) continue;
                float v = acc[mf][nf][e] + bb;
                if constexpr (MODE == 0) {
                    size_t idx = (size_t)gm * ldc + gn;
                    if (res) v += res[idx];
                    ((float*)Cp)[idx] = v;
                } else if constexpr (MODE == 1) {
                    ((__bf16*)Cp)[(size_t)gm * ldc + gn] = (__bf16)v;
                } else {
                    int l = gn >> 10, j = gn & 1023;
                    float vb = v + res[l * 1536 + 512 + j];  // ainb[l][512+j]
                    if (j < DIM_) {
                        ((__bf16*)Cp)[(size_t)l * (B_ * CTX_) * DIM_ + (size_t)gm * DIM_ + j] = (__bf16)vb;
                    } else {
                        int jj = j - DIM_;
                        int bimg = gm / CTX_, k = gm - bimg * CTX_;
                        ((__bf16*)Cp2)[(((size_t)l * B_ * HEADS_ + bimg * HEADS_ + (jj >> 6)) * HD_ + (jj & 63)) * CTXP_ + k] = (__bf16)vb;
                    }
                }
            }
        }
    }
}

template <int BM, int BN, int MODE = 0, bool CMAJ = false>
static inline void mgemm(const __bf16* A, const __bf16* Bw, const float* bias,
                         const float* res, void* C, void* C2, int M, int N, int K,
                         int lda, int ldc, hipStream_t s) {
    dim3 g((N + BN - 1) / BN, (M + BM - 1) / BM);
    mgemm_k<BM, BN, MODE, CMAJ><<<g, 256, 0, s>>>(A, Bw, bias, res, C, C2, M, N, K, lda, ldc);
}

// ---------------- fused attention ----------------
#define KP_ 72    // K LDS row pad (bf16)
#define PP_ 232   // P LDS row pad (bf16)

__global__ __launch_bounds__(256) void attn_k(
    const __bf16* __restrict__ qb, const __bf16* __restrict__ kbb,
    const __bf16* __restrict__ vbT, __bf16* __restrict__ obb) {
    __shared__ __align__(16) __bf16 Ks[CTXP_ * KP_];
    __shared__ __align__(16) __bf16 Ps[64 * PP_];
    int z = blockIdx.z, b = z >> 3, h = z & 7;
    int tid = threadIdx.x, wave = tid >> 6, lane = tid & 63;
    int fr = lane & 15, fk = lane >> 4;
    int q0 = blockIdx.y * 64;
    #pragma unroll
    for (int i = 0; i < 7; ++i) {
        int idx = i * 256 + tid;
        int r = idx >> 3, cu = (idx & 7) * 8;
        uint4 v = {0u, 0u, 0u, 0u};
        if (r < CTX_) v = *(const uint4*)(kbb + ((size_t)(b * CTX_ + r)) * DIM_ + h * HD_ + cu);
        *(uint4*)&Ks[r * KP_ + cu] = v;
    }
    bf16x8 aq[2];
    {
        int qrow = b * N_ + q0 + wave * 16 + fr;
        #pragma unroll
        for (int t = 0; t < 2; ++t)
            aq[t] = *(const bf16x8*)(qb + (size_t)qrow * DIM_ + h * HD_ + t * 32 + fk * 8);
    }
    __syncthreads();
    f32x4 acc[CTXF_] = {};
    #pragma unroll
    for (int t = 0; t < 2; ++t)
        #pragma unroll
        for (int cb = 0; cb < CTXF_; ++cb) {
            bf16x8 bg = *(const bf16x8*)&Ks[(cb * 16 + fr) * KP_ + t * 32 + fk * 8];
            acc[cb] = __builtin_amdgcn_mfma_f32_16x16x32_bf16(aq[t], bg, acc[cb], 0, 0, 0);
        }
    #pragma unroll
    for (int e = 0; e < 4; ++e) {
        float m = -1e30f;
        #pragma unroll
        for (int cb = 0; cb < CTXF_; ++cb) {
            float sv = acc[cb][e] * 0.125f;
            if (cb * 16 + fr >= CTX_) sv = -1e30f;
            acc[cb][e] = sv;
            m = fmaxf(m, sv);
        }
        m = dpp_max16(m);
        float ssum = 0.f;
        #pragma unroll
        for (int cb = 0; cb < CTXF_; ++cb) {
            float p = __expf(acc[cb][e] - m);
            acc[cb][e] = p;
            ssum += p;
        }
        ssum = dpp_red16(ssum);
        float inv = 1.f / ssum;
        #pragma unroll
        for (int cb = 0; cb < CTXF_; ++cb)
            Ps[(wave * 16 + fk * 4 + e) * PP_ + cb * 16 + fr] = (__bf16)(acc[cb][e] * inv);
        Ps[(wave * 16 + fk * 4 + e) * PP_ + 208 + fr] = (__bf16)0.f;
    }
    __syncthreads();
    f32x4 acc2[4] = {};
    const __bf16* vB = vbT + (size_t)z * HD_ * CTXP_;
    #pragma unroll
    for (int sl = 0; sl < 7; ++sl) {
        bf16x8 ap = *(const bf16x8*)&Ps[(wave * 16 + fr) * PP_ + sl * 32 + fk * 8];
        #pragma unroll
        for (int nf = 0; nf < 4; ++nf) {
            bf16x8 bv = *(const bf16x8*)(vB + (size_t)(nf * 16 + fr) * CTXP_ + sl * 32 + fk * 8);
            acc2[nf] = __builtin_amdgcn_mfma_f32_16x16x32_bf16(ap, bv, acc2[nf], 0, 0, 0);
        }
    }
    #pragma unroll
    for (int nf = 0; nf < 4; ++nf)
        #pragma unroll
        for (int e = 0; e < 4; ++e) {
            int gm = b * N_ + q0 + wave * 16 + fk * 4 + e;
            obb[(size_t)gm * DIM_ + h * HD_ + nf * 16 + fr] = (__bf16)acc2[nf][e];
        }
}

// ---------------- host side ----------------

extern "C" void kernel_launch(void* const* d_in, const int* in_sizes, int n_in,
                              void* d_out, int out_size, void* d_ws, size_t ws_size,
                              hipStream_t stream) {
    const int*   text   = (const int*)d_in[0];
    const float* images = (const float*)d_in[1];
    const float* alphap = (const float*)d_in[2];
    const float* dgam   = (const float*)d_in[3];
    const float* dbeta  = (const float*)d_in[4];
    const float* imgW   = (const float*)d_in[5];
    const float* imgb   = (const float*)d_in[6];
    const float* g1W    = (const float*)d_in[7];
    const float* g1b    = (const float*)d_in[8];
    const float* g2W    = (const float*)d_in[9];
    const float* g2b    = (const float*)d_in[10];
    const float* temb   = (const float*)d_in[11];
    const float* pemb   = (const float*)d_in[12];
    const float* ln1g   = (const float*)d_in[13];
    const float* ln1b   = (const float*)d_in[14];
    const float* inW    = (const float*)d_in[15];
    const float* convW  = (const float*)d_in[16];
    const float* convb  = (const float*)d_in[17];
    const float* xpW    = (const float*)d_in[18];
    const float* dtW    = (const float*)d_in[19];
    const float* dtb    = (const float*)d_in[20];
    const float* Alog   = (const float*)d_in[21];
    const float* Dsk    = (const float*)d_in[22];
    const float* outW   = (const float*)d_in[23];
    const float* ln2g   = (const float*)d_in[24];
    const float* ln2b   = (const float*)d_in[25];
    const float* ainW   = (const float*)d_in[26];
    const float* ainb   = (const float*)d_in[27];
    const float* aoutW  = (const float*)d_in[28];
    const float* aoutb  = (const float*)d_in[29];
    const float* fng    = (const float*)d_in[30];
    const float* fnb    = (const float*)d_in[31];
    const float* lgW    = (const float*)d_in[32];
    const float* lgb    = (const float*)d_in[33];
    float* out = (float*)d_out;

    float* w = (float*)d_ws;
    float* imgd   = w; w += (size_t)B_ * CTX_ * IMGD_;   // bf16 dyt out (aliased)
    float* imgf   = w; w += (size_t)B_ * CTX_ * DIM_;
    float* pooled = w; w += B_ * DIM_;
    float* g1     = w; w += B_ * 128;
    float* gate   = w; w += B_ * DIM_;
    float* x      = w; w += (size_t)B_ * N_ * DIM_;
    float* xn     = w; w += (size_t)B_ * N_ * DIM_;      // bf16 ln out (aliased)
    float* dblb   = w; w += (size_t)B_ * N_ * 64;
    // bf16 buffers
    __bf16* xzb   = (__bf16*)w; w += (size_t)B_ * N_ * 2 * DIN_ / 2;
    __bf16* xcb   = (__bf16*)w; w += (size_t)B_ * N_ * DIN_ / 2;
    __bf16* imgfb = (__bf16*)w; w += (size_t)B_ * CTX_ * DIM_ / 2;
    __bf16* ybb   = (__bf16*)w; w += (size_t)B_ * N_ * DIN_ / 2;
    __bf16* qb    = (__bf16*)w; w += (size_t)B_ * N_ * DIM_ / 2;
    __bf16* kbb   = (__bf16*)w; w += (size_t)DEPTH_ * B_ * CTX_ * DIM_ / 2;
    __bf16* vbT   = (__bf16*)w; w += (size_t)DEPTH_ * B_ * HEADS_ * HD_ * CTXP_ / 2;
    __bf16* obb   = (__bf16*)w; w += (size_t)B_ * N_ * DIM_ / 2;
    __bf16* lgT   = (__bf16*)w; w += (size_t)10000 * DIM_ / 2;
    // bf16 weights
    __bf16* inpT  = (__bf16*)w; w += (size_t)DEPTH_ * 2 * DIN_ * DIM_ / 2;
    __bf16* outpT = (__bf16*)w; w += (size_t)DEPTH_ * DIM_ * DIN_ / 2;
    __bf16* qWB   = (__bf16*)w; w += (size_t)DEPTH_ * DIM_ * DIM_ / 2;
    __bf16* kvWB  = (__bf16*)w; w += (size_t)DEPTH_ * 2 * DIM_ * DIM_ / 2;
    __bf16* aoutB = (__bf16*)w; w += (size_t)DEPTH_ * DIM_ * DIM_ / 2;
    __bf16* imgWT = (__bf16*)w; w += (size_t)DIM_ * IMGD_ / 2;
    __bf16* xpWT  = (__bf16*)w; w += (size_t)DEPTH_ * 64 * DIN_ / 2;
    __bf16* imgdb = (__bf16*)imgd;
    __bf16* xnb   = (__bf16*)xn;

    const int TOKENS = B_ * N_;
    const int IMGT   = B_ * CTX_;

    // zero all layers' vbT pad columns once
    hipMemsetAsync(vbT, 0, (size_t)DEPTH_ * B_ * HEADS_ * HD_ * CTXP_ * sizeof(__bf16), stream);

    // ---- weight prep ----
    tconv_kernel<<<dim3(2 * DIN_ / 32, DIM_ / 32, DEPTH_), 256, 0, stream>>>(inW,  inpT,  DIM_, 2 * DIN_);
    tconv_kernel<<<dim3(DIM_ / 32, DIN_ / 32, DEPTH_),     256, 0, stream>>>(outW, outpT, DIN_, DIM_);
    tconv_kernel<<<dim3(DIM_ / 32, IMGD_ / 32, 1),         256, 0, stream>>>(imgW, imgWT, IMGD_, DIM_);
    tconv_kernel<<<dim3(64 / 32, DIN_ / 32, DEPTH_),       256, 0, stream>>>(xpW,  xpWT,  DIN_, 64);
    tconv_kernel<<<dim3((10000 + 31) / 32, DIM_ / 32, 1),  256, 0, stream>>>(lgW, lgT, DIM_, 10000);
    cvt_rows_kernel<<<(DEPTH_ * DIM_ * (DIM_ / 4) + 255) / 256, 256, 0, stream>>>(
        ainW, qWB, DEPTH_ * DIM_, DIM_, 0);
    cvt_rows_kernel<<<(DEPTH_ * 2 * DIM_ * (DIM_ / 4) + 255) / 256, 256, 0, stream>>>(
        ainW, kvWB, DEPTH_ * 2 * DIM_, 2 * DIM_, DIM_);
    cvt_bf16_kernel<<<(DEPTH_ * DIM_ * DIM_ / 4 + 255) / 256, 256, 0, stream>>>(aoutW, aoutB, DEPTH_ * DIM_ * DIM_);

    // ---- image path ----
    {
        int total = B_ * CTX_ * IMGD_;
        dyt_kernel<<<(total + 255) / 256, 256, 0, stream>>>(images, alphap, dgam, dbeta, imgdb, total);
        mgemm<32, 64>(imgdb, imgWT, imgb, nullptr, imgf, nullptr, IMGT, DIM_, IMGD_, IMGD_, DIM_, stream);
        pool_kernel<<<(B_ * DIM_ + 255) / 256, 256, 0, stream>>>(imgf, pooled);
        gate1_kernel<<<(B_ * 128 + 255) / 256, 256, 0, stream>>>(pooled, g1W, g1b, g1);
        gate2_kernel<<<(B_ * DIM_ + 255) / 256, 256, 0, stream>>>(g1, g2W, g2b, gate);
        scale_kernel<<<(B_ * CTX_ * DIM_ + 255) / 256, 256, 0, stream>>>(imgf, gate, imgfb);
    }
    embed_kernel<<<(TOKENS * DIM_ + 255) / 256, 256, 0, stream>>>(text, temb, pemb, x);

    // ---- ALL layers' K/V projections in ONE batched GEMM (col-major slabs) ----
    mgemm<64, 128, 3, true>(imgfb, kvWB, nullptr, ainb, kbb, vbT,
                            IMGT, DEPTH_ * 2 * DIM_, DIM_, DIM_, 0, stream);

    for (int l = 0; l < DEPTH_; ++l) {
        const __bf16* inpT_l  = inpT  + (size_t)l * 2 * DIN_ * DIM_;
        const __bf16* outpT_l = outpT + (size_t)l * DIM_ * DIN_;
        const __bf16* qWB_l   = qWB   + (size_t)l * DIM_ * DIM_;
        const __bf16* aoutB_l = aoutB + (size_t)l * DIM_ * DIM_;
        const __bf16* xpWT_l  = xpWT  + (size_t)l * 64 * DIN_;
        const __bf16* kbb_l   = kbb   + (size_t)l * IMGT * DIM_;
        const __bf16* vbT_l   = vbT   + (size_t)l * B_ * HEADS_ * HD_ * CTXP_;
        const float* cw    = convW + (size_t)l * DIN_ * 4;
        const float* cb    = convb + (size_t)l * DIN_;
        const float* dtw   = dtW  + (size_t)l * DTR_ * DIN_;
        const float* dtbi  = dtb  + (size_t)l * DIN_;
        const float* alog  = Alog + (size_t)l * DIN_ * DST_;
        const float* dsk   = Dsk  + (size_t)l * DIN_;
        const float* ab    = ainb + (size_t)l * 3 * DIM_;
        const float* aob   = aoutb + (size_t)l * DIM_;

        // mamba block (bf16 activations end-to-end)
        ln_kernel<<<TOKENS / 4, 256, 0, stream>>>(x, ln1g + l * DIM_, ln1b + l * DIM_, xnb, TOKENS);
        mgemm<64, 128, 1>(xnb, inpT_l, nullptr, nullptr, xzb, nullptr, TOKENS, 2 * DIN_, DIM_, DIM_, 2 * DIN_, stream);
        conv_silu_kernel<<<(TOKENS * DIN_ / 4 + 255) / 256, 256, 0, stream>>>(xzb, cw, cb, xcb);
        mgemm<32, 64>(xcb, xpWT_l, nullptr, nullptr, dblb, nullptr, TOKENS, 64, DIN_, DIN_, 64, stream);
        scanf_kernel<<<B_ * DIN_ / DG_, 256, 0, stream>>>(xcb, dblb, xzb, dtw, dtbi, alog, dsk, ybb);
        mgemm<32, 64>(ybb, outpT_l, nullptr, x, x, nullptr, TOKENS, DIM_, DIN_, DIN_, DIM_, stream);

        // cross-attention block
        ln_kernel<<<TOKENS / 4, 256, 0, stream>>>(x, ln2g + l * DIM_, ln2b + l * DIM_, xnb, TOKENS);
        mgemm<32, 64, 1>(xnb, qWB_l, ab, nullptr, qb, nullptr, TOKENS, DIM_, DIM_, DIM_, DIM_, stream);
        attn_k<<<dim3(1, 4, B_ * HEADS_), 256, 0, stream>>>(qb, kbb_l, vbT_l, obb);
        mgemm<32, 64>(obb, aoutB_l, aob, x, x, nullptr, TOKENS, DIM_, DIM_, DIM_, DIM_, stream);
    }

    // final LN + logits (128x128 col-major slabs — measured best)
    ln_kernel<<<TOKENS / 4, 256, 0, stream>>>(x, fng, fnb, xnb, TOKENS);
    mgemm<128, 128, 0, true>(xnb, lgT, lgb, nullptr, out, nullptr, TOKENS, 10000, DIM_, DIM_, 10000, stream);
}

// Round 18
// 1133.415 us; speedup vs baseline: 1.0618x; 1.0507x over previous
//
#include <hip/hip_runtime.h>
#include <hip/hip_bf16.h>
#include <stdint.h>

#define B_    8
#define N_    256
#define CTX_  196
#define CTXP_ 224   // ctx padded to multiple of 32 for PV K-loop
#define CTXF_ 13    // score col frags (13*16 = 208 >= 196)
#define IMGD_ 1024
#define DIM_  512
#define DEPTH_ 6
#define DIN_  1024
#define DTR_  32
#define DST_  16
#define HEADS_ 8
#define HD_   64
#define NCHUNK_ 16
#define CLEN_   16   // N_/NCHUNK_
#define DG_     4    // d's per scan block

typedef __bf16 bf16x8 __attribute__((ext_vector_type(8)));
typedef __bf16 bf16x4 __attribute__((ext_vector_type(4)));
typedef float  f32x4  __attribute__((ext_vector_type(4)));

// 16-lane sum via DPP butterfly; all 16 lanes get total
__device__ __forceinline__ float dpp_red16(float v) {
    int y;
    y = __builtin_amdgcn_update_dpp(0, __float_as_int(v), 0xB1, 0xF, 0xF, true);
    v += __int_as_float(y);
    y = __builtin_amdgcn_update_dpp(0, __float_as_int(v), 0x4E, 0xF, 0xF, true);
    v += __int_as_float(y);
    y = __builtin_amdgcn_update_dpp(0, __float_as_int(v), 0x141, 0xF, 0xF, true);
    v += __int_as_float(y);
    y = __builtin_amdgcn_update_dpp(0, __float_as_int(v), 0x140, 0xF, 0xF, true);
    v += __int_as_float(y);
    return v;
}
__device__ __forceinline__ float dpp_max16(float v) {
    int y;
    y = __builtin_amdgcn_update_dpp(0, __float_as_int(v), 0xB1, 0xF, 0xF, true);
    v = fmaxf(v, __int_as_float(y));
    y = __builtin_amdgcn_update_dpp(0, __float_as_int(v), 0x4E, 0xF, 0xF, true);
    v = fmaxf(v, __int_as_float(y));
    y = __builtin_amdgcn_update_dpp(0, __float_as_int(v), 0x141, 0xF, 0xF, true);
    v = fmaxf(v, __int_as_float(y));
    y = __builtin_amdgcn_update_dpp(0, __float_as_int(v), 0x140, 0xF, 0xF, true);
    v = fmaxf(v, __int_as_float(y));
    return v;
}

// async global->LDS 16B (direct-to-LDS DMA; no VGPR round trip)
__device__ __forceinline__ void gload16(const void* g, void* l) {
    __builtin_amdgcn_global_load_lds(
        (const __attribute__((address_space(1))) uint32_t*)g,
        (__attribute__((address_space(3))) uint32_t*)l, 16, 0, 0);
}

// ---------------- elementwise / small kernels ----------------

__global__ void dyt_kernel(const float* __restrict__ img, const float* __restrict__ alpha_p,
                           const float* __restrict__ gamma, const float* __restrict__ beta,
                           __bf16* __restrict__ out, int total) {
    int i = blockIdx.x * 256 + threadIdx.x;
    if (i >= total) return;
    float a = alpha_p[0];
    int c = i & (IMGD_ - 1);
    out[i] = (__bf16)(gamma[c] * tanhf(a * img[i]) + beta[c]);
}

__global__ void pool_kernel(const float* __restrict__ imgf, float* __restrict__ pooled) {
    int i = blockIdx.x * 256 + threadIdx.x;
    if (i >= B_ * DIM_) return;
    int b = i >> 9, c = i & (DIM_ - 1);
    const float* p = imgf + (size_t)b * CTX_ * DIM_ + c;
    float s = 0.f;
    for (int t = 0; t < CTX_; ++t) s += p[t * DIM_];
    pooled[i] = s * (1.f / CTX_);
}

__global__ void gate1_kernel(const float* __restrict__ pooled, const float* __restrict__ W,
                             const float* __restrict__ bias, float* __restrict__ g1) {
    int i = blockIdx.x * 256 + threadIdx.x;
    if (i >= B_ * 128) return;
    int b = i >> 7, j = i & 127;
    const float* p = pooled + b * DIM_;
    float s = bias[j];
    for (int c = 0; c < DIM_; ++c) s += p[c] * W[c * 128 + j];
    g1[i] = 0.5f * s * (1.f + erff(s * 0.70710678118654752f));
}

__global__ void gate2_kernel(const float* __restrict__ g1, const float* __restrict__ W,
                             const float* __restrict__ bias, float* __restrict__ gate) {
    int i = blockIdx.x * 256 + threadIdx.x;
    if (i >= B_ * DIM_) return;
    int b = i >> 9, c = i & (DIM_ - 1);
    const float* p = g1 + b * 128;
    float s = bias[c];
    for (int j = 0; j < 128; ++j) s += p[j] * W[j * DIM_ + c];
    gate[i] = 1.f / (1.f + __expf(-s));
}

__global__ void scale_kernel(const float* __restrict__ imgf, const float* __restrict__ gate,
                             __bf16* __restrict__ imgfb) {
    int i = blockIdx.x * 256 + threadIdx.x;
    if (i >= B_ * CTX_ * DIM_) return;
    int c = i & (DIM_ - 1);
    int b = i / (CTX_ * DIM_);
    imgfb[i] = (__bf16)(imgf[i] * gate[b * DIM_ + c]);
}

__global__ void embed_kernel(const int* __restrict__ text, const float* __restrict__ temb,
                             const float* __restrict__ pemb, float* __restrict__ x) {
    int i = blockIdx.x * 256 + threadIdx.x;
    if (i >= B_ * N_ * DIM_) return;
    int c = i & (DIM_ - 1);
    int row = i >> 9;
    int n = row & (N_ - 1);
    int tok = text[row];
    x[i] = temb[(size_t)tok * DIM_ + c] + pemb[(size_t)n * DIM_ + c];
}

// wave-per-row layernorm, row = 512 floats, bf16 output
__global__ void ln_kernel(const float* __restrict__ x, const float* __restrict__ g,
                          const float* __restrict__ b, __bf16* __restrict__ o, int rows) {
    int row = blockIdx.x * 4 + (threadIdx.x >> 6);
    if (row >= rows) return;
    int lane = threadIdx.x & 63;
    const float* xr = x + (size_t)row * DIM_ + lane * 8;
    float4 v0 = ((const float4*)xr)[0];
    float4 v1 = ((const float4*)xr)[1];
    float r[8] = {v0.x, v0.y, v0.z, v0.w, v1.x, v1.y, v1.z, v1.w};
    float sum = 0.f, sq = 0.f;
    #pragma unroll
    for (int j = 0; j < 8; ++j) { sum += r[j]; sq += r[j] * r[j]; }
    #pragma unroll
    for (int m = 1; m < 64; m <<= 1) { sum += __shfl_xor(sum, m); sq += __shfl_xor(sq, m); }
    float mean = sum * (1.f / DIM_);
    float var  = sq * (1.f / DIM_) - mean * mean;
    float inv  = rsqrtf(fmaxf(var, 0.f) + 1e-5f);
    const float* gp = g + lane * 8;
    const float* bp = b + lane * 8;
    __bf16* op = o + (size_t)row * DIM_ + lane * 8;
    bf16x8 ov;
    #pragma unroll
    for (int j = 0; j < 8; ++j) ov[j] = (__bf16)((r[j] - mean) * inv * gp[j] + bp[j]);
    *(bf16x8*)op = ov;
}

// causal depthwise conv (4 taps) + SiLU; bf16 in (xzb), bf16 out (xcb)
__global__ void conv_silu_kernel(const __bf16* __restrict__ xzb, const float* __restrict__ cw,
                                 const float* __restrict__ cb, __bf16* __restrict__ xcb) {
    int idx = blockIdx.x * 256 + threadIdx.x;
    if (idx >= B_ * N_ * DIN_ / 4) return;
    int i4 = idx * 4;
    int d = i4 & (DIN_ - 1);
    int row = i4 >> 10;
    int n = row & (N_ - 1);
    int rowb = row - n;
    float4 acc = *(const float4*)(cb + d);
    #pragma unroll
    for (int k = 0; k < 4; ++k) {
        int m = n - 3 + k;
        if (m >= 0) {
            bf16x4 v = *(const bf16x4*)(xzb + (size_t)(rowb + m) * (2 * DIN_) + d);
            acc.x += (float)v[0] * cw[(d + 0) * 4 + k];
            acc.y += (float)v[1] * cw[(d + 1) * 4 + k];
            acc.z += (float)v[2] * cw[(d + 2) * 4 + k];
            acc.w += (float)v[3] * cw[(d + 3) * 4 + k];
        }
    }
    bf16x4 p;
    p[0] = (__bf16)(acc.x / (1.f + __expf(-acc.x)));
    p[1] = (__bf16)(acc.y / (1.f + __expf(-acc.y)));
    p[2] = (__bf16)(acc.z / (1.f + __expf(-acc.z)));
    p[3] = (__bf16)(acc.w / (1.f + __expf(-acc.w)));
    *(bf16x4*)(xcb + i4) = p;
}

__global__ void cvt_bf16_kernel(const float* __restrict__ src, __bf16* __restrict__ dst, int count) {
    int i = (blockIdx.x * 256 + threadIdx.x) * 4;
    if (i >= count) return;
    float4 v = *(const float4*)(src + i);
    bf16x4 p = {(__bf16)v.x, (__bf16)v.y, (__bf16)v.z, (__bf16)v.w};
    *(bf16x4*)(dst + i) = p;
}

// row-sliced convert: dst row i (K=512) <- src row (i/rpl)*1536 + off + (i%rpl)
__global__ void cvt_rows_kernel(const float* __restrict__ src, __bf16* __restrict__ dst,
                                int totalRows, int rpl, int off) {
    int t = blockIdx.x * 256 + threadIdx.x;
    int total = totalRows * (DIM_ / 4);
    if (t >= total) return;
    int i = t / (DIM_ / 4), c4 = (t % (DIM_ / 4)) * 4;
    int l = i / rpl, r = i % rpl;
    const float* s = src + ((size_t)l * 1536 + off + r) * DIM_ + c4;
    float4 v = *(const float4*)s;
    bf16x4 p = {(__bf16)v.x, (__bf16)v.y, (__bf16)v.z, (__bf16)v.w};
    *(bf16x4*)(dst + (size_t)i * DIM_ + c4) = p;
}

// ---------------- fused selective scan v5: 4 d's per block, bf16 activations ----
__global__ __launch_bounds__(256) void scanf_kernel(
    const __bf16* __restrict__ xcb, const float* __restrict__ dbl,
    const __bf16* __restrict__ xzb, const float* __restrict__ dtw,
    const float* __restrict__ dtb, const float* __restrict__ A_log,
    const float* __restrict__ Dsk, __bf16* __restrict__ ybb) {
    __shared__ float sdt[DG_][N_], su[DG_][N_];
    __shared__ float sA[DG_][256], sB[DG_][256];
    int bid = blockIdx.x;
    int nwg = gridDim.x;                       // 2048, % 8 == 0
    int bd = (bid & 7) * (nwg >> 3) + (bid >> 3);   // bijective XCD swizzle
    int dg = bd & (DIN_ / DG_ - 1), b = bd / (DIN_ / DG_);
    int d0 = dg * DG_;
    int tid = threadIdx.x, s = tid & 15, c = tid >> 4;
    {
        int row = b * N_ + tid;
        const float* dp = dbl + row * 64;
        float4 acc = *(const float4*)(dtb + d0);
        #pragma unroll
        for (int k = 0; k < DTR_; k += 4) {
            float4 dv = *(const float4*)(dp + k);
            float4 w0 = *(const float4*)(dtw + (k + 0) * DIN_ + d0);
            float4 w1 = *(const float4*)(dtw + (k + 1) * DIN_ + d0);
            float4 w2 = *(const float4*)(dtw + (k + 2) * DIN_ + d0);
            float4 w3 = *(const float4*)(dtw + (k + 3) * DIN_ + d0);
            acc.x += dv.x * w0.x + dv.y * w1.x + dv.z * w2.x + dv.w * w3.x;
            acc.y += dv.x * w0.y + dv.y * w1.y + dv.z * w2.y + dv.w * w3.y;
            acc.z += dv.x * w0.z + dv.y * w1.z + dv.z * w2.z + dv.w * w3.z;
            acc.w += dv.x * w0.w + dv.y * w1.w + dv.z * w2.w + dv.w * w3.w;
        }
        bf16x4 xcv4 = *(const bf16x4*)(xcb + (size_t)row * DIN_ + d0);
        float av[4] = {acc.x, acc.y, acc.z, acc.w};
        float xv[4] = {(float)xcv4[0], (float)xcv4[1], (float)xcv4[2], (float)xcv4[3]};
        #pragma unroll
        for (int g = 0; g < DG_; ++g) {
            float dt = fmaxf(av[g], 0.f) + __logf(1.f + __expf(-fabsf(av[g])));
            sdt[g][tid] = dt;
            su[g][tid] = dt * xv[g];
        }
    }
    float As4[DG_];
    #pragma unroll
    for (int g = 0; g < DG_; ++g) As4[g] = -__expf(A_log[((d0 + g) << 4) | s]);
    __syncthreads();
    int r0 = c * CLEN_;
    int row0 = b * N_ + r0;
    float a[DG_], hb[DG_];
    #pragma unroll
    for (int g = 0; g < DG_; ++g) { a[g] = 1.f; hb[g] = 0.f; }
    #pragma unroll 2
    for (int n = 0; n < CLEN_; ++n) {
        float Bv = dbl[(row0 + n) * 64 + 32 + s];
        #pragma unroll
        for (int g = 0; g < DG_; ++g) {
            float dA = __expf(sdt[g][r0 + n] * As4[g]);
            hb[g] = hb[g] * dA + su[g][r0 + n] * Bv;
            a[g] *= dA;
        }
    }
    #pragma unroll
    for (int g = 0; g < DG_; ++g) { sA[g][tid] = a[g]; sB[g][tid] = hb[g]; }
    __syncthreads();
    float h[DG_];
    #pragma unroll
    for (int g = 0; g < DG_; ++g) h[g] = 0.f;
    for (int j = 0; j < c; ++j)
        #pragma unroll
        for (int g = 0; g < DG_; ++g)
            h[g] = h[g] * sA[g][j * 16 + s] + sB[g][j * 16 + s];
    float4 Dv4 = *(const float4*)(Dsk + d0);
    float Dv[4] = {Dv4.x, Dv4.y, Dv4.z, Dv4.w};
    #pragma unroll 2
    for (int n = 0; n < CLEN_; ++n) {
        int row = row0 + n;
        float Bv = dbl[row * 64 + 32 + s];
        float Cv = dbl[row * 64 + 48 + s];
        float p[DG_];
        #pragma unroll
        for (int g = 0; g < DG_; ++g) {
            float dA = __expf(sdt[g][r0 + n] * As4[g]);
            h[g] = h[g] * dA + su[g][r0 + n] * Bv;
            p[g] = dpp_red16(h[g] * Cv);
        }
        if (s == 0) {
            bf16x4 xcv4 = *(const bf16x4*)(xcb + (size_t)row * DIN_ + d0);
            bf16x4 zz4  = *(const bf16x4*)(xzb + (size_t)row * (2 * DIN_) + DIN_ + d0);
            bf16x4 yo;
            #pragma unroll
            for (int g = 0; g < DG_; ++g) {
                float xv = (float)xcv4[g];
                float zv = (float)zz4[g];
                float y = (p[g] + xv * Dv[g]) * (zv / (1.f + __expf(-zv)));
                yo[g] = (__bf16)y;
            }
            *(bf16x4*)(ybb + (size_t)row * DIN_ + d0) = yo;
        }
    }
}

// ---------------- weight prep ----------------

__global__ void tconv_kernel(const float* __restrict__ src, __bf16* __restrict__ dst,
                             int K, int N) {
    __shared__ float tile[32][33];
    int n0 = blockIdx.x * 32, k0 = blockIdx.y * 32;
    src += (size_t)blockIdx.z * K * N;
    dst += (size_t)blockIdx.z * K * N;
    int tx = threadIdx.x & 31, ty = threadIdx.x >> 5;
    #pragma unroll
    for (int i = 0; i < 32; i += 8) {
        int k = k0 + ty + i, n = n0 + tx;
        tile[ty + i][tx] = (k < K && n < N) ? src[(size_t)k * N + n] : 0.f;
    }
    __syncthreads();
    #pragma unroll
    for (int i = 0; i < 32; i += 8) {
        int n = n0 + ty + i, k = k0 + tx;
        if (n < N && k < K) dst[(size_t)n * K + k] = (__bf16)tile[tx][ty + i];
    }
}

// ---------------- bf16 MFMA GEMM v3: global_load_lds staging ----------------
// MODE 0: fp32 out (+res) with LDS-transposed float4 epilogue (wave writes
//         1 KB contiguous per store burst — streams the fp32 output drain).
// MODE 1: bf16 out. MODE 3: batched-kv epilogue.
// CMAJ: column-major block mapping for N >> M shapes (kv, logits).

template <int BM, int BN, int MODE, bool CMAJ = false>
__global__ __launch_bounds__(256) void mgemm_k(
    const __bf16* __restrict__ A, const __bf16* __restrict__ Bw,
    const float* __restrict__ bias, const float* __restrict__ res,
    void* __restrict__ Cp, void* __restrict__ Cp2,
    int M, int N, int K, int lda, int ldc) {
    constexpr int UA = BM * 4;   // 16B units per 32-K slab tile
    constexpr int UB = BN * 4;
    constexpr int FM = BM / 32, FN = BN / 32;
    constexpr int STAGE_B = (UA + UB) * 32;               //両 double-buffers
    constexpr int CS_B    = (MODE == 0) ? BM * BN * 4 : 0; // fp32 C tile overlay
    constexpr int SMEM_B  = STAGE_B > CS_B ? STAGE_B : CS_B;
    __shared__ __align__(16) char smem[SMEM_B];
    __bf16* As = (__bf16*)smem;                 // [2][UA*8]
    __bf16* Bs = (__bf16*)(smem + (size_t)UA * 32);  // [2][UB*8]
    int tid = threadIdx.x;
    int ntx = gridDim.x;
    int nwg = ntx * gridDim.y;
    int bid = blockIdx.y * ntx + blockIdx.x;
    if ((nwg & 7) == 0) bid = (bid & 7) * (nwg >> 3) + (bid >> 3);
    int row0, col0;
    if constexpr (CMAJ) {
        int nty = nwg / ntx;
        row0 = (bid % nty) * BM;
        col0 = (bid / nty) * BN;
    } else {
        row0 = (bid / ntx) * BM;
        col0 = (bid % ntx) * BN;
    }
    int wave = tid >> 6, lane = tid & 63;
    int wm = (wave >> 1) * (BM / 2), wn = (wave & 1) * (BN / 2);
    int fr = lane & 15, fk = lane >> 4;
    f32x4 acc[FM][FN] = {};

    auto stage = [&](int buf, int k0) {
        #pragma unroll
        for (int j = 0; j < (UA + 255) / 256; ++j) {
            int u = j * 256 + tid;
            if ((UA & 255) == 0 || u < UA) {
                int ks = u / BM, r = u % BM;
                gload16(A + (size_t)(row0 + r) * lda + k0 + ks * 8, &As[((size_t)buf * UA + u) * 8]);
            }
        }
        #pragma unroll
        for (int j = 0; j < (UB + 255) / 256; ++j) {
            int u = j * 256 + tid;
            if ((UB & 255) == 0 || u < UB) {
                int ks = u / BN, r = u % BN;
                gload16(Bw + (size_t)(col0 + r) * K + k0 + ks * 8, &Bs[((size_t)buf * UB + u) * 8]);
            }
        }
    };

    stage(0, 0);
    __syncthreads();
    int NK = K >> 5;
    for (int kt = 0; kt < NK; ++kt) {
        int cur = kt & 1;
        if (kt + 1 < NK) stage(cur ^ 1, (kt + 1) << 5);   // loads fly over MFMA phase
        bf16x8 af[FM], bg[FN];
        #pragma unroll
        for (int mf = 0; mf < FM; ++mf)
            af[mf] = *(const bf16x8*)&As[((size_t)cur * UA + fk * BM + wm + mf * 16 + fr) * 8];
        #pragma unroll
        for (int nf = 0; nf < FN; ++nf)
            bg[nf] = *(const bf16x8*)&Bs[((size_t)cur * UB + fk * BN + wn + nf * 16 + fr) * 8];
        #pragma unroll
        for (int mf = 0; mf < FM; ++mf)
            #pragma unroll
            for (int nf = 0; nf < FN; ++nf)
                acc[mf][nf] = __builtin_amdgcn_mfma_f32_16x16x32_bf16(af[mf], bg[nf], acc[mf][nf], 0, 0, 0);
        __syncthreads();   // drains vmcnt (next tile landed) + protects cur for overwrite
    }
    if constexpr (MODE == 0) {
        // LDS-transposed epilogue: acc -> Cs (row-major fp32), then linear
        // float4 copy-out with bias/res fused (coalesced 1 KB/wave bursts).
        float* Cs = (float*)smem;
        #pragma unroll
        for (int mf = 0; mf < FM; ++mf)
            #pragma unroll
            for (int nf = 0; nf < FN; ++nf)
                #pragma unroll
                for (int e = 0; e < 4; ++e)
                    Cs[(wm + mf * 16 + fk * 4 + e) * BN + wn + nf * 16 + fr] = acc[mf][nf][e];
        __syncthreads();
        for (int u = tid; u < BM * BN / 4; u += 256) {
            int r = u / (BN / 4), c4 = (u % (BN / 4)) * 4;
            int gm = row0 + r, gn = col0 + c4;
            if (gm >= M || gn >= N) continue;
            f32x4 v = *(const f32x4*)&Cs[r * BN + c4];
            if (bias) {
                f32x4 bv = *(const f32x4*)(bias + gn);
                v += bv;
            }
            size_t idx = (size_t)gm * ldc + gn;
            if (res) {
                f32x4 rv = *(const f32x4*)(res + idx);
                v += rv;
            }
            *(f32x4*)((float*)Cp + idx) = v;
        }
    } else {
        #pragma unroll
        for (int mf = 0; mf < FM; ++mf) {
            #pragma unroll
            for (int nf = 0; nf < FN; ++nf) {
                int gn = col0 + wn + nf * 16 + fr;
                if (gn >= N) continue;
                float bb = (MODE != 3 && bias) ? bias[gn] : 0.f;
                #pragma unroll
                for (int e = 0; e < 4; ++e) {
                    int gm = row0 + wm + mf * 16 + fk * 4 + e;
                    if (gm >= M) continue;
                    float v = acc[mf][nf][e] + bb;
                    if constexpr (MODE == 1) {
                        ((__bf16*)Cp)[(size_t)gm * ldc + gn] = (__bf16)v;
                    } else {
                        int l = gn >> 10, j = gn & 1023;
                        float vb = v + res[l * 1536 + 512 + j];  // ainb[l][512+j]
                        if (j < DIM_) {
                            ((__bf16*)Cp)[(size_t)l * (B_ * CTX_) * DIM_ + (size_t)gm * DIM_ + j] = (__bf16)vb;
                        } else {
                            int jj = j - DIM_;
                            int bimg = gm / CTX_, k = gm - bimg * CTX_;
                            ((__bf16*)Cp2)[(((size_t)l * B_ * HEADS_ + bimg * HEADS_ + (jj >> 6)) * HD_ + (jj & 63)) * CTXP_ + k] = (__bf16)vb;
                        }
                    }
                }
            }
        }
    }
}

template <int BM, int BN, int MODE = 0, bool CMAJ = false>
static inline void mgemm(const __bf16* A, const __bf16* Bw, const float* bias,
                         const float* res, void* C, void* C2, int M, int N, int K,
                         int lda, int ldc, hipStream_t s) {
    dim3 g((N + BN - 1) / BN, (M + BM - 1) / BM);
    mgemm_k<BM, BN, MODE, CMAJ><<<g, 256, 0, s>>>(A, Bw, bias, res, C, C2, M, N, K, lda, ldc);
}

// ---------------- fused attention ----------------
#define KP_ 72    // K LDS row pad (bf16)
#define PP_ 232   // P LDS row pad (bf16)

__global__ __launch_bounds__(256) void attn_k(
    const __bf16* __restrict__ qb, const __bf16* __restrict__ kbb,
    const __bf16* __restrict__ vbT, __bf16* __restrict__ obb) {
    __shared__ __align__(16) __bf16 Ks[CTXP_ * KP_];
    __shared__ __align__(16) __bf16 Ps[64 * PP_];
    int z = blockIdx.z, b = z >> 3, h = z & 7;
    int tid = threadIdx.x, wave = tid >> 6, lane = tid & 63;
    int fr = lane & 15, fk = lane >> 4;
    int q0 = blockIdx.y * 64;
    #pragma unroll
    for (int i = 0; i < 7; ++i) {
        int idx = i * 256 + tid;
        int r = idx >> 3, cu = (idx & 7) * 8;
        uint4 v = {0u, 0u, 0u, 0u};
        if (r < CTX_) v = *(const uint4*)(kbb + ((size_t)(b * CTX_ + r)) * DIM_ + h * HD_ + cu);
        *(uint4*)&Ks[r * KP_ + cu] = v;
    }
    bf16x8 aq[2];
    {
        int qrow = b * N_ + q0 + wave * 16 + fr;
        #pragma unroll
        for (int t = 0; t < 2; ++t)
            aq[t] = *(const bf16x8*)(qb + (size_t)qrow * DIM_ + h * HD_ + t * 32 + fk * 8);
    }
    __syncthreads();
    f32x4 acc[CTXF_] = {};
    #pragma unroll
    for (int t = 0; t < 2; ++t)
        #pragma unroll
        for (int cb = 0; cb < CTXF_; ++cb) {
            bf16x8 bg = *(const bf16x8*)&Ks[(cb * 16 + fr) * KP_ + t * 32 + fk * 8];
            acc[cb] = __builtin_amdgcn_mfma_f32_16x16x32_bf16(aq[t], bg, acc[cb], 0, 0, 0);
        }
    #pragma unroll
    for (int e = 0; e < 4; ++e) {
        float m = -1e30f;
        #pragma unroll
        for (int cb = 0; cb < CTXF_; ++cb) {
            float sv = acc[cb][e] * 0.125f;
            if (cb * 16 + fr >= CTX_) sv = -1e30f;
            acc[cb][e] = sv;
            m = fmaxf(m, sv);
        }
        m = dpp_max16(m);
        float ssum = 0.f;
        #pragma unroll
        for (int cb = 0; cb < CTXF_; ++cb) {
            float p = __expf(acc[cb][e] - m);
            acc[cb][e] = p;
            ssum += p;
        }
        ssum = dpp_red16(ssum);
        float inv = 1.f / ssum;
        #pragma unroll
        for (int cb = 0; cb < CTXF_; ++cb)
            Ps[(wave * 16 + fk * 4 + e) * PP_ + cb * 16 + fr] = (__bf16)(acc[cb][e] * inv);
        Ps[(wave * 16 + fk * 4 + e) * PP_ + 208 + fr] = (__bf16)0.f;
    }
    __syncthreads();
    f32x4 acc2[4] = {};
    const __bf16* vB = vbT + (size_t)z * HD_ * CTXP_;
    #pragma unroll
    for (int sl = 0; sl < 7; ++sl) {
        bf16x8 ap = *(const bf16x8*)&Ps[(wave * 16 + fr) * PP_ + sl * 32 + fk * 8];
        #pragma unroll
        for (int nf = 0; nf < 4; ++nf) {
            bf16x8 bv = *(const bf16x8*)(vB + (size_t)(nf * 16 + fr) * CTXP_ + sl * 32 + fk * 8);
            acc2[nf] = __builtin_amdgcn_mfma_f32_16x16x32_bf16(ap, bv, acc2[nf], 0, 0, 0);
        }
    }
    #pragma unroll
    for (int nf = 0; nf < 4; ++nf)
        #pragma unroll
        for (int e = 0; e < 4; ++e) {
            int gm = b * N_ + q0 + wave * 16 + fk * 4 + e;
            obb[(size_t)gm * DIM_ + h * HD_ + nf * 16 + fr] = (__bf16)acc2[nf][e];
        }
}

// ---------------- host side ----------------

extern "C" void kernel_launch(void* const* d_in, const int* in_sizes, int n_in,
                              void* d_out, int out_size, void* d_ws, size_t ws_size,
                              hipStream_t stream) {
    const int*   text   = (const int*)d_in[0];
    const float* images = (const float*)d_in[1];
    const float* alphap = (const float*)d_in[2];
    const float* dgam   = (const float*)d_in[3];
    const float* dbeta  = (const float*)d_in[4];
    const float* imgW   = (const float*)d_in[5];
    const float* imgb   = (const float*)d_in[6];
    const float* g1W    = (const float*)d_in[7];
    const float* g1b    = (const float*)d_in[8];
    const float* g2W    = (const float*)d_in[9];
    const float* g2b    = (const float*)d_in[10];
    const float* temb   = (const float*)d_in[11];
    const float* pemb   = (const float*)d_in[12];
    const float* ln1g   = (const float*)d_in[13];
    const float* ln1b   = (const float*)d_in[14];
    const float* inW    = (const float*)d_in[15];
    const float* convW  = (const float*)d_in[16];
    const float* convb  = (const float*)d_in[17];
    const float* xpW    = (const float*)d_in[18];
    const float* dtW    = (const float*)d_in[19];
    const float* dtb    = (const float*)d_in[20];
    const float* Alog   = (const float*)d_in[21];
    const float* Dsk    = (const float*)d_in[22];
    const float* outW   = (const float*)d_in[23];
    const float* ln2g   = (const float*)d_in[24];
    const float* ln2b   = (const float*)d_in[25];
    const float* ainW   = (const float*)d_in[26];
    const float* ainb   = (const float*)d_in[27];
    const float* aoutW  = (const float*)d_in[28];
    const float* aoutb  = (const float*)d_in[29];
    const float* fng    = (const float*)d_in[30];
    const float* fnb    = (const float*)d_in[31];
    const float* lgW    = (const float*)d_in[32];
    const float* lgb    = (const float*)d_in[33];
    float* out = (float*)d_out;

    float* w = (float*)d_ws;
    float* imgd   = w; w += (size_t)B_ * CTX_ * IMGD_;   // bf16 dyt out (aliased)
    float* imgf   = w; w += (size_t)B_ * CTX_ * DIM_;
    float* pooled = w; w += B_ * DIM_;
    float* g1     = w; w += B_ * 128;
    float* gate   = w; w += B_ * DIM_;
    float* x      = w; w += (size_t)B_ * N_ * DIM_;
    float* xn     = w; w += (size_t)B_ * N_ * DIM_;      // bf16 ln out (aliased)
    float* dblb   = w; w += (size_t)B_ * N_ * 64;
    // bf16 buffers
    __bf16* xzb   = (__bf16*)w; w += (size_t)B_ * N_ * 2 * DIN_ / 2;
    __bf16* xcb   = (__bf16*)w; w += (size_t)B_ * N_ * DIN_ / 2;
    __bf16* imgfb = (__bf16*)w; w += (size_t)B_ * CTX_ * DIM_ / 2;
    __bf16* ybb   = (__bf16*)w; w += (size_t)B_ * N_ * DIN_ / 2;
    __bf16* qb    = (__bf16*)w; w += (size_t)B_ * N_ * DIM_ / 2;
    __bf16* kbb   = (__bf16*)w; w += (size_t)DEPTH_ * B_ * CTX_ * DIM_ / 2;
    __bf16* vbT   = (__bf16*)w; w += (size_t)DEPTH_ * B_ * HEADS_ * HD_ * CTXP_ / 2;
    __bf16* obb   = (__bf16*)w; w += (size_t)B_ * N_ * DIM_ / 2;
    __bf16* lgT   = (__bf16*)w; w += (size_t)10000 * DIM_ / 2;
    // bf16 weights
    __bf16* inpT  = (__bf16*)w; w += (size_t)DEPTH_ * 2 * DIN_ * DIM_ / 2;
    __bf16* outpT = (__bf16*)w; w += (size_t)DEPTH_ * DIM_ * DIN_ / 2;
    __bf16* qWB   = (__bf16*)w; w += (size_t)DEPTH_ * DIM_ * DIM_ / 2;
    __bf16* kvWB  = (__bf16*)w; w += (size_t)DEPTH_ * 2 * DIM_ * DIM_ / 2;
    __bf16* aoutB = (__bf16*)w; w += (size_t)DEPTH_ * DIM_ * DIM_ / 2;
    __bf16* imgWT = (__bf16*)w; w += (size_t)DIM_ * IMGD_ / 2;
    __bf16* xpWT  = (__bf16*)w; w += (size_t)DEPTH_ * 64 * DIN_ / 2;
    __bf16* imgdb = (__bf16*)imgd;
    __bf16* xnb   = (__bf16*)xn;

    const int TOKENS = B_ * N_;
    const int IMGT   = B_ * CTX_;

    // zero all layers' vbT pad columns once
    hipMemsetAsync(vbT, 0, (size_t)DEPTH_ * B_ * HEADS_ * HD_ * CTXP_ * sizeof(__bf16), stream);

    // ---- weight prep ----
    tconv_kernel<<<dim3(2 * DIN_ / 32, DIM_ / 32, DEPTH_), 256, 0, stream>>>(inW,  inpT,  DIM_, 2 * DIN_);
    tconv_kernel<<<dim3(DIM_ / 32, DIN_ / 32, DEPTH_),     256, 0, stream>>>(outW, outpT, DIN_, DIM_);
    tconv_kernel<<<dim3(DIM_ / 32, IMGD_ / 32, 1),         256, 0, stream>>>(imgW, imgWT, IMGD_, DIM_);
    tconv_kernel<<<dim3(64 / 32, DIN_ / 32, DEPTH_),       256, 0, stream>>>(xpW,  xpWT,  DIN_, 64);
    tconv_kernel<<<dim3((10000 + 31) / 32, DIM_ / 32, 1),  256, 0, stream>>>(lgW, lgT, DIM_, 10000);
    cvt_rows_kernel<<<(DEPTH_ * DIM_ * (DIM_ / 4) + 255) / 256, 256, 0, stream>>>(
        ainW, qWB, DEPTH_ * DIM_, DIM_, 0);
    cvt_rows_kernel<<<(DEPTH_ * 2 * DIM_ * (DIM_ / 4) + 255) / 256, 256, 0, stream>>>(
        ainW, kvWB, DEPTH_ * 2 * DIM_, 2 * DIM_, DIM_);
    cvt_bf16_kernel<<<(DEPTH_ * DIM_ * DIM_ / 4 + 255) / 256, 256, 0, stream>>>(aoutW, aoutB, DEPTH_ * DIM_ * DIM_);

    // ---- image path ----
    {
        int total = B_ * CTX_ * IMGD_;
        dyt_kernel<<<(total + 255) / 256, 256, 0, stream>>>(images, alphap, dgam, dbeta, imgdb, total);
        mgemm<32, 64>(imgdb, imgWT, imgb, nullptr, imgf, nullptr, IMGT, DIM_, IMGD_, IMGD_, DIM_, stream);
        pool_kernel<<<(B_ * DIM_ + 255) / 256, 256, 0, stream>>>(imgf, pooled);
        gate1_kernel<<<(B_ * 128 + 255) / 256, 256, 0, stream>>>(pooled, g1W, g1b, g1);
        gate2_kernel<<<(B_ * DIM_ + 255) / 256, 256, 0, stream>>>(g1, g2W, g2b, gate);
        scale_kernel<<<(B_ * CTX_ * DIM_ + 255) / 256, 256, 0, stream>>>(imgf, gate, imgfb);
    }
    embed_kernel<<<(TOKENS * DIM_ + 255) / 256, 256, 0, stream>>>(text, temb, pemb, x);

    // ---- ALL layers' K/V projections in ONE batched GEMM (col-major slabs) ----
    mgemm<64, 128, 3, true>(imgfb, kvWB, nullptr, ainb, kbb, vbT,
                            IMGT, DEPTH_ * 2 * DIM_, DIM_, DIM_, 0, stream);

    for (int l = 0; l < DEPTH_; ++l) {
        const __bf16* inpT_l  = inpT  + (size_t)l * 2 * DIN_ * DIM_;
        const __bf16* outpT_l = outpT + (size_t)l * DIM_ * DIN_;
        const __bf16* qWB_l   = qWB   + (size_t)l * DIM_ * DIM_;
        const __bf16* aoutB_l = aoutB + (size_t)l * DIM_ * DIM_;
        const __bf16* xpWT_l  = xpWT  + (size_t)l * 64 * DIN_;
        const __bf16* kbb_l   = kbb   + (size_t)l * IMGT * DIM_;
        const __bf16* vbT_l   = vbT   + (size_t)l * B_ * HEADS_ * HD_ * CTXP_;
        const float* cw    = convW + (size_t)l * DIN_ * 4;
        const float* cb    = convb + (size_t)l * DIN_;
        const float* dtw   = dtW  + (size_t)l * DTR_ * DIN_;
        const float* dtbi  = dtb  + (size_t)l * DIN_;
        const float* alog  = Alog + (size_t)l * DIN_ * DST_;
        const float* dsk   = Dsk  + (size_t)l * DIN_;
        const float* ab    = ainb + (size_t)l * 3 * DIM_;
        const float* aob   = aoutb + (size_t)l * DIM_;

        // mamba block (bf16 activations end-to-end)
        ln_kernel<<<TOKENS / 4, 256, 0, stream>>>(x, ln1g + l * DIM_, ln1b + l * DIM_, xnb, TOKENS);
        mgemm<64, 128, 1>(xnb, inpT_l, nullptr, nullptr, xzb, nullptr, TOKENS, 2 * DIN_, DIM_, DIM_, 2 * DIN_, stream);
        conv_silu_kernel<<<(TOKENS * DIN_ / 4 + 255) / 256, 256, 0, stream>>>(xzb, cw, cb, xcb);
        mgemm<32, 64>(xcb, xpWT_l, nullptr, nullptr, dblb, nullptr, TOKENS, 64, DIN_, DIN_, 64, stream);
        scanf_kernel<<<B_ * DIN_ / DG_, 256, 0, stream>>>(xcb, dblb, xzb, dtw, dtbi, alog, dsk, ybb);
        mgemm<32, 64>(ybb, outpT_l, nullptr, x, x, nullptr, TOKENS, DIM_, DIN_, DIN_, DIM_, stream);

        // cross-attention block
        ln_kernel<<<TOKENS / 4, 256, 0, stream>>>(x, ln2g + l * DIM_, ln2b + l * DIM_, xnb, TOKENS);
        mgemm<32, 64, 1>(xnb, qWB_l, ab, nullptr, qb, nullptr, TOKENS, DIM_, DIM_, DIM_, DIM_, stream);
        attn_k<<<dim3(1, 4, B_ * HEADS_), 256, 0, stream>>>(qb, kbb_l, vbT_l, obb);
        mgemm<32, 64>(obb, aoutB_l, aob, x, x, nullptr, TOKENS, DIM_, DIM_, DIM_, DIM_, stream);
    }

    // final LN + logits (128x128 col-major slabs, float4 LDS epilogue)
    ln_kernel<<<TOKENS / 4, 256, 0, stream>>>(x, fng, fnb, xnb, TOKENS);
    mgemm<128, 128, 0, true>(xnb, lgT, lgb, nullptr, out, nullptr, TOKENS, 10000, DIM_, DIM_, 10000, stream);
}

// Round 19
// 1126.953 us; speedup vs baseline: 1.0679x; 1.0057x over previous
//
#include <hip/hip_runtime.h>
#include <hip/hip_bf16.h>
#include <stdint.h>

#define B_    8
#define N_    256
#define CTX_  196
#define CTXP_ 224   // ctx padded to multiple of 32 for PV K-loop
#define CTXF_ 13    // score col frags (13*16 = 208 >= 196)
#define IMGD_ 1024
#define DIM_  512
#define DEPTH_ 6
#define DIN_  1024
#define DTR_  32
#define DST_  16
#define HEADS_ 8
#define HD_   64
#define NCHUNK_ 16
#define CLEN_   16   // N_/NCHUNK_
#define DG_     4    // d's per scan block

typedef __bf16 bf16x8 __attribute__((ext_vector_type(8)));
typedef __bf16 bf16x4 __attribute__((ext_vector_type(4)));
typedef float  f32x4  __attribute__((ext_vector_type(4)));

// 16-lane sum via DPP butterfly; all 16 lanes get total
__device__ __forceinline__ float dpp_red16(float v) {
    int y;
    y = __builtin_amdgcn_update_dpp(0, __float_as_int(v), 0xB1, 0xF, 0xF, true);
    v += __int_as_float(y);
    y = __builtin_amdgcn_update_dpp(0, __float_as_int(v), 0x4E, 0xF, 0xF, true);
    v += __int_as_float(y);
    y = __builtin_amdgcn_update_dpp(0, __float_as_int(v), 0x141, 0xF, 0xF, true);
    v += __int_as_float(y);
    y = __builtin_amdgcn_update_dpp(0, __float_as_int(v), 0x140, 0xF, 0xF, true);
    v += __int_as_float(y);
    return v;
}
__device__ __forceinline__ float dpp_max16(float v) {
    int y;
    y = __builtin_amdgcn_update_dpp(0, __float_as_int(v), 0xB1, 0xF, 0xF, true);
    v = fmaxf(v, __int_as_float(y));
    y = __builtin_amdgcn_update_dpp(0, __float_as_int(v), 0x4E, 0xF, 0xF, true);
    v = fmaxf(v, __int_as_float(y));
    y = __builtin_amdgcn_update_dpp(0, __float_as_int(v), 0x141, 0xF, 0xF, true);
    v = fmaxf(v, __int_as_float(y));
    y = __builtin_amdgcn_update_dpp(0, __float_as_int(v), 0x140, 0xF, 0xF, true);
    v = fmaxf(v, __int_as_float(y));
    return v;
}

// async global->LDS 16B (direct-to-LDS DMA; no VGPR round trip)
__device__ __forceinline__ void gload16(const void* g, void* l) {
    __builtin_amdgcn_global_load_lds(
        (const __attribute__((address_space(1))) uint32_t*)g,
        (__attribute__((address_space(3))) uint32_t*)l, 16, 0, 0);
}

// ---------------- elementwise / small kernels ----------------

__global__ void dyt_kernel(const float* __restrict__ img, const float* __restrict__ alpha_p,
                           const float* __restrict__ gamma, const float* __restrict__ beta,
                           __bf16* __restrict__ out, int total) {
    int i = blockIdx.x * 256 + threadIdx.x;
    if (i >= total) return;
    float a = alpha_p[0];
    int c = i & (IMGD_ - 1);
    out[i] = (__bf16)(gamma[c] * tanhf(a * img[i]) + beta[c]);
}

__global__ void pool_kernel(const float* __restrict__ imgf, float* __restrict__ pooled) {
    int i = blockIdx.x * 256 + threadIdx.x;
    if (i >= B_ * DIM_) return;
    int b = i >> 9, c = i & (DIM_ - 1);
    const float* p = imgf + (size_t)b * CTX_ * DIM_ + c;
    float s = 0.f;
    for (int t = 0; t < CTX_; ++t) s += p[t * DIM_];
    pooled[i] = s * (1.f / CTX_);
}

__global__ void gate1_kernel(const float* __restrict__ pooled, const float* __restrict__ W,
                             const float* __restrict__ bias, float* __restrict__ g1) {
    int i = blockIdx.x * 256 + threadIdx.x;
    if (i >= B_ * 128) return;
    int b = i >> 7, j = i & 127;
    const float* p = pooled + b * DIM_;
    float s = bias[j];
    for (int c = 0; c < DIM_; ++c) s += p[c] * W[c * 128 + j];
    g1[i] = 0.5f * s * (1.f + erff(s * 0.70710678118654752f));
}

__global__ void gate2_kernel(const float* __restrict__ g1, const float* __restrict__ W,
                             const float* __restrict__ bias, float* __restrict__ gate) {
    int i = blockIdx.x * 256 + threadIdx.x;
    if (i >= B_ * DIM_) return;
    int b = i >> 9, c = i & (DIM_ - 1);
    const float* p = g1 + b * 128;
    float s = bias[c];
    for (int j = 0; j < 128; ++j) s += p[j] * W[j * DIM_ + c];
    gate[i] = 1.f / (1.f + __expf(-s));
}

__global__ void scale_kernel(const float* __restrict__ imgf, const float* __restrict__ gate,
                             __bf16* __restrict__ imgfb) {
    int i = blockIdx.x * 256 + threadIdx.x;
    if (i >= B_ * CTX_ * DIM_) return;
    int c = i & (DIM_ - 1);
    int b = i / (CTX_ * DIM_);
    imgfb[i] = (__bf16)(imgf[i] * gate[b * DIM_ + c]);
}

__global__ void embed_kernel(const int* __restrict__ text, const float* __restrict__ temb,
                             const float* __restrict__ pemb, float* __restrict__ x) {
    int i = blockIdx.x * 256 + threadIdx.x;
    if (i >= B_ * N_ * DIM_) return;
    int c = i & (DIM_ - 1);
    int row = i >> 9;
    int n = row & (N_ - 1);
    int tok = text[row];
    x[i] = temb[(size_t)tok * DIM_ + c] + pemb[(size_t)n * DIM_ + c];
}

// wave-per-row layernorm, row = 512 floats, bf16 output
__global__ void ln_kernel(const float* __restrict__ x, const float* __restrict__ g,
                          const float* __restrict__ b, __bf16* __restrict__ o, int rows) {
    int row = blockIdx.x * 4 + (threadIdx.x >> 6);
    if (row >= rows) return;
    int lane = threadIdx.x & 63;
    const float* xr = x + (size_t)row * DIM_ + lane * 8;
    float4 v0 = ((const float4*)xr)[0];
    float4 v1 = ((const float4*)xr)[1];
    float r[8] = {v0.x, v0.y, v0.z, v0.w, v1.x, v1.y, v1.z, v1.w};
    float sum = 0.f, sq = 0.f;
    #pragma unroll
    for (int j = 0; j < 8; ++j) { sum += r[j]; sq += r[j] * r[j]; }
    #pragma unroll
    for (int m = 1; m < 64; m <<= 1) { sum += __shfl_xor(sum, m); sq += __shfl_xor(sq, m); }
    float mean = sum * (1.f / DIM_);
    float var  = sq * (1.f / DIM_) - mean * mean;
    float inv  = rsqrtf(fmaxf(var, 0.f) + 1e-5f);
    const float* gp = g + lane * 8;
    const float* bp = b + lane * 8;
    __bf16* op = o + (size_t)row * DIM_ + lane * 8;
    bf16x8 ov;
    #pragma unroll
    for (int j = 0; j < 8; ++j) ov[j] = (__bf16)((r[j] - mean) * inv * gp[j] + bp[j]);
    *(bf16x8*)op = ov;
}

// causal depthwise conv (4 taps) + SiLU; bf16 in (xzb), bf16 out (xcb)
__global__ void conv_silu_kernel(const __bf16* __restrict__ xzb, const float* __restrict__ cw,
                                 const float* __restrict__ cb, __bf16* __restrict__ xcb) {
    int idx = blockIdx.x * 256 + threadIdx.x;
    if (idx >= B_ * N_ * DIN_ / 4) return;
    int i4 = idx * 4;
    int d = i4 & (DIN_ - 1);
    int row = i4 >> 10;
    int n = row & (N_ - 1);
    int rowb = row - n;
    float4 acc = *(const float4*)(cb + d);
    #pragma unroll
    for (int k = 0; k < 4; ++k) {
        int m = n - 3 + k;
        if (m >= 0) {
            bf16x4 v = *(const bf16x4*)(xzb + (size_t)(rowb + m) * (2 * DIN_) + d);
            acc.x += (float)v[0] * cw[(d + 0) * 4 + k];
            acc.y += (float)v[1] * cw[(d + 1) * 4 + k];
            acc.z += (float)v[2] * cw[(d + 2) * 4 + k];
            acc.w += (float)v[3] * cw[(d + 3) * 4 + k];
        }
    }
    bf16x4 p;
    p[0] = (__bf16)(acc.x / (1.f + __expf(-acc.x)));
    p[1] = (__bf16)(acc.y / (1.f + __expf(-acc.y)));
    p[2] = (__bf16)(acc.z / (1.f + __expf(-acc.z)));
    p[3] = (__bf16)(acc.w / (1.f + __expf(-acc.w)));
    *(bf16x4*)(xcb + i4) = p;
}

__global__ void cvt_bf16_kernel(const float* __restrict__ src, __bf16* __restrict__ dst, int count) {
    int i = (blockIdx.x * 256 + threadIdx.x) * 4;
    if (i >= count) return;
    float4 v = *(const float4*)(src + i);
    bf16x4 p = {(__bf16)v.x, (__bf16)v.y, (__bf16)v.z, (__bf16)v.w};
    *(bf16x4*)(dst + i) = p;
}

// row-sliced convert: dst row i (K=512) <- src row (i/rpl)*1536 + off + (i%rpl)
__global__ void cvt_rows_kernel(const float* __restrict__ src, __bf16* __restrict__ dst,
                                int totalRows, int rpl, int off) {
    int t = blockIdx.x * 256 + threadIdx.x;
    int total = totalRows * (DIM_ / 4);
    if (t >= total) return;
    int i = t / (DIM_ / 4), c4 = (t % (DIM_ / 4)) * 4;
    int l = i / rpl, r = i % rpl;
    const float* s = src + ((size_t)l * 1536 + off + r) * DIM_ + c4;
    float4 v = *(const float4*)s;
    bf16x4 p = {(__bf16)v.x, (__bf16)v.y, (__bf16)v.z, (__bf16)v.w};
    *(bf16x4*)(dst + (size_t)i * DIM_ + c4) = p;
}

// ---------------- fused selective scan v5: 4 d's per block, bf16 activations ----
__global__ __launch_bounds__(256) void scanf_kernel(
    const __bf16* __restrict__ xcb, const float* __restrict__ dbl,
    const __bf16* __restrict__ xzb, const float* __restrict__ dtw,
    const float* __restrict__ dtb, const float* __restrict__ A_log,
    const float* __restrict__ Dsk, __bf16* __restrict__ ybb) {
    __shared__ float sdt[DG_][N_], su[DG_][N_];
    __shared__ float sA[DG_][256], sB[DG_][256];
    int bid = blockIdx.x;
    int nwg = gridDim.x;                       // 2048, % 8 == 0
    int bd = (bid & 7) * (nwg >> 3) + (bid >> 3);   // bijective XCD swizzle
    int dg = bd & (DIN_ / DG_ - 1), b = bd / (DIN_ / DG_);
    int d0 = dg * DG_;
    int tid = threadIdx.x, s = tid & 15, c = tid >> 4;
    {
        int row = b * N_ + tid;
        const float* dp = dbl + row * 64;
        float4 acc = *(const float4*)(dtb + d0);
        #pragma unroll
        for (int k = 0; k < DTR_; k += 4) {
            float4 dv = *(const float4*)(dp + k);
            float4 w0 = *(const float4*)(dtw + (k + 0) * DIN_ + d0);
            float4 w1 = *(const float4*)(dtw + (k + 1) * DIN_ + d0);
            float4 w2 = *(const float4*)(dtw + (k + 2) * DIN_ + d0);
            float4 w3 = *(const float4*)(dtw + (k + 3) * DIN_ + d0);
            acc.x += dv.x * w0.x + dv.y * w1.x + dv.z * w2.x + dv.w * w3.x;
            acc.y += dv.x * w0.y + dv.y * w1.y + dv.z * w2.y + dv.w * w3.y;
            acc.z += dv.x * w0.z + dv.y * w1.z + dv.z * w2.z + dv.w * w3.z;
            acc.w += dv.x * w0.w + dv.y * w1.w + dv.z * w2.w + dv.w * w3.w;
        }
        bf16x4 xcv4 = *(const bf16x4*)(xcb + (size_t)row * DIN_ + d0);
        float av[4] = {acc.x, acc.y, acc.z, acc.w};
        float xv[4] = {(float)xcv4[0], (float)xcv4[1], (float)xcv4[2], (float)xcv4[3]};
        #pragma unroll
        for (int g = 0; g < DG_; ++g) {
            float dt = fmaxf(av[g], 0.f) + __logf(1.f + __expf(-fabsf(av[g])));
            sdt[g][tid] = dt;
            su[g][tid] = dt * xv[g];
        }
    }
    float As4[DG_];
    #pragma unroll
    for (int g = 0; g < DG_; ++g) As4[g] = -__expf(A_log[((d0 + g) << 4) | s]);
    __syncthreads();
    int r0 = c * CLEN_;
    int row0 = b * N_ + r0;
    float a[DG_], hb[DG_];
    #pragma unroll
    for (int g = 0; g < DG_; ++g) { a[g] = 1.f; hb[g] = 0.f; }
    #pragma unroll 2
    for (int n = 0; n < CLEN_; ++n) {
        float Bv = dbl[(row0 + n) * 64 + 32 + s];
        #pragma unroll
        for (int g = 0; g < DG_; ++g) {
            float dA = __expf(sdt[g][r0 + n] * As4[g]);
            hb[g] = hb[g] * dA + su[g][r0 + n] * Bv;
            a[g] *= dA;
        }
    }
    #pragma unroll
    for (int g = 0; g < DG_; ++g) { sA[g][tid] = a[g]; sB[g][tid] = hb[g]; }
    __syncthreads();
    float h[DG_];
    #pragma unroll
    for (int g = 0; g < DG_; ++g) h[g] = 0.f;
    for (int j = 0; j < c; ++j)
        #pragma unroll
        for (int g = 0; g < DG_; ++g)
            h[g] = h[g] * sA[g][j * 16 + s] + sB[g][j * 16 + s];
    float4 Dv4 = *(const float4*)(Dsk + d0);
    float Dv[4] = {Dv4.x, Dv4.y, Dv4.z, Dv4.w};
    #pragma unroll 2
    for (int n = 0; n < CLEN_; ++n) {
        int row = row0 + n;
        float Bv = dbl[row * 64 + 32 + s];
        float Cv = dbl[row * 64 + 48 + s];
        float p[DG_];
        #pragma unroll
        for (int g = 0; g < DG_; ++g) {
            float dA = __expf(sdt[g][r0 + n] * As4[g]);
            h[g] = h[g] * dA + su[g][r0 + n] * Bv;
            p[g] = dpp_red16(h[g] * Cv);
        }
        if (s == 0) {
            bf16x4 xcv4 = *(const bf16x4*)(xcb + (size_t)row * DIN_ + d0);
            bf16x4 zz4  = *(const bf16x4*)(xzb + (size_t)row * (2 * DIN_) + DIN_ + d0);
            bf16x4 yo;
            #pragma unroll
            for (int g = 0; g < DG_; ++g) {
                float xv = (float)xcv4[g];
                float zv = (float)zz4[g];
                float y = (p[g] + xv * Dv[g]) * (zv / (1.f + __expf(-zv)));
                yo[g] = (__bf16)y;
            }
            *(bf16x4*)(ybb + (size_t)row * DIN_ + d0) = yo;
        }
    }
}

// ---------------- weight prep ----------------

__global__ void tconv_kernel(const float* __restrict__ src, __bf16* __restrict__ dst,
                             int K, int N) {
    __shared__ float tile[32][33];
    int n0 = blockIdx.x * 32, k0 = blockIdx.y * 32;
    src += (size_t)blockIdx.z * K * N;
    dst += (size_t)blockIdx.z * K * N;
    int tx = threadIdx.x & 31, ty = threadIdx.x >> 5;
    #pragma unroll
    for (int i = 0; i < 32; i += 8) {
        int k = k0 + ty + i, n = n0 + tx;
        tile[ty + i][tx] = (k < K && n < N) ? src[(size_t)k * N + n] : 0.f;
    }
    __syncthreads();
    #pragma unroll
    for (int i = 0; i < 32; i += 8) {
        int n = n0 + ty + i, k = k0 + tx;
        if (n < N && k < K) dst[(size_t)n * K + k] = (__bf16)tile[tx][ty + i];
    }
}

// ---------------- bf16 MFMA GEMM v3: global_load_lds staging ----------------
// MODE 0: fp32 out (+res), LDS-transposed float4 epilogue processed in TWO
//         row-halves (half-size C overlay -> higher occupancy; +4 row pad
//         kills store bank conflicts). MODE 1: bf16 out. MODE 3: batched-kv.
// CMAJ: column-major block mapping for N >> M shapes (kv, logits).

template <int BM, int BN, int MODE, bool CMAJ = false>
__global__ __launch_bounds__(256) void mgemm_k(
    const __bf16* __restrict__ A, const __bf16* __restrict__ Bw,
    const float* __restrict__ bias, const float* __restrict__ res,
    void* __restrict__ Cp, void* __restrict__ Cp2,
    int M, int N, int K, int lda, int ldc) {
    constexpr int UA = BM * 4;   // 16B units per 32-K slab tile
    constexpr int UB = BN * 4;
    constexpr int FM = BM / 32, FN = BN / 32;
    constexpr int CPAD = BN + 4;                           // padded LDS C row
    constexpr int STAGE_B = (UA + UB) * 32;                // both double-buffers
    constexpr int CS_B    = (MODE == 0) ? (BM / 2) * CPAD * 4 : 0;
    constexpr int SMEM_B  = STAGE_B > CS_B ? STAGE_B : CS_B;
    __shared__ __align__(16) char smem[SMEM_B];
    __bf16* As = (__bf16*)smem;                      // [2][UA*8]
    __bf16* Bs = (__bf16*)(smem + (size_t)UA * 32);  // [2][UB*8]
    int tid = threadIdx.x;
    int ntx = gridDim.x;
    int nwg = ntx * gridDim.y;
    int bid = blockIdx.y * ntx + blockIdx.x;
    if ((nwg & 7) == 0) bid = (bid & 7) * (nwg >> 3) + (bid >> 3);
    int row0, col0;
    if constexpr (CMAJ) {
        int nty = nwg / ntx;
        row0 = (bid % nty) * BM;
        col0 = (bid / nty) * BN;
    } else {
        row0 = (bid / ntx) * BM;
        col0 = (bid % ntx) * BN;
    }
    int wave = tid >> 6, lane = tid & 63;
    int wm = (wave >> 1) * (BM / 2), wn = (wave & 1) * (BN / 2);
    int fr = lane & 15, fk = lane >> 4;
    f32x4 acc[FM][FN] = {};

    auto stage = [&](int buf, int k0) {
        #pragma unroll
        for (int j = 0; j < (UA + 255) / 256; ++j) {
            int u = j * 256 + tid;
            if ((UA & 255) == 0 || u < UA) {
                int ks = u / BM, r = u % BM;
                gload16(A + (size_t)(row0 + r) * lda + k0 + ks * 8, &As[((size_t)buf * UA + u) * 8]);
            }
        }
        #pragma unroll
        for (int j = 0; j < (UB + 255) / 256; ++j) {
            int u = j * 256 + tid;
            if ((UB & 255) == 0 || u < UB) {
                int ks = u / BN, r = u % BN;
                gload16(Bw + (size_t)(col0 + r) * K + k0 + ks * 8, &Bs[((size_t)buf * UB + u) * 8]);
            }
        }
    };

    stage(0, 0);
    __syncthreads();
    int NK = K >> 5;
    for (int kt = 0; kt < NK; ++kt) {
        int cur = kt & 1;
        if (kt + 1 < NK) stage(cur ^ 1, (kt + 1) << 5);   // loads fly over MFMA phase
        bf16x8 af[FM], bg[FN];
        #pragma unroll
        for (int mf = 0; mf < FM; ++mf)
            af[mf] = *(const bf16x8*)&As[((size_t)cur * UA + fk * BM + wm + mf * 16 + fr) * 8];
        #pragma unroll
        for (int nf = 0; nf < FN; ++nf)
            bg[nf] = *(const bf16x8*)&Bs[((size_t)cur * UB + fk * BN + wn + nf * 16 + fr) * 8];
        #pragma unroll
        for (int mf = 0; mf < FM; ++mf)
            #pragma unroll
            for (int nf = 0; nf < FN; ++nf)
                acc[mf][nf] = __builtin_amdgcn_mfma_f32_16x16x32_bf16(af[mf], bg[nf], acc[mf][nf], 0, 0, 0);
        __syncthreads();   // drains vmcnt (next tile landed) + protects cur for overwrite
    }
    if constexpr (MODE == 0) {
        // Two-half LDS-transposed epilogue: waves 0-1 own rows [0,BM/2),
        // waves 2-3 own [BM/2,BM). Half-size overlay -> SMEM ~= stage size.
        float* Cs = (float*)smem;
        #pragma unroll
        for (int half = 0; half < 2; ++half) {
            if (wm == half * (BM / 2)) {
                #pragma unroll
                for (int mf = 0; mf < FM; ++mf)
                    #pragma unroll
                    for (int nf = 0; nf < FN; ++nf)
                        #pragma unroll
                        for (int e = 0; e < 4; ++e)
                            Cs[(mf * 16 + fk * 4 + e) * CPAD + wn + nf * 16 + fr] = acc[mf][nf][e];
            }
            __syncthreads();
            for (int u = tid; u < (BM / 2) * BN / 4; u += 256) {
                int r = u / (BN / 4), c4 = (u % (BN / 4)) * 4;
                int gm = row0 + half * (BM / 2) + r, gn = col0 + c4;
                if (gm < M && gn < N) {
                    f32x4 v = *(const f32x4*)&Cs[r * CPAD + c4];
                    if (bias) v += *(const f32x4*)(bias + gn);
                    size_t idx = (size_t)gm * ldc + gn;
                    if (res) v += *(const f32x4*)(res + idx);
                    *(f32x4*)((float*)Cp + idx) = v;
                }
            }
            __syncthreads();
        }
    } else {
        #pragma unroll
        for (int mf = 0; mf < FM; ++mf) {
            #pragma unroll
            for (int nf = 0; nf < FN; ++nf) {
                int gn = col0 + wn + nf * 16 + fr;
                if (gn >= N) continue;
                float bb = (MODE != 3 && bias) ? bias[gn] : 0.f;
                #pragma unroll
                for (int e = 0; e < 4; ++e) {
                    int gm = row0 + wm + mf * 16 + fk * 4 + e;
                    if (gm >= M) continue;
                    float v = acc[mf][nf][e] + bb;
                    if constexpr (MODE == 1) {
                        ((__bf16*)Cp)[(size_t)gm * ldc + gn] = (__bf16)v;
                    } else {
                        int l = gn >> 10, j = gn & 1023;
                        float vb = v + res[l * 1536 + 512 + j];  // ainb[l][512+j]
                        if (j < DIM_) {
                            ((__bf16*)Cp)[(size_t)l * (B_ * CTX_) * DIM_ + (size_t)gm * DIM_ + j] = (__bf16)vb;
                        } else {
                            int jj = j - DIM_;
                            int bimg = gm / CTX_, k = gm - bimg * CTX_;
                            ((__bf16*)Cp2)[(((size_t)l * B_ * HEADS_ + bimg * HEADS_ + (jj >> 6)) * HD_ + (jj & 63)) * CTXP_ + k] = (__bf16)vb;
                        }
                    }
                }
            }
        }
    }
}

template <int BM, int BN, int MODE = 0, bool CMAJ = false>
static inline void mgemm(const __bf16* A, const __bf16* Bw, const float* bias,
                         const float* res, void* C, void* C2, int M, int N, int K,
                         int lda, int ldc, hipStream_t s) {
    dim3 g((N + BN - 1) / BN, (M + BM - 1) / BM);
    mgemm_k<BM, BN, MODE, CMAJ><<<g, 256, 0, s>>>(A, Bw, bias, res, C, C2, M, N, K, lda, ldc);
}

// ---------------- fused attention ----------------
#define KP_ 72    // K LDS row pad (bf16)
#define PP_ 232   // P LDS row pad (bf16)

__global__ __launch_bounds__(256) void attn_k(
    const __bf16* __restrict__ qb, const __bf16* __restrict__ kbb,
    const __bf16* __restrict__ vbT, __bf16* __restrict__ obb) {
    __shared__ __align__(16) __bf16 Ks[CTXP_ * KP_];
    __shared__ __align__(16) __bf16 Ps[64 * PP_];
    int z = blockIdx.z, b = z >> 3, h = z & 7;
    int tid = threadIdx.x, wave = tid >> 6, lane = tid & 63;
    int fr = lane & 15, fk = lane >> 4;
    int q0 = blockIdx.y * 64;
    #pragma unroll
    for (int i = 0; i < 7; ++i) {
        int idx = i * 256 + tid;
        int r = idx >> 3, cu = (idx & 7) * 8;
        uint4 v = {0u, 0u, 0u, 0u};
        if (r < CTX_) v = *(const uint4*)(kbb + ((size_t)(b * CTX_ + r)) * DIM_ + h * HD_ + cu);
        *(uint4*)&Ks[r * KP_ + cu] = v;
    }
    bf16x8 aq[2];
    {
        int qrow = b * N_ + q0 + wave * 16 + fr;
        #pragma unroll
        for (int t = 0; t < 2; ++t)
            aq[t] = *(const bf16x8*)(qb + (size_t)qrow * DIM_ + h * HD_ + t * 32 + fk * 8);
    }
    __syncthreads();
    f32x4 acc[CTXF_] = {};
    #pragma unroll
    for (int t = 0; t < 2; ++t)
        #pragma unroll
        for (int cb = 0; cb < CTXF_; ++cb) {
            bf16x8 bg = *(const bf16x8*)&Ks[(cb * 16 + fr) * KP_ + t * 32 + fk * 8];
            acc[cb] = __builtin_amdgcn_mfma_f32_16x16x32_bf16(aq[t], bg, acc[cb], 0, 0, 0);
        }
    #pragma unroll
    for (int e = 0; e < 4; ++e) {
        float m = -1e30f;
        #pragma unroll
        for (int cb = 0; cb < CTXF_; ++cb) {
            float sv = acc[cb][e] * 0.125f;
            if (cb * 16 + fr >= CTX_) sv = -1e30f;
            acc[cb][e] = sv;
            m = fmaxf(m, sv);
        }
        m = dpp_max16(m);
        float ssum = 0.f;
        #pragma unroll
        for (int cb = 0; cb < CTXF_; ++cb) {
            float p = __expf(acc[cb][e] - m);
            acc[cb][e] = p;
            ssum += p;
        }
        ssum = dpp_red16(ssum);
        float inv = 1.f / ssum;
        #pragma unroll
        for (int cb = 0; cb < CTXF_; ++cb)
            Ps[(wave * 16 + fk * 4 + e) * PP_ + cb * 16 + fr] = (__bf16)(acc[cb][e] * inv);
        Ps[(wave * 16 + fk * 4 + e) * PP_ + 208 + fr] = (__bf16)0.f;
    }
    __syncthreads();
    f32x4 acc2[4] = {};
    const __bf16* vB = vbT + (size_t)z * HD_ * CTXP_;
    #pragma unroll
    for (int sl = 0; sl < 7; ++sl) {
        bf16x8 ap = *(const bf16x8*)&Ps[(wave * 16 + fr) * PP_ + sl * 32 + fk * 8];
        #pragma unroll
        for (int nf = 0; nf < 4; ++nf) {
            bf16x8 bv = *(const bf16x8*)(vB + (size_t)(nf * 16 + fr) * CTXP_ + sl * 32 + fk * 8);
            acc2[nf] = __builtin_amdgcn_mfma_f32_16x16x32_bf16(ap, bv, acc2[nf], 0, 0, 0);
        }
    }
    #pragma unroll
    for (int nf = 0; nf < 4; ++nf)
        #pragma unroll
        for (int e = 0; e < 4; ++e) {
            int gm = b * N_ + q0 + wave * 16 + fk * 4 + e;
            obb[(size_t)gm * DIM_ + h * HD_ + nf * 16 + fr] = (__bf16)acc2[nf][e];
        }
}

// ---------------- host side ----------------

extern "C" void kernel_launch(void* const* d_in, const int* in_sizes, int n_in,
                              void* d_out, int out_size, void* d_ws, size_t ws_size,
                              hipStream_t stream) {
    const int*   text   = (const int*)d_in[0];
    const float* images = (const float*)d_in[1];
    const float* alphap = (const float*)d_in[2];
    const float* dgam   = (const float*)d_in[3];
    const float* dbeta  = (const float*)d_in[4];
    const float* imgW   = (const float*)d_in[5];
    const float* imgb   = (const float*)d_in[6];
    const float* g1W    = (const float*)d_in[7];
    const float* g1b    = (const float*)d_in[8];
    const float* g2W    = (const float*)d_in[9];
    const float* g2b    = (const float*)d_in[10];
    const float* temb   = (const float*)d_in[11];
    const float* pemb   = (const float*)d_in[12];
    const float* ln1g   = (const float*)d_in[13];
    const float* ln1b   = (const float*)d_in[14];
    const float* inW    = (const float*)d_in[15];
    const float* convW  = (const float*)d_in[16];
    const float* convb  = (const float*)d_in[17];
    const float* xpW    = (const float*)d_in[18];
    const float* dtW    = (const float*)d_in[19];
    const float* dtb    = (const float*)d_in[20];
    const float* Alog   = (const float*)d_in[21];
    const float* Dsk    = (const float*)d_in[22];
    const float* outW   = (const float*)d_in[23];
    const float* ln2g   = (const float*)d_in[24];
    const float* ln2b   = (const float*)d_in[25];
    const float* ainW   = (const float*)d_in[26];
    const float* ainb   = (const float*)d_in[27];
    const float* aoutW  = (const float*)d_in[28];
    const float* aoutb  = (const float*)d_in[29];
    const float* fng    = (const float*)d_in[30];
    const float* fnb    = (const float*)d_in[31];
    const float* lgW    = (const float*)d_in[32];
    const float* lgb    = (const float*)d_in[33];
    float* out = (float*)d_out;

    float* w = (float*)d_ws;
    float* imgd   = w; w += (size_t)B_ * CTX_ * IMGD_;   // bf16 dyt out (aliased)
    float* imgf   = w; w += (size_t)B_ * CTX_ * DIM_;
    float* pooled = w; w += B_ * DIM_;
    float* g1     = w; w += B_ * 128;
    float* gate   = w; w += B_ * DIM_;
    float* x      = w; w += (size_t)B_ * N_ * DIM_;
    float* xn     = w; w += (size_t)B_ * N_ * DIM_;      // bf16 ln out (aliased)
    float* dblb   = w; w += (size_t)B_ * N_ * 64;
    // bf16 buffers
    __bf16* xzb   = (__bf16*)w; w += (size_t)B_ * N_ * 2 * DIN_ / 2;
    __bf16* xcb   = (__bf16*)w; w += (size_t)B_ * N_ * DIN_ / 2;
    __bf16* imgfb = (__bf16*)w; w += (size_t)B_ * CTX_ * DIM_ / 2;
    __bf16* ybb   = (__bf16*)w; w += (size_t)B_ * N_ * DIN_ / 2;
    __bf16* qb    = (__bf16*)w; w += (size_t)B_ * N_ * DIM_ / 2;
    __bf16* kbb   = (__bf16*)w; w += (size_t)DEPTH_ * B_ * CTX_ * DIM_ / 2;
    __bf16* vbT   = (__bf16*)w; w += (size_t)DEPTH_ * B_ * HEADS_ * HD_ * CTXP_ / 2;
    __bf16* obb   = (__bf16*)w; w += (size_t)B_ * N_ * DIM_ / 2;
    __bf16* lgT   = (__bf16*)w; w += (size_t)10000 * DIM_ / 2;
    // bf16 weights
    __bf16* inpT  = (__bf16*)w; w += (size_t)DEPTH_ * 2 * DIN_ * DIM_ / 2;
    __bf16* outpT = (__bf16*)w; w += (size_t)DEPTH_ * DIM_ * DIN_ / 2;
    __bf16* qWB   = (__bf16*)w; w += (size_t)DEPTH_ * DIM_ * DIM_ / 2;
    __bf16* kvWB  = (__bf16*)w; w += (size_t)DEPTH_ * 2 * DIM_ * DIM_ / 2;
    __bf16* aoutB = (__bf16*)w; w += (size_t)DEPTH_ * DIM_ * DIM_ / 2;
    __bf16* imgWT = (__bf16*)w; w += (size_t)DIM_ * IMGD_ / 2;
    __bf16* xpWT  = (__bf16*)w; w += (size_t)DEPTH_ * 64 * DIN_ / 2;
    __bf16* imgdb = (__bf16*)imgd;
    __bf16* xnb   = (__bf16*)xn;

    const int TOKENS = B_ * N_;
    const int IMGT   = B_ * CTX_;

    // zero all layers' vbT pad columns once
    hipMemsetAsync(vbT, 0, (size_t)DEPTH_ * B_ * HEADS_ * HD_ * CTXP_ * sizeof(__bf16), stream);

    // ---- weight prep ----
    tconv_kernel<<<dim3(2 * DIN_ / 32, DIM_ / 32, DEPTH_), 256, 0, stream>>>(inW,  inpT,  DIM_, 2 * DIN_);
    tconv_kernel<<<dim3(DIM_ / 32, DIN_ / 32, DEPTH_),     256, 0, stream>>>(outW, outpT, DIN_, DIM_);
    tconv_kernel<<<dim3(DIM_ / 32, IMGD_ / 32, 1),         256, 0, stream>>>(imgW, imgWT, IMGD_, DIM_);
    tconv_kernel<<<dim3(64 / 32, DIN_ / 32, DEPTH_),       256, 0, stream>>>(xpW,  xpWT,  DIN_, 64);
    tconv_kernel<<<dim3((10000 + 31) / 32, DIM_ / 32, 1),  256, 0, stream>>>(lgW, lgT, DIM_, 10000);
    cvt_rows_kernel<<<(DEPTH_ * DIM_ * (DIM_ / 4) + 255) / 256, 256, 0, stream>>>(
        ainW, qWB, DEPTH_ * DIM_, DIM_, 0);
    cvt_rows_kernel<<<(DEPTH_ * 2 * DIM_ * (DIM_ / 4) + 255) / 256, 256, 0, stream>>>(
        ainW, kvWB, DEPTH_ * 2 * DIM_, 2 * DIM_, DIM_);
    cvt_bf16_kernel<<<(DEPTH_ * DIM_ * DIM_ / 4 + 255) / 256, 256, 0, stream>>>(aoutW, aoutB, DEPTH_ * DIM_ * DIM_);

    // ---- image path ----
    {
        int total = B_ * CTX_ * IMGD_;
        dyt_kernel<<<(total + 255) / 256, 256, 0, stream>>>(images, alphap, dgam, dbeta, imgdb, total);
        mgemm<32, 64>(imgdb, imgWT, imgb, nullptr, imgf, nullptr, IMGT, DIM_, IMGD_, IMGD_, DIM_, stream);
        pool_kernel<<<(B_ * DIM_ + 255) / 256, 256, 0, stream>>>(imgf, pooled);
        gate1_kernel<<<(B_ * 128 + 255) / 256, 256, 0, stream>>>(pooled, g1W, g1b, g1);
        gate2_kernel<<<(B_ * DIM_ + 255) / 256, 256, 0, stream>>>(g1, g2W, g2b, gate);
        scale_kernel<<<(B_ * CTX_ * DIM_ + 255) / 256, 256, 0, stream>>>(imgf, gate, imgfb);
    }
    embed_kernel<<<(TOKENS * DIM_ + 255) / 256, 256, 0, stream>>>(text, temb, pemb, x);

    // ---- ALL layers' K/V projections in ONE batched GEMM (col-major slabs) ----
    mgemm<64, 128, 3, true>(imgfb, kvWB, nullptr, ainb, kbb, vbT,
                            IMGT, DEPTH_ * 2 * DIM_, DIM_, DIM_, 0, stream);

    for (int l = 0; l < DEPTH_; ++l) {
        const __bf16* inpT_l  = inpT  + (size_t)l * 2 * DIN_ * DIM_;
        const __bf16* outpT_l = outpT + (size_t)l * DIM_ * DIN_;
        const __bf16* qWB_l   = qWB   + (size_t)l * DIM_ * DIM_;
        const __bf16* aoutB_l = aoutB + (size_t)l * DIM_ * DIM_;
        const __bf16* xpWT_l  = xpWT  + (size_t)l * 64 * DIN_;
        const __bf16* kbb_l   = kbb   + (size_t)l * IMGT * DIM_;
        const __bf16* vbT_l   = vbT   + (size_t)l * B_ * HEADS_ * HD_ * CTXP_;
        const float* cw    = convW + (size_t)l * DIN_ * 4;
        const float* cb    = convb + (size_t)l * DIN_;
        const float* dtw   = dtW  + (size_t)l * DTR_ * DIN_;
        const float* dtbi  = dtb  + (size_t)l * DIN_;
        const float* alog  = Alog + (size_t)l * DIN_ * DST_;
        const float* dsk   = Dsk  + (size_t)l * DIN_;
        const float* ab    = ainb + (size_t)l * 3 * DIM_;
        const float* aob   = aoutb + (size_t)l * DIM_;

        // mamba block (bf16 activations end-to-end)
        ln_kernel<<<TOKENS / 4, 256, 0, stream>>>(x, ln1g + l * DIM_, ln1b + l * DIM_, xnb, TOKENS);
        mgemm<64, 128, 1>(xnb, inpT_l, nullptr, nullptr, xzb, nullptr, TOKENS, 2 * DIN_, DIM_, DIM_, 2 * DIN_, stream);
        conv_silu_kernel<<<(TOKENS * DIN_ / 4 + 255) / 256, 256, 0, stream>>>(xzb, cw, cb, xcb);
        mgemm<32, 64>(xcb, xpWT_l, nullptr, nullptr, dblb, nullptr, TOKENS, 64, DIN_, DIN_, 64, stream);
        scanf_kernel<<<B_ * DIN_ / DG_, 256, 0, stream>>>(xcb, dblb, xzb, dtw, dtbi, alog, dsk, ybb);
        mgemm<32, 64>(ybb, outpT_l, nullptr, x, x, nullptr, TOKENS, DIM_, DIN_, DIN_, DIM_, stream);

        // cross-attention block
        ln_kernel<<<TOKENS / 4, 256, 0, stream>>>(x, ln2g + l * DIM_, ln2b + l * DIM_, xnb, TOKENS);
        mgemm<32, 64, 1>(xnb, qWB_l, ab, nullptr, qb, nullptr, TOKENS, DIM_, DIM_, DIM_, DIM_, stream);
        attn_k<<<dim3(1, 4, B_ * HEADS_), 256, 0, stream>>>(qb, kbb_l, vbT_l, obb);
        mgemm<32, 64>(obb, aoutB_l, aob, x, x, nullptr, TOKENS, DIM_, DIM_, DIM_, DIM_, stream);
    }

    // final LN + logits (128x128 col-major slabs, two-half float4 LDS epilogue)
    ln_kernel<<<TOKENS / 4, 256, 0, stream>>>(x, fng, fnb, xnb, TOKENS);
    mgemm<128, 128, 0, true>(xnb, lgT, lgb, nullptr, out, nullptr, TOKENS, 10000, DIM_, DIM_, 10000, stream);
}

// Round 20
// 1123.090 us; speedup vs baseline: 1.0716x; 1.0034x over previous
//
#include <hip/hip_runtime.h>
#include <hip/hip_bf16.h>
#include <stdint.h>

#define B_    8
#define N_    256
#define CTX_  196
#define CTXP_ 224   // ctx padded to multiple of 32 for PV K-loop
#define CTXF_ 13    // score col frags (13*16 = 208 >= 196)
#define IMGD_ 1024
#define DIM_  512
#define DEPTH_ 6
#define DIN_  1024
#define DTR_  32
#define DST_  16
#define HEADS_ 8
#define HD_   64
#define NCHUNK_ 16
#define CLEN_   16   // N_/NCHUNK_
#define DG_     4    // d's per scan block

typedef __bf16 bf16x8 __attribute__((ext_vector_type(8)));
typedef __bf16 bf16x4 __attribute__((ext_vector_type(4)));
typedef float  f32x4  __attribute__((ext_vector_type(4)));

// 16-lane sum via DPP butterfly; all 16 lanes get total
__device__ __forceinline__ float dpp_red16(float v) {
    int y;
    y = __builtin_amdgcn_update_dpp(0, __float_as_int(v), 0xB1, 0xF, 0xF, true);
    v += __int_as_float(y);
    y = __builtin_amdgcn_update_dpp(0, __float_as_int(v), 0x4E, 0xF, 0xF, true);
    v += __int_as_float(y);
    y = __builtin_amdgcn_update_dpp(0, __float_as_int(v), 0x141, 0xF, 0xF, true);
    v += __int_as_float(y);
    y = __builtin_amdgcn_update_dpp(0, __float_as_int(v), 0x140, 0xF, 0xF, true);
    v += __int_as_float(y);
    return v;
}
__device__ __forceinline__ float dpp_max16(float v) {
    int y;
    y = __builtin_amdgcn_update_dpp(0, __float_as_int(v), 0xB1, 0xF, 0xF, true);
    v = fmaxf(v, __int_as_float(y));
    y = __builtin_amdgcn_update_dpp(0, __float_as_int(v), 0x4E, 0xF, 0xF, true);
    v = fmaxf(v, __int_as_float(y));
    y = __builtin_amdgcn_update_dpp(0, __float_as_int(v), 0x141, 0xF, 0xF, true);
    v = fmaxf(v, __int_as_float(y));
    y = __builtin_amdgcn_update_dpp(0, __float_as_int(v), 0x140, 0xF, 0xF, true);
    v = fmaxf(v, __int_as_float(y));
    return v;
}

// async global->LDS 16B (direct-to-LDS DMA; no VGPR round trip)
__device__ __forceinline__ void gload16(const void* g, void* l) {
    __builtin_amdgcn_global_load_lds(
        (const __attribute__((address_space(1))) uint32_t*)g,
        (__attribute__((address_space(3))) uint32_t*)l, 16, 0, 0);
}

// ---------------- elementwise / small kernels ----------------

__global__ void dyt_kernel(const float* __restrict__ img, const float* __restrict__ alpha_p,
                           const float* __restrict__ gamma, const float* __restrict__ beta,
                           __bf16* __restrict__ out, int total) {
    int i = blockIdx.x * 256 + threadIdx.x;
    if (i >= total) return;
    float a = alpha_p[0];
    int c = i & (IMGD_ - 1);
    out[i] = (__bf16)(gamma[c] * tanhf(a * img[i]) + beta[c]);
}

__global__ void pool_kernel(const float* __restrict__ imgf, float* __restrict__ pooled) {
    int i = blockIdx.x * 256 + threadIdx.x;
    if (i >= B_ * DIM_) return;
    int b = i >> 9, c = i & (DIM_ - 1);
    const float* p = imgf + (size_t)b * CTX_ * DIM_ + c;
    float s = 0.f;
    for (int t = 0; t < CTX_; ++t) s += p[t * DIM_];
    pooled[i] = s * (1.f / CTX_);
}

__global__ void gate1_kernel(const float* __restrict__ pooled, const float* __restrict__ W,
                             const float* __restrict__ bias, float* __restrict__ g1) {
    int i = blockIdx.x * 256 + threadIdx.x;
    if (i >= B_ * 128) return;
    int b = i >> 7, j = i & 127;
    const float* p = pooled + b * DIM_;
    float s = bias[j];
    for (int c = 0; c < DIM_; ++c) s += p[c] * W[c * 128 + j];
    g1[i] = 0.5f * s * (1.f + erff(s * 0.70710678118654752f));
}

__global__ void gate2_kernel(const float* __restrict__ g1, const float* __restrict__ W,
                             const float* __restrict__ bias, float* __restrict__ gate) {
    int i = blockIdx.x * 256 + threadIdx.x;
    if (i >= B_ * DIM_) return;
    int b = i >> 9, c = i & (DIM_ - 1);
    const float* p = g1 + b * 128;
    float s = bias[c];
    for (int j = 0; j < 128; ++j) s += p[j] * W[j * DIM_ + c];
    gate[i] = 1.f / (1.f + __expf(-s));
}

__global__ void scale_kernel(const float* __restrict__ imgf, const float* __restrict__ gate,
                             __bf16* __restrict__ imgfb) {
    int i = blockIdx.x * 256 + threadIdx.x;
    if (i >= B_ * CTX_ * DIM_) return;
    int c = i & (DIM_ - 1);
    int b = i / (CTX_ * DIM_);
    imgfb[i] = (__bf16)(imgf[i] * gate[b * DIM_ + c]);
}

__global__ void embed_kernel(const int* __restrict__ text, const float* __restrict__ temb,
                             const float* __restrict__ pemb, float* __restrict__ x) {
    int i = blockIdx.x * 256 + threadIdx.x;
    if (i >= B_ * N_ * DIM_) return;
    int c = i & (DIM_ - 1);
    int row = i >> 9;
    int n = row & (N_ - 1);
    int tok = text[row];
    x[i] = temb[(size_t)tok * DIM_ + c] + pemb[(size_t)n * DIM_ + c];
}

// wave-per-row layernorm, row = 512 floats, bf16 output
__global__ void ln_kernel(const float* __restrict__ x, const float* __restrict__ g,
                          const float* __restrict__ b, __bf16* __restrict__ o, int rows) {
    int row = blockIdx.x * 4 + (threadIdx.x >> 6);
    if (row >= rows) return;
    int lane = threadIdx.x & 63;
    const float* xr = x + (size_t)row * DIM_ + lane * 8;
    float4 v0 = ((const float4*)xr)[0];
    float4 v1 = ((const float4*)xr)[1];
    float r[8] = {v0.x, v0.y, v0.z, v0.w, v1.x, v1.y, v1.z, v1.w};
    float sum = 0.f, sq = 0.f;
    #pragma unroll
    for (int j = 0; j < 8; ++j) { sum += r[j]; sq += r[j] * r[j]; }
    #pragma unroll
    for (int m = 1; m < 64; m <<= 1) { sum += __shfl_xor(sum, m); sq += __shfl_xor(sq, m); }
    float mean = sum * (1.f / DIM_);
    float var  = sq * (1.f / DIM_) - mean * mean;
    float inv  = rsqrtf(fmaxf(var, 0.f) + 1e-5f);
    const float* gp = g + lane * 8;
    const float* bp = b + lane * 8;
    __bf16* op = o + (size_t)row * DIM_ + lane * 8;
    bf16x8 ov;
    #pragma unroll
    for (int j = 0; j < 8; ++j) ov[j] = (__bf16)((r[j] - mean) * inv * gp[j] + bp[j]);
    *(bf16x8*)op = ov;
}

// causal depthwise conv (4 taps) + SiLU; bf16 in (xzb), bf16 out (xcb)
__global__ void conv_silu_kernel(const __bf16* __restrict__ xzb, const float* __restrict__ cw,
                                 const float* __restrict__ cb, __bf16* __restrict__ xcb) {
    int idx = blockIdx.x * 256 + threadIdx.x;
    if (idx >= B_ * N_ * DIN_ / 4) return;
    int i4 = idx * 4;
    int d = i4 & (DIN_ - 1);
    int row = i4 >> 10;
    int n = row & (N_ - 1);
    int rowb = row - n;
    float4 acc = *(const float4*)(cb + d);
    #pragma unroll
    for (int k = 0; k < 4; ++k) {
        int m = n - 3 + k;
        if (m >= 0) {
            bf16x4 v = *(const bf16x4*)(xzb + (size_t)(rowb + m) * (2 * DIN_) + d);
            acc.x += (float)v[0] * cw[(d + 0) * 4 + k];
            acc.y += (float)v[1] * cw[(d + 1) * 4 + k];
            acc.z += (float)v[2] * cw[(d + 2) * 4 + k];
            acc.w += (float)v[3] * cw[(d + 3) * 4 + k];
        }
    }
    bf16x4 p;
    p[0] = (__bf16)(acc.x / (1.f + __expf(-acc.x)));
    p[1] = (__bf16)(acc.y / (1.f + __expf(-acc.y)));
    p[2] = (__bf16)(acc.z / (1.f + __expf(-acc.z)));
    p[3] = (__bf16)(acc.w / (1.f + __expf(-acc.w)));
    *(bf16x4*)(xcb + i4) = p;
}

__global__ void cvt_bf16_kernel(const float* __restrict__ src, __bf16* __restrict__ dst, int count) {
    int i = (blockIdx.x * 256 + threadIdx.x) * 4;
    if (i >= count) return;
    float4 v = *(const float4*)(src + i);
    bf16x4 p = {(__bf16)v.x, (__bf16)v.y, (__bf16)v.z, (__bf16)v.w};
    *(bf16x4*)(dst + i) = p;
}

// row-sliced convert: dst row i (K=512) <- src row (i/rpl)*1536 + off + (i%rpl)
__global__ void cvt_rows_kernel(const float* __restrict__ src, __bf16* __restrict__ dst,
                                int totalRows, int rpl, int off) {
    int t = blockIdx.x * 256 + threadIdx.x;
    int total = totalRows * (DIM_ / 4);
    if (t >= total) return;
    int i = t / (DIM_ / 4), c4 = (t % (DIM_ / 4)) * 4;
    int l = i / rpl, r = i % rpl;
    const float* s = src + ((size_t)l * 1536 + off + r) * DIM_ + c4;
    float4 v = *(const float4*)s;
    bf16x4 p = {(__bf16)v.x, (__bf16)v.y, (__bf16)v.z, (__bf16)v.w};
    *(bf16x4*)(dst + (size_t)i * DIM_ + c4) = p;
}

// ---------------- fused selective scan v5: 4 d's per block, bf16 activations ----
__global__ __launch_bounds__(256) void scanf_kernel(
    const __bf16* __restrict__ xcb, const float* __restrict__ dbl,
    const __bf16* __restrict__ xzb, const float* __restrict__ dtw,
    const float* __restrict__ dtb, const float* __restrict__ A_log,
    const float* __restrict__ Dsk, __bf16* __restrict__ ybb) {
    __shared__ float sdt[DG_][N_], su[DG_][N_];
    __shared__ float sA[DG_][256], sB[DG_][256];
    int bid = blockIdx.x;
    int nwg = gridDim.x;                       // 2048, % 8 == 0
    int bd = (bid & 7) * (nwg >> 3) + (bid >> 3);   // bijective XCD swizzle
    int dg = bd & (DIN_ / DG_ - 1), b = bd / (DIN_ / DG_);
    int d0 = dg * DG_;
    int tid = threadIdx.x, s = tid & 15, c = tid >> 4;
    {
        int row = b * N_ + tid;
        const float* dp = dbl + row * 64;
        float4 acc = *(const float4*)(dtb + d0);
        #pragma unroll
        for (int k = 0; k < DTR_; k += 4) {
            float4 dv = *(const float4*)(dp + k);
            float4 w0 = *(const float4*)(dtw + (k + 0) * DIN_ + d0);
            float4 w1 = *(const float4*)(dtw + (k + 1) * DIN_ + d0);
            float4 w2 = *(const float4*)(dtw + (k + 2) * DIN_ + d0);
            float4 w3 = *(const float4*)(dtw + (k + 3) * DIN_ + d0);
            acc.x += dv.x * w0.x + dv.y * w1.x + dv.z * w2.x + dv.w * w3.x;
            acc.y += dv.x * w0.y + dv.y * w1.y + dv.z * w2.y + dv.w * w3.y;
            acc.z += dv.x * w0.z + dv.y * w1.z + dv.z * w2.z + dv.w * w3.z;
            acc.w += dv.x * w0.w + dv.y * w1.w + dv.z * w2.w + dv.w * w3.w;
        }
        bf16x4 xcv4 = *(const bf16x4*)(xcb + (size_t)row * DIN_ + d0);
        float av[4] = {acc.x, acc.y, acc.z, acc.w};
        float xv[4] = {(float)xcv4[0], (float)xcv4[1], (float)xcv4[2], (float)xcv4[3]};
        #pragma unroll
        for (int g = 0; g < DG_; ++g) {
            float dt = fmaxf(av[g], 0.f) + __logf(1.f + __expf(-fabsf(av[g])));
            sdt[g][tid] = dt;
            su[g][tid] = dt * xv[g];
        }
    }
    float As4[DG_];
    #pragma unroll
    for (int g = 0; g < DG_; ++g) As4[g] = -__expf(A_log[((d0 + g) << 4) | s]);
    __syncthreads();
    int r0 = c * CLEN_;
    int row0 = b * N_ + r0;
    float a[DG_], hb[DG_];
    #pragma unroll
    for (int g = 0; g < DG_; ++g) { a[g] = 1.f; hb[g] = 0.f; }
    #pragma unroll 2
    for (int n = 0; n < CLEN_; ++n) {
        float Bv = dbl[(row0 + n) * 64 + 32 + s];
        #pragma unroll
        for (int g = 0; g < DG_; ++g) {
            float dA = __expf(sdt[g][r0 + n] * As4[g]);
            hb[g] = hb[g] * dA + su[g][r0 + n] * Bv;
            a[g] *= dA;
        }
    }
    #pragma unroll
    for (int g = 0; g < DG_; ++g) { sA[g][tid] = a[g]; sB[g][tid] = hb[g]; }
    __syncthreads();
    float h[DG_];
    #pragma unroll
    for (int g = 0; g < DG_; ++g) h[g] = 0.f;
    for (int j = 0; j < c; ++j)
        #pragma unroll
        for (int g = 0; g < DG_; ++g)
            h[g] = h[g] * sA[g][j * 16 + s] + sB[g][j * 16 + s];
    float4 Dv4 = *(const float4*)(Dsk + d0);
    float Dv[4] = {Dv4.x, Dv4.y, Dv4.z, Dv4.w};
    #pragma unroll 2
    for (int n = 0; n < CLEN_; ++n) {
        int row = row0 + n;
        float Bv = dbl[row * 64 + 32 + s];
        float Cv = dbl[row * 64 + 48 + s];
        float p[DG_];
        #pragma unroll
        for (int g = 0; g < DG_; ++g) {
            float dA = __expf(sdt[g][r0 + n] * As4[g]);
            h[g] = h[g] * dA + su[g][r0 + n] * Bv;
            p[g] = dpp_red16(h[g] * Cv);
        }
        if (s == 0) {
            bf16x4 xcv4 = *(const bf16x4*)(xcb + (size_t)row * DIN_ + d0);
            bf16x4 zz4  = *(const bf16x4*)(xzb + (size_t)row * (2 * DIN_) + DIN_ + d0);
            bf16x4 yo;
            #pragma unroll
            for (int g = 0; g < DG_; ++g) {
                float xv = (float)xcv4[g];
                float zv = (float)zz4[g];
                float y = (p[g] + xv * Dv[g]) * (zv / (1.f + __expf(-zv)));
                yo[g] = (__bf16)y;
            }
            *(bf16x4*)(ybb + (size_t)row * DIN_ + d0) = yo;
        }
    }
}

// ---------------- weight prep ----------------

__global__ void tconv_kernel(const float* __restrict__ src, __bf16* __restrict__ dst,
                             int K, int N) {
    __shared__ float tile[32][33];
    int n0 = blockIdx.x * 32, k0 = blockIdx.y * 32;
    src += (size_t)blockIdx.z * K * N;
    dst += (size_t)blockIdx.z * K * N;
    int tx = threadIdx.x & 31, ty = threadIdx.x >> 5;
    #pragma unroll
    for (int i = 0; i < 32; i += 8) {
        int k = k0 + ty + i, n = n0 + tx;
        tile[ty + i][tx] = (k < K && n < N) ? src[(size_t)k * N + n] : 0.f;
    }
    __syncthreads();
    #pragma unroll
    for (int i = 0; i < 32; i += 8) {
        int n = n0 + ty + i, k = k0 + tx;
        if (n < N && k < K) dst[(size_t)n * K + k] = (__bf16)tile[tx][ty + i];
    }
}

// ---------------- bf16 MFMA GEMM v3/v4 ----------------
// MODE 0: fp32 out (+res), two-half LDS-transposed float4 epilogue.
// MODE 1: bf16 out. MODE 3: batched-kv epilogue.
// CMAJ: column-major block mapping for N >> M shapes (kv, logits).
// PIPE3: 3-buffer, 2-deep prefetch with COUNTED vmcnt + raw barriers (T3/T4):
//   per iter: vmcnt(LPT)+bar (buf t ready) -> ds_read+MFMA -> bar -> stage t+2.
//   One stage always stays in flight across the barrier (no full drain).

template <int BM, int BN, int MODE, bool CMAJ = false, bool PIPE3 = false>
__global__ __launch_bounds__(256) void mgemm_k(
    const __bf16* __restrict__ A, const __bf16* __restrict__ Bw,
    const float* __restrict__ bias, const float* __restrict__ res,
    void* __restrict__ Cp, void* __restrict__ Cp2,
    int M, int N, int K, int lda, int ldc) {
    constexpr int UA = BM * 4;   // 16B units per 32-K slab tile
    constexpr int UB = BN * 4;
    constexpr int FM = BM / 32, FN = BN / 32;
    constexpr int NBUF = PIPE3 ? 3 : 2;
    constexpr int LPT = UA / 256 + UB / 256;   // loads per thread per stage
    static_assert(!PIPE3 || (UA % 256 == 0 && UB % 256 == 0), "PIPE3 needs uniform loads");
    constexpr int CPAD = BN + 4;                           // padded LDS C row
    constexpr int STAGE_B = NBUF * (UA + UB) * 16;
    constexpr int CS_B    = (MODE == 0) ? (BM / 2) * CPAD * 4 : 0;
    constexpr int SMEM_B  = STAGE_B > CS_B ? STAGE_B : CS_B;
    __shared__ __align__(16) char smem[SMEM_B];
    __bf16* As = (__bf16*)smem;                            // [NBUF][UA*8]
    __bf16* Bs = (__bf16*)(smem + (size_t)NBUF * UA * 16); // [NBUF][UB*8]
    int tid = threadIdx.x;
    int ntx = gridDim.x;
    int nwg = ntx * gridDim.y;
    int bid = blockIdx.y * ntx + blockIdx.x;
    if ((nwg & 7) == 0) bid = (bid & 7) * (nwg >> 3) + (bid >> 3);
    int row0, col0;
    if constexpr (CMAJ) {
        int nty = nwg / ntx;
        row0 = (bid % nty) * BM;
        col0 = (bid / nty) * BN;
    } else {
        row0 = (bid / ntx) * BM;
        col0 = (bid % ntx) * BN;
    }
    int wave = tid >> 6, lane = tid & 63;
    int wm = (wave >> 1) * (BM / 2), wn = (wave & 1) * (BN / 2);
    int fr = lane & 15, fk = lane >> 4;
    f32x4 acc[FM][FN] = {};

    auto stage = [&](int buf, int k0) {
        #pragma unroll
        for (int j = 0; j < (UA + 255) / 256; ++j) {
            int u = j * 256 + tid;
            if ((UA & 255) == 0 || u < UA) {
                int ks = u / BM, r = u % BM;
                gload16(A + (size_t)(row0 + r) * lda + k0 + ks * 8, &As[((size_t)buf * UA + u) * 8]);
            }
        }
        #pragma unroll
        for (int j = 0; j < (UB + 255) / 256; ++j) {
            int u = j * 256 + tid;
            if ((UB & 255) == 0 || u < UB) {
                int ks = u / BN, r = u % BN;
                gload16(Bw + (size_t)(col0 + r) * K + k0 + ks * 8, &Bs[((size_t)buf * UB + u) * 8]);
            }
        }
    };
    auto mfma_step = [&](int cur) {
        bf16x8 af[FM], bg[FN];
        #pragma unroll
        for (int mf = 0; mf < FM; ++mf)
            af[mf] = *(const bf16x8*)&As[((size_t)cur * UA + fk * BM + wm + mf * 16 + fr) * 8];
        #pragma unroll
        for (int nf = 0; nf < FN; ++nf)
            bg[nf] = *(const bf16x8*)&Bs[((size_t)cur * UB + fk * BN + wn + nf * 16 + fr) * 8];
        #pragma unroll
        for (int mf = 0; mf < FM; ++mf)
            #pragma unroll
            for (int nf = 0; nf < FN; ++nf)
                acc[mf][nf] = __builtin_amdgcn_mfma_f32_16x16x32_bf16(af[mf], bg[nf], acc[mf][nf], 0, 0, 0);
    };

    int NK = K >> 5;
    if constexpr (PIPE3) {
        stage(0, 0);
        if (NK > 1) stage(1, 32);
        for (int kt = 0; kt < NK; ++kt) {
            if (kt + 1 < NK) {
                if constexpr (LPT == 3) asm volatile("s_waitcnt vmcnt(3)" ::: "memory");
                else                    asm volatile("s_waitcnt vmcnt(4)" ::: "memory");
            } else {
                asm volatile("s_waitcnt vmcnt(0)" ::: "memory");
            }
            asm volatile("s_barrier" ::: "memory");
            mfma_step(kt % 3);
            asm volatile("s_barrier" ::: "memory");
            if (kt + 2 < NK) stage((kt + 2) % 3, (kt + 2) << 5);
        }
    } else {
        stage(0, 0);
        __syncthreads();
        for (int kt = 0; kt < NK; ++kt) {
            int cur = kt & 1;
            if (kt + 1 < NK) stage(cur ^ 1, (kt + 1) << 5);
            mfma_step(cur);
            __syncthreads();
        }
    }
    if constexpr (MODE == 0) {
        // Two-half LDS-transposed epilogue (half-size padded C overlay).
        float* Cs = (float*)smem;
        #pragma unroll
        for (int half = 0; half < 2; ++half) {
            if (wm == half * (BM / 2)) {
                #pragma unroll
                for (int mf = 0; mf < FM; ++mf)
                    #pragma unroll
                    for (int nf = 0; nf < FN; ++nf)
                        #pragma unroll
                        for (int e = 0; e < 4; ++e)
                            Cs[(mf * 16 + fk * 4 + e) * CPAD + wn + nf * 16 + fr] = acc[mf][nf][e];
            }
            __syncthreads();
            for (int u = tid; u < (BM / 2) * BN / 4; u += 256) {
                int r = u / (BN / 4), c4 = (u % (BN / 4)) * 4;
                int gm = row0 + half * (BM / 2) + r, gn = col0 + c4;
                if (gm < M && gn < N) {
                    f32x4 v = *(const f32x4*)&Cs[r * CPAD + c4];
                    if (bias) v += *(const f32x4*)(bias + gn);
                    size_t idx = (size_t)gm * ldc + gn;
                    if (res) v += *(const f32x4*)(res + idx);
                    *(f32x4*)((float*)Cp + idx) = v;
                }
            }
            __syncthreads();
        }
    } else {
        #pragma unroll
        for (int mf = 0; mf < FM; ++mf) {
            #pragma unroll
            for (int nf = 0; nf < FN; ++nf) {
                int gn = col0 + wn + nf * 16 + fr;
                if (gn >= N) continue;
                float bb = (MODE != 3 && bias) ? bias[gn] : 0.f;
                #pragma unroll
                for (int e = 0; e < 4; ++e) {
                    int gm = row0 + wm + mf * 16 + fk * 4 + e;
                    if (gm >= M) continue;
                    float v = acc[mf][nf][e] + bb;
                    if constexpr (MODE == 1) {
                        ((__bf16*)Cp)[(size_t)gm * ldc + gn] = (__bf16)v;
                    } else {
                        int l = gn >> 10, j = gn & 1023;
                        float vb = v + res[l * 1536 + 512 + j];  // ainb[l][512+j]
                        if (j < DIM_) {
                            ((__bf16*)Cp)[(size_t)l * (B_ * CTX_) * DIM_ + (size_t)gm * DIM_ + j] = (__bf16)vb;
                        } else {
                            int jj = j - DIM_;
                            int bimg = gm / CTX_, k = gm - bimg * CTX_;
                            ((__bf16*)Cp2)[(((size_t)l * B_ * HEADS_ + bimg * HEADS_ + (jj >> 6)) * HD_ + (jj & 63)) * CTXP_ + k] = (__bf16)vb;
                        }
                    }
                }
            }
        }
    }
}

template <int BM, int BN, int MODE = 0, bool CMAJ = false, bool PIPE3 = false>
static inline void mgemm(const __bf16* A, const __bf16* Bw, const float* bias,
                         const float* res, void* C, void* C2, int M, int N, int K,
                         int lda, int ldc, hipStream_t s) {
    dim3 g((N + BN - 1) / BN, (M + BM - 1) / BM);
    mgemm_k<BM, BN, MODE, CMAJ, PIPE3><<<g, 256, 0, s>>>(A, Bw, bias, res, C, C2, M, N, K, lda, ldc);
}

// ---------------- fused attention ----------------
#define KP_ 72    // K LDS row pad (bf16)
#define PP_ 232   // P LDS row pad (bf16)

__global__ __launch_bounds__(256) void attn_k(
    const __bf16* __restrict__ qb, const __bf16* __restrict__ kbb,
    const __bf16* __restrict__ vbT, __bf16* __restrict__ obb) {
    __shared__ __align__(16) __bf16 Ks[CTXP_ * KP_];
    __shared__ __align__(16) __bf16 Ps[64 * PP_];
    int z = blockIdx.z, b = z >> 3, h = z & 7;
    int tid = threadIdx.x, wave = tid >> 6, lane = tid & 63;
    int fr = lane & 15, fk = lane >> 4;
    int q0 = blockIdx.y * 64;
    #pragma unroll
    for (int i = 0; i < 7; ++i) {
        int idx = i * 256 + tid;
        int r = idx >> 3, cu = (idx & 7) * 8;
        uint4 v = {0u, 0u, 0u, 0u};
        if (r < CTX_) v = *(const uint4*)(kbb + ((size_t)(b * CTX_ + r)) * DIM_ + h * HD_ + cu);
        *(uint4*)&Ks[r * KP_ + cu] = v;
    }
    bf16x8 aq[2];
    {
        int qrow = b * N_ + q0 + wave * 16 + fr;
        #pragma unroll
        for (int t = 0; t < 2; ++t)
            aq[t] = *(const bf16x8*)(qb + (size_t)qrow * DIM_ + h * HD_ + t * 32 + fk * 8);
    }
    __syncthreads();
    f32x4 acc[CTXF_] = {};
    #pragma unroll
    for (int t = 0; t < 2; ++t)
        #pragma unroll
        for (int cb = 0; cb < CTXF_; ++cb) {
            bf16x8 bg = *(const bf16x8*)&Ks[(cb * 16 + fr) * KP_ + t * 32 + fk * 8];
            acc[cb] = __builtin_amdgcn_mfma_f32_16x16x32_bf16(aq[t], bg, acc[cb], 0, 0, 0);
        }
    #pragma unroll
    for (int e = 0; e < 4; ++e) {
        float m = -1e30f;
        #pragma unroll
        for (int cb = 0; cb < CTXF_; ++cb) {
            float sv = acc[cb][e] * 0.125f;
            if (cb * 16 + fr >= CTX_) sv = -1e30f;
            acc[cb][e] = sv;
            m = fmaxf(m, sv);
        }
        m = dpp_max16(m);
        float ssum = 0.f;
        #pragma unroll
        for (int cb = 0; cb < CTXF_; ++cb) {
            float p = __expf(acc[cb][e] - m);
            acc[cb][e] = p;
            ssum += p;
        }
        ssum = dpp_red16(ssum);
        float inv = 1.f / ssum;
        #pragma unroll
        for (int cb = 0; cb < CTXF_; ++cb)
            Ps[(wave * 16 + fk * 4 + e) * PP_ + cb * 16 + fr] = (__bf16)(acc[cb][e] * inv);
        Ps[(wave * 16 + fk * 4 + e) * PP_ + 208 + fr] = (__bf16)0.f;
    }
    __syncthreads();
    f32x4 acc2[4] = {};
    const __bf16* vB = vbT + (size_t)z * HD_ * CTXP_;
    #pragma unroll
    for (int sl = 0; sl < 7; ++sl) {
        bf16x8 ap = *(const bf16x8*)&Ps[(wave * 16 + fr) * PP_ + sl * 32 + fk * 8];
        #pragma unroll
        for (int nf = 0; nf < 4; ++nf) {
            bf16x8 bv = *(const bf16x8*)(vB + (size_t)(nf * 16 + fr) * CTXP_ + sl * 32 + fk * 8);
            acc2[nf] = __builtin_amdgcn_mfma_f32_16x16x32_bf16(ap, bv, acc2[nf], 0, 0, 0);
        }
    }
    #pragma unroll
    for (int nf = 0; nf < 4; ++nf)
        #pragma unroll
        for (int e = 0; e < 4; ++e) {
            int gm = b * N_ + q0 + wave * 16 + fk * 4 + e;
            obb[(size_t)gm * DIM_ + h * HD_ + nf * 16 + fr] = (__bf16)acc2[nf][e];
        }
}

// ---------------- host side ----------------

extern "C" void kernel_launch(void* const* d_in, const int* in_sizes, int n_in,
                              void* d_out, int out_size, void* d_ws, size_t ws_size,
                              hipStream_t stream) {
    const int*   text   = (const int*)d_in[0];
    const float* images = (const float*)d_in[1];
    const float* alphap = (const float*)d_in[2];
    const float* dgam   = (const float*)d_in[3];
    const float* dbeta  = (const float*)d_in[4];
    const float* imgW   = (const float*)d_in[5];
    const float* imgb   = (const float*)d_in[6];
    const float* g1W    = (const float*)d_in[7];
    const float* g1b    = (const float*)d_in[8];
    const float* g2W    = (const float*)d_in[9];
    const float* g2b    = (const float*)d_in[10];
    const float* temb   = (const float*)d_in[11];
    const float* pemb   = (const float*)d_in[12];
    const float* ln1g   = (const float*)d_in[13];
    const float* ln1b   = (const float*)d_in[14];
    const float* inW    = (const float*)d_in[15];
    const float* convW  = (const float*)d_in[16];
    const float* convb  = (const float*)d_in[17];
    const float* xpW    = (const float*)d_in[18];
    const float* dtW    = (const float*)d_in[19];
    const float* dtb    = (const float*)d_in[20];
    const float* Alog   = (const float*)d_in[21];
    const float* Dsk    = (const float*)d_in[22];
    const float* outW   = (const float*)d_in[23];
    const float* ln2g   = (const float*)d_in[24];
    const float* ln2b   = (const float*)d_in[25];
    const float* ainW   = (const float*)d_in[26];
    const float* ainb   = (const float*)d_in[27];
    const float* aoutW  = (const float*)d_in[28];
    const float* aoutb  = (const float*)d_in[29];
    const float* fng    = (const float*)d_in[30];
    const float* fnb    = (const float*)d_in[31];
    const float* lgW    = (const float*)d_in[32];
    const float* lgb    = (const float*)d_in[33];
    float* out = (float*)d_out;

    float* w = (float*)d_ws;
    float* imgd   = w; w += (size_t)B_ * CTX_ * IMGD_;   // bf16 dyt out (aliased)
    float* imgf   = w; w += (size_t)B_ * CTX_ * DIM_;
    float* pooled = w; w += B_ * DIM_;
    float* g1     = w; w += B_ * 128;
    float* gate   = w; w += B_ * DIM_;
    float* x      = w; w += (size_t)B_ * N_ * DIM_;
    float* xn     = w; w += (size_t)B_ * N_ * DIM_;      // bf16 ln out (aliased)
    float* dblb   = w; w += (size_t)B_ * N_ * 64;
    // bf16 buffers
    __bf16* xzb   = (__bf16*)w; w += (size_t)B_ * N_ * 2 * DIN_ / 2;
    __bf16* xcb   = (__bf16*)w; w += (size_t)B_ * N_ * DIN_ / 2;
    __bf16* imgfb = (__bf16*)w; w += (size_t)B_ * CTX_ * DIM_ / 2;
    __bf16* ybb   = (__bf16*)w; w += (size_t)B_ * N_ * DIN_ / 2;
    __bf16* qb    = (__bf16*)w; w += (size_t)B_ * N_ * DIM_ / 2;
    __bf16* kbb   = (__bf16*)w; w += (size_t)DEPTH_ * B_ * CTX_ * DIM_ / 2;
    __bf16* vbT   = (__bf16*)w; w += (size_t)DEPTH_ * B_ * HEADS_ * HD_ * CTXP_ / 2;
    __bf16* obb   = (__bf16*)w; w += (size_t)B_ * N_ * DIM_ / 2;
    __bf16* lgT   = (__bf16*)w; w += (size_t)10000 * DIM_ / 2;
    // bf16 weights
    __bf16* inpT  = (__bf16*)w; w += (size_t)DEPTH_ * 2 * DIN_ * DIM_ / 2;
    __bf16* outpT = (__bf16*)w; w += (size_t)DEPTH_ * DIM_ * DIN_ / 2;
    __bf16* qWB   = (__bf16*)w; w += (size_t)DEPTH_ * DIM_ * DIM_ / 2;
    __bf16* kvWB  = (__bf16*)w; w += (size_t)DEPTH_ * 2 * DIM_ * DIM_ / 2;
    __bf16* aoutB = (__bf16*)w; w += (size_t)DEPTH_ * DIM_ * DIM_ / 2;
    __bf16* imgWT = (__bf16*)w; w += (size_t)DIM_ * IMGD_ / 2;
    __bf16* xpWT  = (__bf16*)w; w += (size_t)DEPTH_ * 64 * DIN_ / 2;
    __bf16* imgdb = (__bf16*)imgd;
    __bf16* xnb   = (__bf16*)xn;

    const int TOKENS = B_ * N_;
    const int IMGT   = B_ * CTX_;

    // zero all layers' vbT pad columns once
    hipMemsetAsync(vbT, 0, (size_t)DEPTH_ * B_ * HEADS_ * HD_ * CTXP_ * sizeof(__bf16), stream);

    // ---- weight prep ----
    tconv_kernel<<<dim3(2 * DIN_ / 32, DIM_ / 32, DEPTH_), 256, 0, stream>>>(inW,  inpT,  DIM_, 2 * DIN_);
    tconv_kernel<<<dim3(DIM_ / 32, DIN_ / 32, DEPTH_),     256, 0, stream>>>(outW, outpT, DIN_, DIM_);
    tconv_kernel<<<dim3(DIM_ / 32, IMGD_ / 32, 1),         256, 0, stream>>>(imgW, imgWT, IMGD_, DIM_);
    tconv_kernel<<<dim3(64 / 32, DIN_ / 32, DEPTH_),       256, 0, stream>>>(xpW,  xpWT,  DIN_, 64);
    tconv_kernel<<<dim3((10000 + 31) / 32, DIM_ / 32, 1),  256, 0, stream>>>(lgW, lgT, DIM_, 10000);
    cvt_rows_kernel<<<(DEPTH_ * DIM_ * (DIM_ / 4) + 255) / 256, 256, 0, stream>>>(
        ainW, qWB, DEPTH_ * DIM_, DIM_, 0);
    cvt_rows_kernel<<<(DEPTH_ * 2 * DIM_ * (DIM_ / 4) + 255) / 256, 256, 0, stream>>>(
        ainW, kvWB, DEPTH_ * 2 * DIM_, 2 * DIM_, DIM_);
    cvt_bf16_kernel<<<(DEPTH_ * DIM_ * DIM_ / 4 + 255) / 256, 256, 0, stream>>>(aoutW, aoutB, DEPTH_ * DIM_ * DIM_);

    // ---- image path ----
    {
        int total = B_ * CTX_ * IMGD_;
        dyt_kernel<<<(total + 255) / 256, 256, 0, stream>>>(images, alphap, dgam, dbeta, imgdb, total);
        mgemm<32, 64>(imgdb, imgWT, imgb, nullptr, imgf, nullptr, IMGT, DIM_, IMGD_, IMGD_, DIM_, stream);
        pool_kernel<<<(B_ * DIM_ + 255) / 256, 256, 0, stream>>>(imgf, pooled);
        gate1_kernel<<<(B_ * 128 + 255) / 256, 256, 0, stream>>>(pooled, g1W, g1b, g1);
        gate2_kernel<<<(B_ * DIM_ + 255) / 256, 256, 0, stream>>>(g1, g2W, g2b, gate);
        scale_kernel<<<(B_ * CTX_ * DIM_ + 255) / 256, 256, 0, stream>>>(imgf, gate, imgfb);
    }
    embed_kernel<<<(TOKENS * DIM_ + 255) / 256, 256, 0, stream>>>(text, temb, pemb, x);

    // ---- ALL layers' K/V projections in ONE batched GEMM (col-major, PIPE3) ----
    mgemm<64, 128, 3, true, true>(imgfb, kvWB, nullptr, ainb, kbb, vbT,
                                  IMGT, DEPTH_ * 2 * DIM_, DIM_, DIM_, 0, stream);

    for (int l = 0; l < DEPTH_; ++l) {
        const __bf16* inpT_l  = inpT  + (size_t)l * 2 * DIN_ * DIM_;
        const __bf16* outpT_l = outpT + (size_t)l * DIM_ * DIN_;
        const __bf16* qWB_l   = qWB   + (size_t)l * DIM_ * DIM_;
        const __bf16* aoutB_l = aoutB + (size_t)l * DIM_ * DIM_;
        const __bf16* xpWT_l  = xpWT  + (size_t)l * 64 * DIN_;
        const __bf16* kbb_l   = kbb   + (size_t)l * IMGT * DIM_;
        const __bf16* vbT_l   = vbT   + (size_t)l * B_ * HEADS_ * HD_ * CTXP_;
        const float* cw    = convW + (size_t)l * DIN_ * 4;
        const float* cb    = convb + (size_t)l * DIN_;
        const float* dtw   = dtW  + (size_t)l * DTR_ * DIN_;
        const float* dtbi  = dtb  + (size_t)l * DIN_;
        const float* alog  = Alog + (size_t)l * DIN_ * DST_;
        const float* dsk   = Dsk  + (size_t)l * DIN_;
        const float* ab    = ainb + (size_t)l * 3 * DIM_;
        const float* aob   = aoutb + (size_t)l * DIM_;

        // mamba block (bf16 activations end-to-end)
        ln_kernel<<<TOKENS / 4, 256, 0, stream>>>(x, ln1g + l * DIM_, ln1b + l * DIM_, xnb, TOKENS);
        mgemm<64, 128, 1, false, true>(xnb, inpT_l, nullptr, nullptr, xzb, nullptr, TOKENS, 2 * DIN_, DIM_, DIM_, 2 * DIN_, stream);
        conv_silu_kernel<<<(TOKENS * DIN_ / 4 + 255) / 256, 256, 0, stream>>>(xzb, cw, cb, xcb);
        mgemm<32, 64>(xcb, xpWT_l, nullptr, nullptr, dblb, nullptr, TOKENS, 64, DIN_, DIN_, 64, stream);
        scanf_kernel<<<B_ * DIN_ / DG_, 256, 0, stream>>>(xcb, dblb, xzb, dtw, dtbi, alog, dsk, ybb);
        mgemm<32, 64>(ybb, outpT_l, nullptr, x, x, nullptr, TOKENS, DIM_, DIN_, DIN_, DIM_, stream);

        // cross-attention block
        ln_kernel<<<TOKENS / 4, 256, 0, stream>>>(x, ln2g + l * DIM_, ln2b + l * DIM_, xnb, TOKENS);
        mgemm<32, 64, 1>(xnb, qWB_l, ab, nullptr, qb, nullptr, TOKENS, DIM_, DIM_, DIM_, DIM_, stream);
        attn_k<<<dim3(1, 4, B_ * HEADS_), 256, 0, stream>>>(qb, kbb_l, vbT_l, obb);
        mgemm<32, 64>(obb, aoutB_l, aob, x, x, nullptr, TOKENS, DIM_, DIM_, DIM_, DIM_, stream);
    }

    // final LN + logits (128x128 col-major, PIPE3 counted-vmcnt pipeline)
    ln_kernel<<<TOKENS / 4, 256, 0, stream>>>(x, fng, fnb, xnb, TOKENS);
    mgemm<128, 128, 0, true, true>(xnb, lgT, lgb, nullptr, out, nullptr, TOKENS, 10000, DIM_, DIM_, 10000, stream);
}

// Round 21
// 1120.866 us; speedup vs baseline: 1.0737x; 1.0020x over previous
//
#include <hip/hip_runtime.h>
#include <hip/hip_bf16.h>
#include <stdint.h>

#define B_    8
#define N_    256
#define CTX_  196
#define CTXP_ 224   // ctx padded to multiple of 32 for PV K-loop
#define CTXF_ 13    // score col frags (13*16 = 208 >= 196)
#define IMGD_ 1024
#define DIM_  512
#define DEPTH_ 6
#define DIN_  1024
#define DTR_  32
#define DST_  16
#define HEADS_ 8
#define HD_   64
#define NCHUNK_ 16
#define CLEN_   16   // N_/NCHUNK_
#define DG_     4    // d's per scan block

typedef __bf16 bf16x8 __attribute__((ext_vector_type(8)));
typedef __bf16 bf16x4 __attribute__((ext_vector_type(4)));
typedef float  f32x4  __attribute__((ext_vector_type(4)));

// 16-lane sum via DPP butterfly; all 16 lanes get total
__device__ __forceinline__ float dpp_red16(float v) {
    int y;
    y = __builtin_amdgcn_update_dpp(0, __float_as_int(v), 0xB1, 0xF, 0xF, true);
    v += __int_as_float(y);
    y = __builtin_amdgcn_update_dpp(0, __float_as_int(v), 0x4E, 0xF, 0xF, true);
    v += __int_as_float(y);
    y = __builtin_amdgcn_update_dpp(0, __float_as_int(v), 0x141, 0xF, 0xF, true);
    v += __int_as_float(y);
    y = __builtin_amdgcn_update_dpp(0, __float_as_int(v), 0x140, 0xF, 0xF, true);
    v += __int_as_float(y);
    return v;
}
__device__ __forceinline__ float dpp_max16(float v) {
    int y;
    y = __builtin_amdgcn_update_dpp(0, __float_as_int(v), 0xB1, 0xF, 0xF, true);
    v = fmaxf(v, __int_as_float(y));
    y = __builtin_amdgcn_update_dpp(0, __float_as_int(v), 0x4E, 0xF, 0xF, true);
    v = fmaxf(v, __int_as_float(y));
    y = __builtin_amdgcn_update_dpp(0, __float_as_int(v), 0x141, 0xF, 0xF, true);
    v = fmaxf(v, __int_as_float(y));
    y = __builtin_amdgcn_update_dpp(0, __float_as_int(v), 0x140, 0xF, 0xF, true);
    v = fmaxf(v, __int_as_float(y));
    return v;
}

// async global->LDS 16B (direct-to-LDS DMA; no VGPR round trip)
__device__ __forceinline__ void gload16(const void* g, void* l) {
    __builtin_amdgcn_global_load_lds(
        (const __attribute__((address_space(1))) uint32_t*)g,
        (__attribute__((address_space(3))) uint32_t*)l, 16, 0, 0);
}

// ---------------- elementwise / small kernels ----------------

__global__ void dyt_kernel(const float* __restrict__ img, const float* __restrict__ alpha_p,
                           const float* __restrict__ gamma, const float* __restrict__ beta,
                           __bf16* __restrict__ out, int total) {
    int i = blockIdx.x * 256 + threadIdx.x;
    if (i >= total) return;
    float a = alpha_p[0];
    int c = i & (IMGD_ - 1);
    out[i] = (__bf16)(gamma[c] * tanhf(a * img[i]) + beta[c]);
}

__global__ void pool_kernel(const float* __restrict__ imgf, float* __restrict__ pooled) {
    int i = blockIdx.x * 256 + threadIdx.x;
    if (i >= B_ * DIM_) return;
    int b = i >> 9, c = i & (DIM_ - 1);
    const float* p = imgf + (size_t)b * CTX_ * DIM_ + c;
    float s = 0.f;
    for (int t = 0; t < CTX_; ++t) s += p[t * DIM_];
    pooled[i] = s * (1.f / CTX_);
}

__global__ void gate1_kernel(const float* __restrict__ pooled, const float* __restrict__ W,
                             const float* __restrict__ bias, float* __restrict__ g1) {
    int i = blockIdx.x * 256 + threadIdx.x;
    if (i >= B_ * 128) return;
    int b = i >> 7, j = i & 127;
    const float* p = pooled + b * DIM_;
    float s = bias[j];
    for (int c = 0; c < DIM_; ++c) s += p[c] * W[c * 128 + j];
    g1[i] = 0.5f * s * (1.f + erff(s * 0.70710678118654752f));
}

__global__ void gate2_kernel(const float* __restrict__ g1, const float* __restrict__ W,
                             const float* __restrict__ bias, float* __restrict__ gate) {
    int i = blockIdx.x * 256 + threadIdx.x;
    if (i >= B_ * DIM_) return;
    int b = i >> 9, c = i & (DIM_ - 1);
    const float* p = g1 + b * 128;
    float s = bias[c];
    for (int j = 0; j < 128; ++j) s += p[j] * W[j * DIM_ + c];
    gate[i] = 1.f / (1.f + __expf(-s));
}

__global__ void scale_kernel(const float* __restrict__ imgf, const float* __restrict__ gate,
                             __bf16* __restrict__ imgfb) {
    int i = blockIdx.x * 256 + threadIdx.x;
    if (i >= B_ * CTX_ * DIM_) return;
    int c = i & (DIM_ - 1);
    int b = i / (CTX_ * DIM_);
    imgfb[i] = (__bf16)(imgf[i] * gate[b * DIM_ + c]);
}

__global__ void embed_kernel(const int* __restrict__ text, const float* __restrict__ temb,
                             const float* __restrict__ pemb, float* __restrict__ x) {
    int i = blockIdx.x * 256 + threadIdx.x;
    if (i >= B_ * N_ * DIM_) return;
    int c = i & (DIM_ - 1);
    int row = i >> 9;
    int n = row & (N_ - 1);
    int tok = text[row];
    x[i] = temb[(size_t)tok * DIM_ + c] + pemb[(size_t)n * DIM_ + c];
}

// wave-per-row layernorm, row = 512 floats, bf16 output
__global__ void ln_kernel(const float* __restrict__ x, const float* __restrict__ g,
                          const float* __restrict__ b, __bf16* __restrict__ o, int rows) {
    int row = blockIdx.x * 4 + (threadIdx.x >> 6);
    if (row >= rows) return;
    int lane = threadIdx.x & 63;
    const float* xr = x + (size_t)row * DIM_ + lane * 8;
    float4 v0 = ((const float4*)xr)[0];
    float4 v1 = ((const float4*)xr)[1];
    float r[8] = {v0.x, v0.y, v0.z, v0.w, v1.x, v1.y, v1.z, v1.w};
    float sum = 0.f, sq = 0.f;
    #pragma unroll
    for (int j = 0; j < 8; ++j) { sum += r[j]; sq += r[j] * r[j]; }
    #pragma unroll
    for (int m = 1; m < 64; m <<= 1) { sum += __shfl_xor(sum, m); sq += __shfl_xor(sq, m); }
    float mean = sum * (1.f / DIM_);
    float var  = sq * (1.f / DIM_) - mean * mean;
    float inv  = rsqrtf(fmaxf(var, 0.f) + 1e-5f);
    const float* gp = g + lane * 8;
    const float* bp = b + lane * 8;
    __bf16* op = o + (size_t)row * DIM_ + lane * 8;
    bf16x8 ov;
    #pragma unroll
    for (int j = 0; j < 8; ++j) ov[j] = (__bf16)((r[j] - mean) * inv * gp[j] + bp[j]);
    *(bf16x8*)op = ov;
}

// causal depthwise conv (4 taps) + SiLU; bf16 in (xzb), bf16 out (xcb)
__global__ void conv_silu_kernel(const __bf16* __restrict__ xzb, const float* __restrict__ cw,
                                 const float* __restrict__ cb, __bf16* __restrict__ xcb) {
    int idx = blockIdx.x * 256 + threadIdx.x;
    if (idx >= B_ * N_ * DIN_ / 4) return;
    int i4 = idx * 4;
    int d = i4 & (DIN_ - 1);
    int row = i4 >> 10;
    int n = row & (N_ - 1);
    int rowb = row - n;
    float4 acc = *(const float4*)(cb + d);
    #pragma unroll
    for (int k = 0; k < 4; ++k) {
        int m = n - 3 + k;
        if (m >= 0) {
            bf16x4 v = *(const bf16x4*)(xzb + (size_t)(rowb + m) * (2 * DIN_) + d);
            acc.x += (float)v[0] * cw[(d + 0) * 4 + k];
            acc.y += (float)v[1] * cw[(d + 1) * 4 + k];
            acc.z += (float)v[2] * cw[(d + 2) * 4 + k];
            acc.w += (float)v[3] * cw[(d + 3) * 4 + k];
        }
    }
    bf16x4 p;
    p[0] = (__bf16)(acc.x / (1.f + __expf(-acc.x)));
    p[1] = (__bf16)(acc.y / (1.f + __expf(-acc.y)));
    p[2] = (__bf16)(acc.z / (1.f + __expf(-acc.z)));
    p[3] = (__bf16)(acc.w / (1.f + __expf(-acc.w)));
    *(bf16x4*)(xcb + i4) = p;
}

__global__ void cvt_bf16_kernel(const float* __restrict__ src, __bf16* __restrict__ dst, int count) {
    int i = (blockIdx.x * 256 + threadIdx.x) * 4;
    if (i >= count) return;
    float4 v = *(const float4*)(src + i);
    bf16x4 p = {(__bf16)v.x, (__bf16)v.y, (__bf16)v.z, (__bf16)v.w};
    *(bf16x4*)(dst + i) = p;
}

// row-sliced convert: dst row i (K=512) <- src row (i/rpl)*1536 + off + (i%rpl)
__global__ void cvt_rows_kernel(const float* __restrict__ src, __bf16* __restrict__ dst,
                                int totalRows, int rpl, int off) {
    int t = blockIdx.x * 256 + threadIdx.x;
    int total = totalRows * (DIM_ / 4);
    if (t >= total) return;
    int i = t / (DIM_ / 4), c4 = (t % (DIM_ / 4)) * 4;
    int l = i / rpl, r = i % rpl;
    const float* s = src + ((size_t)l * 1536 + off + r) * DIM_ + c4;
    float4 v = *(const float4*)s;
    bf16x4 p = {(__bf16)v.x, (__bf16)v.y, (__bf16)v.z, (__bf16)v.w};
    *(bf16x4*)(dst + (size_t)i * DIM_ + c4) = p;
}

// ---------------- fused selective scan v5: 4 d's per block, bf16 activations ----
__global__ __launch_bounds__(256) void scanf_kernel(
    const __bf16* __restrict__ xcb, const float* __restrict__ dbl,
    const __bf16* __restrict__ xzb, const float* __restrict__ dtw,
    const float* __restrict__ dtb, const float* __restrict__ A_log,
    const float* __restrict__ Dsk, __bf16* __restrict__ ybb) {
    __shared__ float sdt[DG_][N_], su[DG_][N_];
    __shared__ float sA[DG_][256], sB[DG_][256];
    int bid = blockIdx.x;
    int nwg = gridDim.x;                       // 2048, % 8 == 0
    int bd = (bid & 7) * (nwg >> 3) + (bid >> 3);   // bijective XCD swizzle
    int dg = bd & (DIN_ / DG_ - 1), b = bd / (DIN_ / DG_);
    int d0 = dg * DG_;
    int tid = threadIdx.x, s = tid & 15, c = tid >> 4;
    {
        int row = b * N_ + tid;
        const float* dp = dbl + row * 64;
        float4 acc = *(const float4*)(dtb + d0);
        #pragma unroll
        for (int k = 0; k < DTR_; k += 4) {
            float4 dv = *(const float4*)(dp + k);
            float4 w0 = *(const float4*)(dtw + (k + 0) * DIN_ + d0);
            float4 w1 = *(const float4*)(dtw + (k + 1) * DIN_ + d0);
            float4 w2 = *(const float4*)(dtw + (k + 2) * DIN_ + d0);
            float4 w3 = *(const float4*)(dtw + (k + 3) * DIN_ + d0);
            acc.x += dv.x * w0.x + dv.y * w1.x + dv.z * w2.x + dv.w * w3.x;
            acc.y += dv.x * w0.y + dv.y * w1.y + dv.z * w2.y + dv.w * w3.y;
            acc.z += dv.x * w0.z + dv.y * w1.z + dv.z * w2.z + dv.w * w3.z;
            acc.w += dv.x * w0.w + dv.y * w1.w + dv.z * w2.w + dv.w * w3.w;
        }
        bf16x4 xcv4 = *(const bf16x4*)(xcb + (size_t)row * DIN_ + d0);
        float av[4] = {acc.x, acc.y, acc.z, acc.w};
        float xv[4] = {(float)xcv4[0], (float)xcv4[1], (float)xcv4[2], (float)xcv4[3]};
        #pragma unroll
        for (int g = 0; g < DG_; ++g) {
            float dt = fmaxf(av[g], 0.f) + __logf(1.f + __expf(-fabsf(av[g])));
            sdt[g][tid] = dt;
            su[g][tid] = dt * xv[g];
        }
    }
    float As4[DG_];
    #pragma unroll
    for (int g = 0; g < DG_; ++g) As4[g] = -__expf(A_log[((d0 + g) << 4) | s]);
    __syncthreads();
    int r0 = c * CLEN_;
    int row0 = b * N_ + r0;
    float a[DG_], hb[DG_];
    #pragma unroll
    for (int g = 0; g < DG_; ++g) { a[g] = 1.f; hb[g] = 0.f; }
    #pragma unroll 2
    for (int n = 0; n < CLEN_; ++n) {
        float Bv = dbl[(row0 + n) * 64 + 32 + s];
        #pragma unroll
        for (int g = 0; g < DG_; ++g) {
            float dA = __expf(sdt[g][r0 + n] * As4[g]);
            hb[g] = hb[g] * dA + su[g][r0 + n] * Bv;
            a[g] *= dA;
        }
    }
    #pragma unroll
    for (int g = 0; g < DG_; ++g) { sA[g][tid] = a[g]; sB[g][tid] = hb[g]; }
    __syncthreads();
    float h[DG_];
    #pragma unroll
    for (int g = 0; g < DG_; ++g) h[g] = 0.f;
    for (int j = 0; j < c; ++j)
        #pragma unroll
        for (int g = 0; g < DG_; ++g)
            h[g] = h[g] * sA[g][j * 16 + s] + sB[g][j * 16 + s];
    float4 Dv4 = *(const float4*)(Dsk + d0);
    float Dv[4] = {Dv4.x, Dv4.y, Dv4.z, Dv4.w};
    #pragma unroll 2
    for (int n = 0; n < CLEN_; ++n) {
        int row = row0 + n;
        float Bv = dbl[row * 64 + 32 + s];
        float Cv = dbl[row * 64 + 48 + s];
        float p[DG_];
        #pragma unroll
        for (int g = 0; g < DG_; ++g) {
            float dA = __expf(sdt[g][r0 + n] * As4[g]);
            h[g] = h[g] * dA + su[g][r0 + n] * Bv;
            p[g] = dpp_red16(h[g] * Cv);
        }
        if (s == 0) {
            bf16x4 xcv4 = *(const bf16x4*)(xcb + (size_t)row * DIN_ + d0);
            bf16x4 zz4  = *(const bf16x4*)(xzb + (size_t)row * (2 * DIN_) + DIN_ + d0);
            bf16x4 yo;
            #pragma unroll
            for (int g = 0; g < DG_; ++g) {
                float xv = (float)xcv4[g];
                float zv = (float)zz4[g];
                float y = (p[g] + xv * Dv[g]) * (zv / (1.f + __expf(-zv)));
                yo[g] = (__bf16)y;
            }
            *(bf16x4*)(ybb + (size_t)row * DIN_ + d0) = yo;
        }
    }
}

// ---------------- weight prep ----------------

__global__ void tconv_kernel(const float* __restrict__ src, __bf16* __restrict__ dst,
                             int K, int N) {
    __shared__ float tile[32][33];
    int n0 = blockIdx.x * 32, k0 = blockIdx.y * 32;
    src += (size_t)blockIdx.z * K * N;
    dst += (size_t)blockIdx.z * K * N;
    int tx = threadIdx.x & 31, ty = threadIdx.x >> 5;
    #pragma unroll
    for (int i = 0; i < 32; i += 8) {
        int k = k0 + ty + i, n = n0 + tx;
        tile[ty + i][tx] = (k < K && n < N) ? src[(size_t)k * N + n] : 0.f;
    }
    __syncthreads();
    #pragma unroll
    for (int i = 0; i < 32; i += 8) {
        int n = n0 + ty + i, k = k0 + tx;
        if (n < N && k < K) dst[(size_t)n * K + k] = (__bf16)tile[tx][ty + i];
    }
}

// ---------------- bf16 MFMA GEMM v3/v4 ----------------
// MODE 0: fp32 out (+res), two-half LDS-transposed float4 epilogue.
// MODE 1: bf16 out. MODE 3: batched-kv epilogue.
// CMAJ: column-major block mapping for N >> M shapes (kv, logits).
// PIPE3: 3-buffer, 2-deep prefetch with COUNTED vmcnt + raw barriers (T3/T4).
//   Use only where occupancy is NOT LDS-limited (grid-limited or epilogue-
//   overlay-limited kernels); at latency-bound shapes TLP > ILP (m114).

template <int BM, int BN, int MODE, bool CMAJ = false, bool PIPE3 = false>
__global__ __launch_bounds__(256) void mgemm_k(
    const __bf16* __restrict__ A, const __bf16* __restrict__ Bw,
    const float* __restrict__ bias, const float* __restrict__ res,
    void* __restrict__ Cp, void* __restrict__ Cp2,
    int M, int N, int K, int lda, int ldc) {
    constexpr int UA = BM * 4;   // 16B units per 32-K slab tile
    constexpr int UB = BN * 4;
    constexpr int FM = BM / 32, FN = BN / 32;
    constexpr int NBUF = PIPE3 ? 3 : 2;
    constexpr int LPT = UA / 256 + UB / 256;   // loads per thread per stage
    static_assert(!PIPE3 || (UA % 256 == 0 && UB % 256 == 0), "PIPE3 needs uniform loads");
    constexpr int CPAD = BN + 4;                           // padded LDS C row
    constexpr int STAGE_B = NBUF * (UA + UB) * 16;
    constexpr int CS_B    = (MODE == 0) ? (BM / 2) * CPAD * 4 : 0;
    constexpr int SMEM_B  = STAGE_B > CS_B ? STAGE_B : CS_B;
    __shared__ __align__(16) char smem[SMEM_B];
    __bf16* As = (__bf16*)smem;                            // [NBUF][UA*8]
    __bf16* Bs = (__bf16*)(smem + (size_t)NBUF * UA * 16); // [NBUF][UB*8]
    int tid = threadIdx.x;
    int ntx = gridDim.x;
    int nwg = ntx * gridDim.y;
    int bid = blockIdx.y * ntx + blockIdx.x;
    if ((nwg & 7) == 0) bid = (bid & 7) * (nwg >> 3) + (bid >> 3);
    int row0, col0;
    if constexpr (CMAJ) {
        int nty = nwg / ntx;
        row0 = (bid % nty) * BM;
        col0 = (bid / nty) * BN;
    } else {
        row0 = (bid / ntx) * BM;
        col0 = (bid % ntx) * BN;
    }
    int wave = tid >> 6, lane = tid & 63;
    int wm = (wave >> 1) * (BM / 2), wn = (wave & 1) * (BN / 2);
    int fr = lane & 15, fk = lane >> 4;
    f32x4 acc[FM][FN] = {};

    auto stage = [&](int buf, int k0) {
        #pragma unroll
        for (int j = 0; j < (UA + 255) / 256; ++j) {
            int u = j * 256 + tid;
            if ((UA & 255) == 0 || u < UA) {
                int ks = u / BM, r = u % BM;
                gload16(A + (size_t)(row0 + r) * lda + k0 + ks * 8, &As[((size_t)buf * UA + u) * 8]);
            }
        }
        #pragma unroll
        for (int j = 0; j < (UB + 255) / 256; ++j) {
            int u = j * 256 + tid;
            if ((UB & 255) == 0 || u < UB) {
                int ks = u / BN, r = u % BN;
                gload16(Bw + (size_t)(col0 + r) * K + k0 + ks * 8, &Bs[((size_t)buf * UB + u) * 8]);
            }
        }
    };
    auto mfma_step = [&](int cur) {
        bf16x8 af[FM], bg[FN];
        #pragma unroll
        for (int mf = 0; mf < FM; ++mf)
            af[mf] = *(const bf16x8*)&As[((size_t)cur * UA + fk * BM + wm + mf * 16 + fr) * 8];
        #pragma unroll
        for (int nf = 0; nf < FN; ++nf)
            bg[nf] = *(const bf16x8*)&Bs[((size_t)cur * UB + fk * BN + wn + nf * 16 + fr) * 8];
        #pragma unroll
        for (int mf = 0; mf < FM; ++mf)
            #pragma unroll
            for (int nf = 0; nf < FN; ++nf)
                acc[mf][nf] = __builtin_amdgcn_mfma_f32_16x16x32_bf16(af[mf], bg[nf], acc[mf][nf], 0, 0, 0);
    };

    int NK = K >> 5;
    if constexpr (PIPE3) {
        stage(0, 0);
        if (NK > 1) stage(1, 32);
        for (int kt = 0; kt < NK; ++kt) {
            if (kt + 1 < NK) {
                if constexpr (LPT == 3) asm volatile("s_waitcnt vmcnt(3)" ::: "memory");
                else                    asm volatile("s_waitcnt vmcnt(4)" ::: "memory");
            } else {
                asm volatile("s_waitcnt vmcnt(0)" ::: "memory");
            }
            asm volatile("s_barrier" ::: "memory");
            mfma_step(kt % 3);
            asm volatile("s_barrier" ::: "memory");
            if (kt + 2 < NK) stage((kt + 2) % 3, (kt + 2) << 5);
        }
    } else {
        stage(0, 0);
        __syncthreads();
        for (int kt = 0; kt < NK; ++kt) {
            int cur = kt & 1;
            if (kt + 1 < NK) stage(cur ^ 1, (kt + 1) << 5);
            mfma_step(cur);
            __syncthreads();
        }
    }
    if constexpr (MODE == 0) {
        // Two-half LDS-transposed epilogue (half-size padded C overlay).
        float* Cs = (float*)smem;
        #pragma unroll
        for (int half = 0; half < 2; ++half) {
            if (wm == half * (BM / 2)) {
                #pragma unroll
                for (int mf = 0; mf < FM; ++mf)
                    #pragma unroll
                    for (int nf = 0; nf < FN; ++nf)
                        #pragma unroll
                        for (int e = 0; e < 4; ++e)
                            Cs[(mf * 16 + fk * 4 + e) * CPAD + wn + nf * 16 + fr] = acc[mf][nf][e];
            }
            __syncthreads();
            for (int u = tid; u < (BM / 2) * BN / 4; u += 256) {
                int r = u / (BN / 4), c4 = (u % (BN / 4)) * 4;
                int gm = row0 + half * (BM / 2) + r, gn = col0 + c4;
                if (gm < M && gn < N) {
                    f32x4 v = *(const f32x4*)&Cs[r * CPAD + c4];
                    if (bias) v += *(const f32x4*)(bias + gn);
                    size_t idx = (size_t)gm * ldc + gn;
                    if (res) v += *(const f32x4*)(res + idx);
                    *(f32x4*)((float*)Cp + idx) = v;
                }
            }
            __syncthreads();
        }
    } else {
        #pragma unroll
        for (int mf = 0; mf < FM; ++mf) {
            #pragma unroll
            for (int nf = 0; nf < FN; ++nf) {
                int gn = col0 + wn + nf * 16 + fr;
                if (gn >= N) continue;
                float bb = (MODE != 3 && bias) ? bias[gn] : 0.f;
                #pragma unroll
                for (int e = 0; e < 4; ++e) {
                    int gm = row0 + wm + mf * 16 + fk * 4 + e;
                    if (gm >= M) continue;
                    float v = acc[mf][nf][e] + bb;
                    if constexpr (MODE == 1) {
                        ((__bf16*)Cp)[(size_t)gm * ldc + gn] = (__bf16)v;
                    } else {
                        int l = gn >> 10, j = gn & 1023;
                        float vb = v + res[l * 1536 + 512 + j];  // ainb[l][512+j]
                        if (j < DIM_) {
                            ((__bf16*)Cp)[(size_t)l * (B_ * CTX_) * DIM_ + (size_t)gm * DIM_ + j] = (__bf16)vb;
                        } else {
                            int jj = j - DIM_;
                            int bimg = gm / CTX_, k = gm - bimg * CTX_;
                            ((__bf16*)Cp2)[(((size_t)l * B_ * HEADS_ + bimg * HEADS_ + (jj >> 6)) * HD_ + (jj & 63)) * CTXP_ + k] = (__bf16)vb;
                        }
                    }
                }
            }
        }
    }
}

template <int BM, int BN, int MODE = 0, bool CMAJ = false, bool PIPE3 = false>
static inline void mgemm(const __bf16* A, const __bf16* Bw, const float* bias,
                         const float* res, void* C, void* C2, int M, int N, int K,
                         int lda, int ldc, hipStream_t s) {
    dim3 g((N + BN - 1) / BN, (M + BM - 1) / BM);
    mgemm_k<BM, BN, MODE, CMAJ, PIPE3><<<g, 256, 0, s>>>(A, Bw, bias, res, C, C2, M, N, K, lda, ldc);
}

// ---------------- fused attention ----------------
#define KP_ 72    // K LDS row pad (bf16)
#define PP_ 232   // P LDS row pad (bf16)

__global__ __launch_bounds__(256) void attn_k(
    const __bf16* __restrict__ qb, const __bf16* __restrict__ kbb,
    const __bf16* __restrict__ vbT, __bf16* __restrict__ obb) {
    __shared__ __align__(16) __bf16 Ks[CTXP_ * KP_];
    __shared__ __align__(16) __bf16 Ps[64 * PP_];
    int z = blockIdx.z, b = z >> 3, h = z & 7;
    int tid = threadIdx.x, wave = tid >> 6, lane = tid & 63;
    int fr = lane & 15, fk = lane >> 4;
    int q0 = blockIdx.y * 64;
    #pragma unroll
    for (int i = 0; i < 7; ++i) {
        int idx = i * 256 + tid;
        int r = idx >> 3, cu = (idx & 7) * 8;
        uint4 v = {0u, 0u, 0u, 0u};
        if (r < CTX_) v = *(const uint4*)(kbb + ((size_t)(b * CTX_ + r)) * DIM_ + h * HD_ + cu);
        *(uint4*)&Ks[r * KP_ + cu] = v;
    }
    bf16x8 aq[2];
    {
        int qrow = b * N_ + q0 + wave * 16 + fr;
        #pragma unroll
        for (int t = 0; t < 2; ++t)
            aq[t] = *(const bf16x8*)(qb + (size_t)qrow * DIM_ + h * HD_ + t * 32 + fk * 8);
    }
    __syncthreads();
    f32x4 acc[CTXF_] = {};
    #pragma unroll
    for (int t = 0; t < 2; ++t)
        #pragma unroll
        for (int cb = 0; cb < CTXF_; ++cb) {
            bf16x8 bg = *(const bf16x8*)&Ks[(cb * 16 + fr) * KP_ + t * 32 + fk * 8];
            acc[cb] = __builtin_amdgcn_mfma_f32_16x16x32_bf16(aq[t], bg, acc[cb], 0, 0, 0);
        }
    #pragma unroll
    for (int e = 0; e < 4; ++e) {
        float m = -1e30f;
        #pragma unroll
        for (int cb = 0; cb < CTXF_; ++cb) {
            float sv = acc[cb][e] * 0.125f;
            if (cb * 16 + fr >= CTX_) sv = -1e30f;
            acc[cb][e] = sv;
            m = fmaxf(m, sv);
        }
        m = dpp_max16(m);
        float ssum = 0.f;
        #pragma unroll
        for (int cb = 0; cb < CTXF_; ++cb) {
            float p = __expf(acc[cb][e] - m);
            acc[cb][e] = p;
            ssum += p;
        }
        ssum = dpp_red16(ssum);
        float inv = 1.f / ssum;
        #pragma unroll
        for (int cb = 0; cb < CTXF_; ++cb)
            Ps[(wave * 16 + fk * 4 + e) * PP_ + cb * 16 + fr] = (__bf16)(acc[cb][e] * inv);
        Ps[(wave * 16 + fk * 4 + e) * PP_ + 208 + fr] = (__bf16)0.f;
    }
    __syncthreads();
    f32x4 acc2[4] = {};
    const __bf16* vB = vbT + (size_t)z * HD_ * CTXP_;
    #pragma unroll
    for (int sl = 0; sl < 7; ++sl) {
        bf16x8 ap = *(const bf16x8*)&Ps[(wave * 16 + fr) * PP_ + sl * 32 + fk * 8];
        #pragma unroll
        for (int nf = 0; nf < 4; ++nf) {
            bf16x8 bv = *(const bf16x8*)(vB + (size_t)(nf * 16 + fr) * CTXP_ + sl * 32 + fk * 8);
            acc2[nf] = __builtin_amdgcn_mfma_f32_16x16x32_bf16(ap, bv, acc2[nf], 0, 0, 0);
        }
    }
    #pragma unroll
    for (int nf = 0; nf < 4; ++nf)
        #pragma unroll
        for (int e = 0; e < 4; ++e) {
            int gm = b * N_ + q0 + wave * 16 + fk * 4 + e;
            obb[(size_t)gm * DIM_ + h * HD_ + nf * 16 + fr] = (__bf16)acc2[nf][e];
        }
}

// ---------------- host side ----------------

extern "C" void kernel_launch(void* const* d_in, const int* in_sizes, int n_in,
                              void* d_out, int out_size, void* d_ws, size_t ws_size,
                              hipStream_t stream) {
    const int*   text   = (const int*)d_in[0];
    const float* images = (const float*)d_in[1];
    const float* alphap = (const float*)d_in[2];
    const float* dgam   = (const float*)d_in[3];
    const float* dbeta  = (const float*)d_in[4];
    const float* imgW   = (const float*)d_in[5];
    const float* imgb   = (const float*)d_in[6];
    const float* g1W    = (const float*)d_in[7];
    const float* g1b    = (const float*)d_in[8];
    const float* g2W    = (const float*)d_in[9];
    const float* g2b    = (const float*)d_in[10];
    const float* temb   = (const float*)d_in[11];
    const float* pemb   = (const float*)d_in[12];
    const float* ln1g   = (const float*)d_in[13];
    const float* ln1b   = (const float*)d_in[14];
    const float* inW    = (const float*)d_in[15];
    const float* convW  = (const float*)d_in[16];
    const float* convb  = (const float*)d_in[17];
    const float* xpW    = (const float*)d_in[18];
    const float* dtW    = (const float*)d_in[19];
    const float* dtb    = (const float*)d_in[20];
    const float* Alog   = (const float*)d_in[21];
    const float* Dsk    = (const float*)d_in[22];
    const float* outW   = (const float*)d_in[23];
    const float* ln2g   = (const float*)d_in[24];
    const float* ln2b   = (const float*)d_in[25];
    const float* ainW   = (const float*)d_in[26];
    const float* ainb   = (const float*)d_in[27];
    const float* aoutW  = (const float*)d_in[28];
    const float* aoutb  = (const float*)d_in[29];
    const float* fng    = (const float*)d_in[30];
    const float* fnb    = (const float*)d_in[31];
    const float* lgW    = (const float*)d_in[32];
    const float* lgb    = (const float*)d_in[33];
    float* out = (float*)d_out;

    float* w = (float*)d_ws;
    float* imgd   = w; w += (size_t)B_ * CTX_ * IMGD_;   // bf16 dyt out (aliased)
    float* imgf   = w; w += (size_t)B_ * CTX_ * DIM_;
    float* pooled = w; w += B_ * DIM_;
    float* g1     = w; w += B_ * 128;
    float* gate   = w; w += B_ * DIM_;
    float* x      = w; w += (size_t)B_ * N_ * DIM_;
    float* xn     = w; w += (size_t)B_ * N_ * DIM_;      // bf16 ln out (aliased)
    float* dblb   = w; w += (size_t)B_ * N_ * 64;
    // bf16 buffers
    __bf16* xzb   = (__bf16*)w; w += (size_t)B_ * N_ * 2 * DIN_ / 2;
    __bf16* xcb   = (__bf16*)w; w += (size_t)B_ * N_ * DIN_ / 2;
    __bf16* imgfb = (__bf16*)w; w += (size_t)B_ * CTX_ * DIM_ / 2;
    __bf16* ybb   = (__bf16*)w; w += (size_t)B_ * N_ * DIN_ / 2;
    __bf16* qb    = (__bf16*)w; w += (size_t)B_ * N_ * DIM_ / 2;
    __bf16* kbb   = (__bf16*)w; w += (size_t)DEPTH_ * B_ * CTX_ * DIM_ / 2;
    __bf16* vbT   = (__bf16*)w; w += (size_t)DEPTH_ * B_ * HEADS_ * HD_ * CTXP_ / 2;
    __bf16* obb   = (__bf16*)w; w += (size_t)B_ * N_ * DIM_ / 2;
    __bf16* lgT   = (__bf16*)w; w += (size_t)10000 * DIM_ / 2;
    // bf16 weights
    __bf16* inpT  = (__bf16*)w; w += (size_t)DEPTH_ * 2 * DIN_ * DIM_ / 2;
    __bf16* outpT = (__bf16*)w; w += (size_t)DEPTH_ * DIM_ * DIN_ / 2;
    __bf16* qWB   = (__bf16*)w; w += (size_t)DEPTH_ * DIM_ * DIM_ / 2;
    __bf16* kvWB  = (__bf16*)w; w += (size_t)DEPTH_ * 2 * DIM_ * DIM_ / 2;
    __bf16* aoutB = (__bf16*)w; w += (size_t)DEPTH_ * DIM_ * DIM_ / 2;
    __bf16* imgWT = (__bf16*)w; w += (size_t)DIM_ * IMGD_ / 2;
    __bf16* xpWT  = (__bf16*)w; w += (size_t)DEPTH_ * 64 * DIN_ / 2;
    __bf16* imgdb = (__bf16*)imgd;
    __bf16* xnb   = (__bf16*)xn;

    const int TOKENS = B_ * N_;
    const int IMGT   = B_ * CTX_;

    // zero all layers' vbT pad columns once
    hipMemsetAsync(vbT, 0, (size_t)DEPTH_ * B_ * HEADS_ * HD_ * CTXP_ * sizeof(__bf16), stream);

    // ---- weight prep ----
    tconv_kernel<<<dim3(2 * DIN_ / 32, DIM_ / 32, DEPTH_), 256, 0, stream>>>(inW,  inpT,  DIM_, 2 * DIN_);
    tconv_kernel<<<dim3(DIM_ / 32, DIN_ / 32, DEPTH_),     256, 0, stream>>>(outW, outpT, DIN_, DIM_);
    tconv_kernel<<<dim3(DIM_ / 32, IMGD_ / 32, 1),         256, 0, stream>>>(imgW, imgWT, IMGD_, DIM_);
    tconv_kernel<<<dim3(64 / 32, DIN_ / 32, DEPTH_),       256, 0, stream>>>(xpW,  xpWT,  DIN_, 64);
    tconv_kernel<<<dim3((10000 + 31) / 32, DIM_ / 32, 1),  256, 0, stream>>>(lgW, lgT, DIM_, 10000);
    cvt_rows_kernel<<<(DEPTH_ * DIM_ * (DIM_ / 4) + 255) / 256, 256, 0, stream>>>(
        ainW, qWB, DEPTH_ * DIM_, DIM_, 0);
    cvt_rows_kernel<<<(DEPTH_ * 2 * DIM_ * (DIM_ / 4) + 255) / 256, 256, 0, stream>>>(
        ainW, kvWB, DEPTH_ * 2 * DIM_, 2 * DIM_, DIM_);
    cvt_bf16_kernel<<<(DEPTH_ * DIM_ * DIM_ / 4 + 255) / 256, 256, 0, stream>>>(aoutW, aoutB, DEPTH_ * DIM_ * DIM_);

    // ---- image path ----
    {
        int total = B_ * CTX_ * IMGD_;
        dyt_kernel<<<(total + 255) / 256, 256, 0, stream>>>(images, alphap, dgam, dbeta, imgdb, total);
        mgemm<32, 64>(imgdb, imgWT, imgb, nullptr, imgf, nullptr, IMGT, DIM_, IMGD_, IMGD_, DIM_, stream);
        pool_kernel<<<(B_ * DIM_ + 255) / 256, 256, 0, stream>>>(imgf, pooled);
        gate1_kernel<<<(B_ * 128 + 255) / 256, 256, 0, stream>>>(pooled, g1W, g1b, g1);
        gate2_kernel<<<(B_ * DIM_ + 255) / 256, 256, 0, stream>>>(g1, g2W, g2b, gate);
        scale_kernel<<<(B_ * CTX_ * DIM_ + 255) / 256, 256, 0, stream>>>(imgf, gate, imgfb);
    }
    embed_kernel<<<(TOKENS * DIM_ + 255) / 256, 256, 0, stream>>>(text, temb, pemb, x);

    // ---- ALL layers' K/V projections in ONE batched GEMM ----
    // 2-stage (NOT PIPE3): this shape is latency-bound; 6 blocks/CU residency
    // beats a deeper pipeline at 4 blocks/CU (R20 counter evidence).
    mgemm<64, 128, 3, true, false>(imgfb, kvWB, nullptr, ainb, kbb, vbT,
                                   IMGT, DEPTH_ * 2 * DIM_, DIM_, DIM_, 0, stream);

    for (int l = 0; l < DEPTH_; ++l) {
        const __bf16* inpT_l  = inpT  + (size_t)l * 2 * DIN_ * DIM_;
        const __bf16* outpT_l = outpT + (size_t)l * DIM_ * DIN_;
        const __bf16* qWB_l   = qWB   + (size_t)l * DIM_ * DIM_;
        const __bf16* aoutB_l = aoutB + (size_t)l * DIM_ * DIM_;
        const __bf16* xpWT_l  = xpWT  + (size_t)l * 64 * DIN_;
        const __bf16* kbb_l   = kbb   + (size_t)l * IMGT * DIM_;
        const __bf16* vbT_l   = vbT   + (size_t)l * B_ * HEADS_ * HD_ * CTXP_;
        const float* cw    = convW + (size_t)l * DIN_ * 4;
        const float* cb    = convb + (size_t)l * DIN_;
        const float* dtw   = dtW  + (size_t)l * DTR_ * DIN_;
        const float* dtbi  = dtb  + (size_t)l * DIN_;
        const float* alog  = Alog + (size_t)l * DIN_ * DST_;
        const float* dsk   = Dsk  + (size_t)l * DIN_;
        const float* ab    = ainb + (size_t)l * 3 * DIM_;
        const float* aob   = aoutb + (size_t)l * DIM_;

        // mamba block (bf16 activations end-to-end)
        ln_kernel<<<TOKENS / 4, 256, 0, stream>>>(x, ln1g + l * DIM_, ln1b + l * DIM_, xnb, TOKENS);
        mgemm<64, 128, 1, false, true>(xnb, inpT_l, nullptr, nullptr, xzb, nullptr, TOKENS, 2 * DIN_, DIM_, DIM_, 2 * DIN_, stream);
        conv_silu_kernel<<<(TOKENS * DIN_ / 4 + 255) / 256, 256, 0, stream>>>(xzb, cw, cb, xcb);
        mgemm<32, 64>(xcb, xpWT_l, nullptr, nullptr, dblb, nullptr, TOKENS, 64, DIN_, DIN_, 64, stream);
        scanf_kernel<<<B_ * DIN_ / DG_, 256, 0, stream>>>(xcb, dblb, xzb, dtw, dtbi, alog, dsk, ybb);
        mgemm<32, 64>(ybb, outpT_l, nullptr, x, x, nullptr, TOKENS, DIM_, DIN_, DIN_, DIM_, stream);

        // cross-attention block
        ln_kernel<<<TOKENS / 4, 256, 0, stream>>>(x, ln2g + l * DIM_, ln2b + l * DIM_, xnb, TOKENS);
        mgemm<32, 64, 1>(xnb, qWB_l, ab, nullptr, qb, nullptr, TOKENS, DIM_, DIM_, DIM_, DIM_, stream);
        attn_k<<<dim3(1, 4, B_ * HEADS_), 256, 0, stream>>>(qb, kbb_l, vbT_l, obb);
        mgemm<32, 64>(obb, aoutB_l, aob, x, x, nullptr, TOKENS, DIM_, DIM_, DIM_, DIM_, stream);
    }

    // final LN + logits (128x128 col-major, PIPE3 counted-vmcnt pipeline)
    ln_kernel<<<TOKENS / 4, 256, 0, stream>>>(x, fng, fnb, xnb, TOKENS);
    mgemm<128, 128, 0, true, true>(xnb, lgT, lgb, nullptr, out, nullptr, TOKENS, 10000, DIM_, DIM_, 10000, stream);
}